// Round 9
// baseline (488.265 us; speedup 1.0000x reference)
//
#include <hip/hip_runtime.h>
#include <hip/hip_bf16.h>

// Problem constants (match reference)
#define NN   50000   // N0+N1
#define NN0  30000
#define EE   400000
#define NB_SCAN ((NN + 1023) / 1024)   // 49
#define NRT   3125                     // row tiles (16 rows each)
#define NGRP  ((NRT + 3) / 4)          // 782 row groups (64 rows)
#define NT0   1875                     // type-0 row tiles (30000/16, exact)

typedef unsigned short u16;
typedef unsigned int   u32;

typedef __attribute__((ext_vector_type(8))) __bf16 bf16x8;
typedef __attribute__((ext_vector_type(4))) float  f32x4;

// ---------- bf16 storage helpers (fp32 math everywhere) ----------
__device__ __forceinline__ float bf2f(u16 u){ return __uint_as_float(((u32)u)<<16); }
__device__ __forceinline__ float lo16(u32 u){ return __uint_as_float(u<<16); }
__device__ __forceinline__ float hi16(u32 u){ return __uint_as_float(u & 0xffff0000u); }
__device__ __forceinline__ u16 f2bf(float f){
  u32 x = __float_as_uint(f);
  x += 0x7fffu + ((x>>16)&1u);      // round-to-nearest-even
  return (u16)(x>>16);
}
__device__ __forceinline__ float elu_f(float x){ return x>0.f ? x : __expf(x)-1.f; }
__device__ __forceinline__ float lrelu(float x){ return x>0.f ? x : 0.2f*x; }
__device__ __forceinline__ bf16x8 ld_frag(const u16* p){
  uint4 v = *(const uint4*)p;
  return __builtin_bit_cast(bf16x8, v);
}
__device__ __forceinline__ bf16x8 cvt8(const float* p){   // 8 f32 -> bf16x8
  float4 u = ((const float4*)p)[0];
  float4 v = ((const float4*)p)[1];
  u32 w0 = (u32)f2bf(u.x) | ((u32)f2bf(u.y)<<16);
  u32 w1 = (u32)f2bf(u.z) | ((u32)f2bf(u.w)<<16);
  u32 w2 = (u32)f2bf(v.x) | ((u32)f2bf(v.y)<<16);
  u32 w3 = (u32)f2bf(v.z) | ((u32)f2bf(v.w)<<16);
  uint4 r{w0,w1,w2,w3};
  return __builtin_bit_cast(bf16x8, r);
}

// ---------- fused prep: mixw softmax + all weight packing + V = [W*al | W*ar] --
__global__ __launch_bounds__(256) void k_prep(
    const float* __restrict__ mix_w, float* __restrict__ wsoft,
    const float* __restrict__ W0, u16* __restrict__ W0p,
    const float* __restrict__ W1, u16* __restrict__ W1p,
    const float* __restrict__ W2, const float* __restrict__ res2, u16* __restrict__ W2p,
    const float* __restrict__ fcw0, const float* __restrict__ fcw1, u16* __restrict__ Fp,
    const float* __restrict__ al0, const float* __restrict__ ar0, u16* __restrict__ Vp)
{
  int t = blockIdx.x*256 + threadIdx.x;
  if (t < 6){
    float a0 = mix_w[t*2+0], a1 = mix_w[t*2+1];
    float mx = fmaxf(a0,a1);
    float e0 = __expf(a0-mx), e1 = __expf(a1-mx);
    wsoft[t*2+0] = e0/(e0+e1); wsoft[t*2+1] = e1/(e0+e1);
  }
  if (t < 4096){                    // W0: per graph 2048 frags, KB=2, NCOL=256
    int gg = t>>11, fi = t&2047;
    int lane = fi&63, kb = (fi>>6)&1, ct = fi>>7;
    int q = lane>>4, c = lane&15;
    const float* src = W0 + (size_t)gg*16384;
    u16* o = W0p + (size_t)gg*16384 + (size_t)fi*8;
    #pragma unroll
    for (int j=0;j<8;j++) o[j] = f2bf(src[(size_t)(kb*32+q*8+j)*256 + ct*16 + c]);
  } else if (t < 20480){            // W1: per graph 8192 frags, KB=8, NCOL=256
    int u = t - 4096;
    int gg = u>>13, fi = u&8191;
    int lane = fi&63, kb = (fi>>6)&7, ct = fi>>9;
    int q = lane>>4, c = lane&15;
    const float* src = W1 + (size_t)gg*65536;
    u16* o = W1p + (size_t)gg*65536 + (size_t)fi*8;
    #pragma unroll
    for (int j=0;j<8;j++) o[j] = f2bf(src[(size_t)(kb*32+q*8+j)*256 + ct*16 + c]);
  } else if (t < 22528){            // W2cat: 2048 frags, KB=8, NCOL=64
    int fi = t - 20480;
    int lane = fi&63, kb = (fi>>6)&7, ct = fi>>9;
    int q = lane>>4, c = lane&15;
    int cl = ct*16 + c;
    int i = cl>>5, which = (cl>>4)&1;
    const float* src = which ? res2 : W2;
    u16* o = W2p + (size_t)fi*8;
    #pragma unroll
    for (int j=0;j<8;j++) o[j] = f2bf(src[(size_t)i*4096 + (size_t)(kb*32+q*8+j)*16 + (cl&15)]);
  } else if (t < 24576){            // fc_w: per type 1024 frags, KB=4, NCOL=64
    int u = t - 22528;
    int tt = u>>10, fi = u&1023;
    int lane = fi&63, kb = (fi>>6)&3, ct = fi>>8;
    int q = lane>>4, c = lane&15;
    const float* src = tt ? fcw1 : fcw0;
    u16* o = Fp + (size_t)tt*8192 + (size_t)fi*8;
    #pragma unroll
    for (int j=0;j<8;j++) o[j] = f2bf(src[(size_t)(kb*32+q*8+j)*64 + ct*16 + c]);
  } else if (t < 25600){            // Vp: 64x16, KB=2; col c: which=c>>3, g=(c>>2)&1, h=c&3
    int u = t - 24576;
    int fi = u>>3, j = u&7;
    int lane = fi&63, kb = fi>>6;
    int q = lane>>4, c = lane&15;
    int k = kb*32 + q*8 + j;
    int which = c>>3, g=(c>>2)&1, h=c&3;
    const float* sel = (which ? ar0 : al0) + (size_t)(g*4+h)*64;
    const float* Wrow = W0 + (size_t)g*16384 + (size_t)k*256 + h*64;
    float s=0.f;
    #pragma unroll 8
    for (int d=0;d<64;d++) s = fmaf(Wrow[d], sel[d], s);
    Vp[(size_t)fi*8 + j] = f2bf(s);
  }
}

// ================= CSR build (both graphs, rebuilt every launch) ===============
__global__ void k_count2(const int* __restrict__ d0, const int* __restrict__ d1,
                         int* __restrict__ cnt2){
  int t = blockIdx.x*256 + threadIdx.x;
  int g = blockIdx.y;
  if (t < EE) atomicAdd(&cnt2[g*NN + (g ? d1[t] : d0[t])], 1);
}

__global__ __launch_bounds__(1024) void k_scan1(const int* __restrict__ cnt2,
                                                int* __restrict__ row2, int* __restrict__ bsum){
  __shared__ int wsum[16];
  int g = blockIdx.y;
  int lane = threadIdx.x & 63, wid = threadIdx.x >> 6;
  int i = blockIdx.x*1024 + threadIdx.x;
  int v = (i < NN) ? cnt2[g*NN + i] : 0;
  int x = v;
  #pragma unroll
  for (int off = 1; off < 64; off <<= 1){
    int y = __shfl_up(x, off, 64);
    if (lane >= off) x += y;
  }
  if (lane == 63) wsum[wid] = x;
  __syncthreads();
  if (wid == 0 && lane < 16){
    int s = wsum[lane];
    #pragma unroll
    for (int off = 1; off < 16; off <<= 1){
      int y = __shfl_up(s, off, 16);
      if (lane >= off) s += y;
    }
    wsum[lane] = s;
  }
  __syncthreads();
  int incl = x + (wid ? wsum[wid-1] : 0);
  if (i < NN) row2[(size_t)g*(NN+1) + i] = incl - v;
  if (threadIdx.x == 1023) bsum[g*NB_SCAN + blockIdx.x] = incl;
}

__global__ __launch_bounds__(128) void k_scan2(const int* __restrict__ bsum, int* __restrict__ boff){
  int g = threadIdx.x >> 6, lane = threadIdx.x & 63;
  int v = (lane < NB_SCAN) ? bsum[g*NB_SCAN + lane] : 0;
  int x = v;
  #pragma unroll
  for (int off = 1; off < 64; off <<= 1){
    int y = __shfl_up(x, off, 64);
    if (lane >= off) x += y;
  }
  if (lane < NB_SCAN) boff[g*NB_SCAN + lane] = x - v;
}

__global__ __launch_bounds__(1024) void k_scan3(int* __restrict__ row2, const int* __restrict__ boff){
  int g = blockIdx.y;
  int i = blockIdx.x*1024 + threadIdx.x;
  if (i < NN) row2[(size_t)g*(NN+1) + i] += boff[g*NB_SCAN + blockIdx.x];
  if (blockIdx.x == 0 && threadIdx.x == 0) row2[(size_t)g*(NN+1) + NN] = EE;
}

// scatter: col2 (u16 src id) per CSR slot
__global__ void k_scatter2(const int* __restrict__ s0, const int* __restrict__ d0,
                           const int* __restrict__ s1, const int* __restrict__ d1,
                           const int* __restrict__ row2, int* __restrict__ fill2,
                           u16* __restrict__ col2){
  int t = blockIdx.x*256 + threadIdx.x;
  int g = blockIdx.y;
  if (t >= EE) return;
  int d = g ? d1[t] : d0[t];
  int s = g ? s1[t] : s0[t];
  int pos = atomicAdd(&fill2[g*NN + d], 1);
  col2[(size_t)g*EE + row2[(size_t)g*(NN+1) + d] + pos] = (u16)s;
}

// ---------- alpha + inv-den, H=4 (node-parallel, CSR order) ----------
__global__ void k_alphaden4(const int* __restrict__ row2, const u16* __restrict__ col2,
                            const float* __restrict__ el, const float* __restrict__ er,
                            size_t elStride, float* __restrict__ xbuf,
                            float* __restrict__ invd){
  int n = blockIdx.x*256 + threadIdx.x;
  int g = blockIdx.y;
  if (n >= NN) return;
  const int* rw = row2 + (size_t)g*(NN+1);
  const u16* cl = col2 + (size_t)g*EE;
  const float* elg = el + (size_t)g*elStride;
  float4 r4 = ((const float4*)(er + (size_t)g*elStride))[n];
  float4* xb = (float4*)xbuf + (size_t)g*EE;
  int beg = rw[n], end = rw[n+1];
  float d0=0.f,d1=0.f,d2=0.f,d3=0.f;
  for (int k=beg; k<end; k++){
    int s = cl[k];
    float4 e = ((const float4*)elg)[s];
    float4 x;
    x.x = __expf(lrelu(e.x + r4.x));
    x.y = __expf(lrelu(e.y + r4.y));
    x.z = __expf(lrelu(e.z + r4.z));
    x.w = __expf(lrelu(e.w + r4.w));
    xb[k] = x;
    d0 += x.x; d1 += x.y; d2 += x.z; d3 += x.w;
  }
  bool has = (end > beg);
  float4 iv;
  iv.x = has ? 1.f/d0 : 0.f; iv.y = has ? 1.f/d1 : 0.f;
  iv.z = has ? 1.f/d2 : 0.f; iv.w = has ? 1.f/d3 : 0.f;
  ((float4*)invd)[(size_t)g*NN + n] = iv;
}

// ---------- alpha + inv-den, H=1 (layer 2) ----------
__global__ void k_alphaden1(const int* __restrict__ row2, const u16* __restrict__ col2,
                            const float* __restrict__ el2, const float* __restrict__ er2,
                            float* __restrict__ xb2, float* __restrict__ invd1){
  int n = blockIdx.x*256 + threadIdx.x;
  int g = blockIdx.y;
  if (n >= NN) return;
  const int* rw = row2 + (size_t)g*(NN+1);
  const u16* cl = col2 + (size_t)g*EE;
  const float* elg = el2 + (size_t)g*NN;
  float ern = er2[(size_t)g*NN + n];
  float* xb = xb2 + (size_t)g*EE;
  int beg = rw[n], end = rw[n+1];
  float d = 0.f;
  for (int k=beg; k<end; k++){
    float x = __expf(lrelu(elg[cl[k]] + ern));
    xb[k] = x;
    d += x;
  }
  invd1[(size_t)g*NN + n] = (end>beg) ? 1.f/d : 0.f;
}

// ---------- input projection (MFMA): h0(N,64) = feat_t @ fc_w_t + fc_b_t -------
__global__ __launch_bounds__(256) void k_inproj_m(
    const float* __restrict__ f0, const float* __restrict__ f1,
    const u16* __restrict__ Fp, const float* __restrict__ fb0, const float* __restrict__ fb1,
    u16* __restrict__ h0)
{
  int wv = threadIdx.x>>6, ln = threadIdx.x&63;
  int ti = blockIdx.x*4 + wv;
  if (ti >= NRT) return;
  int q = ln>>4, c = ln&15;
  int type = (ti < NT0) ? 0 : 1;
  const float* F = type ? f1 : f0;
  int rbase = type ? (ti*16 - NN0) : ti*16;
  const u16* Bg = Fp + (size_t)type*8192;
  const float* bb = type ? fb1 : fb0;
  f32x4 acc[4] = {};
  const float* Ap = F + (size_t)(rbase + c)*128;
  #pragma unroll
  for (int kb=0; kb<4; kb++){
    bf16x8 a = cvt8(Ap + kb*32 + q*8);
    #pragma unroll
    for (int ct=0; ct<4; ct++){
      bf16x8 b = ld_frag(Bg + ((size_t)(ct*4+kb)*64 + ln)*8);
      acc[ct] = __builtin_amdgcn_mfma_f32_16x16x32_bf16(a, b, acc[ct], 0,0,0);
    }
  }
  #pragma unroll
  for (int ct=0; ct<4; ct++){
    float bv = bb[ct*16+c];
    #pragma unroll
    for (int j=0;j<4;j++){
      int row = ti*16 + q*4 + j;
      h0[(size_t)row*64 + ct*16 + c] = f2bf(acc[ct][j] + bv);
    }
  }
}

// ---------- layer-0 el/er: (N,64) @ Vp(64,16) ----------
__global__ __launch_bounds__(256) void k_eler0(
    const u16* __restrict__ h0, const u16* __restrict__ Vp,
    float* __restrict__ elA, float* __restrict__ erA)
{
  int wv = threadIdx.x>>6, ln = threadIdx.x&63;
  int ti = blockIdx.x*4 + wv;
  if (ti >= NRT) return;
  int q = ln>>4, c = ln&15;
  f32x4 acc = {};
  const u16* Ap = h0 + (size_t)(ti*16 + c)*64 + q*8;
  #pragma unroll
  for (int kb=0; kb<2; kb++){
    bf16x8 a = ld_frag(Ap + kb*32);
    bf16x8 b = ld_frag(Vp + ((size_t)(kb*64 + ln))*8);
    acc = __builtin_amdgcn_mfma_f32_16x16x32_bf16(a, b, acc, 0,0,0);
  }
  int which = c>>3, g = (c>>2)&1, h = c&3;
  float* dst = (which ? erA : elA) + (size_t)g*NN*4;
  #pragma unroll
  for (int j=0;j<4;j++){
    int row = ti*16 + q*4 + j;
    dst[row*4 + h] = acc[j];
  }
}

// ---------- layer 0 fused: aggregate h0 into LDS, head-GEMM + ELU + mix -> h1 --
// block = one 16-node row tile; phase 1: wave aggregates 4 nodes x 2 graphs;
// phase 2: wave wv = head wv, MFMA A from LDS (row pad 8 u16 -> 2-way = free).
__global__ __launch_bounds__(256) void k_fused0(
    const int* __restrict__ row2, const u16* __restrict__ col2,
    const float* __restrict__ xbuf, const float* __restrict__ invd,
    const u16* __restrict__ h0,
    const u16* __restrict__ W0p, const float* __restrict__ b0,
    const float* __restrict__ wsoft, u16* __restrict__ h1)
{
  __shared__ u16 hs[2][16][264];
  int wv = threadIdx.x>>6, ln = threadIdx.x&63;
  int ti = blockIdx.x;                  // 0..NRT-1
  // phase 1
  #pragma unroll
  for (int r=0; r<4; r++){
    int nl = wv*4 + r;
    int n = ti*16 + nl;
    #pragma unroll
    for (int g=0; g<2; g++){
      const int* rw = row2 + (size_t)g*(NN+1);
      const u16* cl = col2 + (size_t)g*EE;
      const float4* xb = (const float4*)xbuf + (size_t)g*EE;
      int beg = rw[n], end = rw[n+1];
      float a0=0.f,a1=0.f,a2=0.f,a3=0.f;
      int k = beg;
      for (; k+2<=end; k+=2){
        int s0 = cl[k], s1 = cl[k+1];
        float4 x0 = xb[k], x1 = xb[k+1];
        float v0 = bf2f(h0[(size_t)s0*64 + ln]);
        float v1 = bf2f(h0[(size_t)s1*64 + ln]);
        a0 += x0.x*v0 + x1.x*v1; a1 += x0.y*v0 + x1.y*v1;
        a2 += x0.z*v0 + x1.z*v1; a3 += x0.w*v0 + x1.w*v1;
      }
      for (; k<end; k++){
        int s = cl[k];
        float4 x = xb[k];
        float v = bf2f(h0[(size_t)s*64 + ln]);
        a0+=x.x*v; a1+=x.y*v; a2+=x.z*v; a3+=x.w*v;
      }
      float4 iv = ((const float4*)invd)[(size_t)g*NN + n];
      hs[g][nl][0*64+ln] = f2bf(a0*iv.x);
      hs[g][nl][1*64+ln] = f2bf(a1*iv.y);
      hs[g][nl][2*64+ln] = f2bf(a2*iv.z);
      hs[g][nl][3*64+ln] = f2bf(a3*iv.w);
    }
  }
  __syncthreads();
  // phase 2: head h = wv
  int q = ln>>4, c = ln&15;
  int h = wv;
  int type = (ti < NT0) ? 0 : 1;
  float wg0 = wsoft[type*6 + 0];
  float wg1 = wsoft[type*6 + 1];
  f32x4 acc[2][4] = {};
  #pragma unroll
  for (int g=0; g<2; g++){
    const u16* Bg = W0p + (size_t)g*16384;
    #pragma unroll
    for (int kb=0; kb<2; kb++){
      bf16x8 a = ld_frag(&hs[g][c][h*64 + kb*32 + q*8]);
      #pragma unroll
      for (int ct=0; ct<4; ct++){
        int ctg = h*4 + ct;
        bf16x8 b = ld_frag(Bg + ((size_t)(ctg*2 + kb)*64 + ln)*8);
        acc[g][ct] = __builtin_amdgcn_mfma_f32_16x16x32_bf16(a, b, acc[g][ct], 0,0,0);
      }
    }
  }
  #pragma unroll
  for (int ct=0; ct<4; ct++){
    int colg = h*64 + ct*16 + c;
    float bb0 = b0[colg], bb1 = b0[256 + colg];
    #pragma unroll
    for (int j=0;j<4;j++){
      int row = ti*16 + q*4 + j;
      float o = wg0*elu_f(acc[0][ct][j] + bb0) + wg1*elu_f(acc[1][ct][j] + bb1);
      h1[(size_t)row*256 + colg] = f2bf(o);
    }
  }
}

// ---------- MFMA GEMM, 4 row-tiles x 4 col-tiles per wave (layer 1) ------------
template<int K>
__global__ __launch_bounds__(256) void k_gemm4(
    const u16* __restrict__ A,
    const u16* __restrict__ Bp, size_t bpStride,
    const float* __restrict__ al, const float* __restrict__ ar, int alStride,
    u16* __restrict__ feat, size_t featStride,
    float* __restrict__ el, float* __restrict__ er, size_t elStride)
{
  constexpr int KB = K/32;
  int wv = threadIdx.x>>6, ln = threadIdx.x&63;
  int bid = blockIdx.x;
  int g = bid / NGRP, grp = bid % NGRP;
  int split = wv, q = ln>>4, c = ln&15;
  const u16* Bpg = Bp + (size_t)g*bpStride;
  const float* alg = al + (size_t)g*alStride;
  const float* arg = ar + (size_t)g*alStride;
  u16* featg = feat + (size_t)g*featStride;
  float* elg = el + (size_t)g*elStride;
  float* erg = er + (size_t)g*elStride;

  f32x4 acc[4][4] = {};
  int  tbase = grp*4;
  bool valid[4];
  const u16* Ap[4];
  #pragma unroll
  for (int rt=0; rt<4; rt++){
    int ti = tbase + rt;
    valid[rt] = (ti < NRT);
    if (!valid[rt]) ti = NRT-1;
    Ap[rt] = A + (size_t)(ti*16 + c)*K + q*8;
  }
  const u16* Bbase = Bpg + ((size_t)(split*4)*KB*64 + ln)*8;

  #pragma unroll 2
  for (int kb=0; kb<KB; kb++){
    bf16x8 b[4], a[4];
    #pragma unroll
    for (int ct=0; ct<4; ct++) b[ct] = ld_frag(Bbase + (size_t)(ct*KB + kb)*64*8);
    #pragma unroll
    for (int rt=0; rt<4; rt++) a[rt] = ld_frag(Ap[rt] + kb*32);
    #pragma unroll
    for (int rt=0; rt<4; rt++)
      #pragma unroll
      for (int ct=0; ct<4; ct++)
        acc[rt][ct] = __builtin_amdgcn_mfma_f32_16x16x32_bf16(a[rt], b[ct], acc[rt][ct], 0,0,0);
  }

  float alv[4], arv[4];
  #pragma unroll
  for (int ct=0;ct<4;ct++){
    int cg = (split*4+ct)*16 + c;
    alv[ct] = alg[cg]; arv[ct] = arg[cg];
  }
  #pragma unroll
  for (int rt=0; rt<4; rt++){
    if (!valid[rt]) continue;
    int row0 = (tbase+rt)*16;
    #pragma unroll
    for (int j=0;j<4;j++){
      float ep=0.f, rp=0.f;
      #pragma unroll
      for (int ct=0;ct<4;ct++){ ep += acc[rt][ct][j]*alv[ct]; rp += acc[rt][ct][j]*arv[ct]; }
      #pragma unroll
      for (int off=8; off; off>>=1){ ep += __shfl_xor(ep,off,16); rp += __shfl_xor(rp,off,16); }
      int row = row0 + q*4 + j;
      if (c==0){ elg[row*4+split]=ep; erg[row*4+split]=rp; }
      #pragma unroll
      for (int ct=0;ct<4;ct++)
        featg[(size_t)row*256 + (split*4+ct)*16 + c] = f2bf(acc[rt][ct][j]);
    }
  }
}

// ---------- fused dual-graph gather aggregation (256 cols, H=4), layer 1 -------
// alpha x precomputed; inv-den precomputed; unroll x8
template<int RES>
__global__ __launch_bounds__(256) void k_aggNF(
    const int* __restrict__ row2, const u16* __restrict__ col2,
    const float* __restrict__ xbuf, const float* __restrict__ invd,
    const u16* __restrict__ feat, size_t featStride,
    const u16* __restrict__ hres, const float* __restrict__ bias,
    const float* __restrict__ wsoft, int l,
    u16* __restrict__ hout)
{
  int wv = threadIdx.x>>6, ln = threadIdx.x&63;
  int n = blockIdx.x*4 + wv;
  int h = ln>>4;
  int type = (n<NN0)?0:1;
  float rx=0.f, ry=0.f, rz=0.f, rw_=0.f;
  if (RES){
    uint2 r = ((const uint2*)hres)[(size_t)n*64 + ln];
    rx=lo16(r.x); ry=hi16(r.x); rz=lo16(r.y); rw_=hi16(r.y);
  }
  float o0=0.f,o1=0.f,o2=0.f,o3=0.f;
  #pragma unroll
  for (int g=0; g<2; g++){
    const int* rw = row2 + (size_t)g*(NN+1);
    const u16* cl = col2 + (size_t)g*EE;
    const float* xb = xbuf + (size_t)g*EE*4;
    const uint2* fp = (const uint2*)(feat + (size_t)g*featStride);
    int beg = rw[n], end = rw[n+1];
    float a0=0.f,a1=0.f,a2=0.f,a3=0.f;
    int k = beg;
    for (; k+8<=end; k+=8){
      int s[8]; float x[8]; uint2 f[8];
      #pragma unroll
      for (int u=0; u<8; u++) s[u] = cl[k+u];
      #pragma unroll
      for (int u=0; u<8; u++) x[u] = xb[(size_t)(k+u)*4 + h];
      #pragma unroll
      for (int u=0; u<8; u++) f[u] = fp[(size_t)s[u]*64 + ln];
      #pragma unroll
      for (int u=0; u<8; u++){
        a0 += x[u]*lo16(f[u].x); a1 += x[u]*hi16(f[u].x);
        a2 += x[u]*lo16(f[u].y); a3 += x[u]*hi16(f[u].y);
      }
    }
    for (; k+4<=end; k+=4){
      int s0=cl[k], s1=cl[k+1], s2=cl[k+2], s3=cl[k+3];
      float x0 = xb[(size_t)k*4 + h];
      float x1 = xb[(size_t)(k+1)*4 + h];
      float x2 = xb[(size_t)(k+2)*4 + h];
      float x3 = xb[(size_t)(k+3)*4 + h];
      uint2 f0 = fp[(size_t)s0*64 + ln];
      uint2 f1 = fp[(size_t)s1*64 + ln];
      uint2 f2 = fp[(size_t)s2*64 + ln];
      uint2 f3 = fp[(size_t)s3*64 + ln];
      a0 += x0*lo16(f0.x) + x1*lo16(f1.x) + x2*lo16(f2.x) + x3*lo16(f3.x);
      a1 += x0*hi16(f0.x) + x1*hi16(f1.x) + x2*hi16(f2.x) + x3*hi16(f3.x);
      a2 += x0*lo16(f0.y) + x1*lo16(f1.y) + x2*lo16(f2.y) + x3*lo16(f3.y);
      a3 += x0*hi16(f0.y) + x1*hi16(f1.y) + x2*hi16(f2.y) + x3*hi16(f3.y);
    }
    for (; k<end; k++){
      int s = cl[k];
      float x = xb[(size_t)k*4 + h];
      uint2 f = fp[(size_t)s*64 + ln];
      a0 += x*lo16(f.x); a1 += x*hi16(f.x); a2 += x*lo16(f.y); a3 += x*hi16(f.y);
    }
    float inv = invd[((size_t)g*NN + n)*4 + h];
    float4 bv = ((const float4*)(bias + g*256))[ln];
    a0 = a0*inv + bv.x; a1 = a1*inv + bv.y; a2 = a2*inv + bv.z; a3 = a3*inv + bv.w;
    if (RES){ a0 += rx; a1 += ry; a2 += rz; a3 += rw_; }
    float w = wsoft[type*6 + l*2 + g];
    o0 += w*elu_f(a0); o1 += w*elu_f(a1); o2 += w*elu_f(a2); o3 += w*elu_f(a3);
  }
  uint2 o;
  o.x = (u32)f2bf(o0) | ((u32)f2bf(o1)<<16);
  o.y = (u32)f2bf(o2) | ((u32)f2bf(o3)<<16);
  ((uint2*)hout)[(size_t)n*64 + ln] = o;
}

// ---------- layer-2 MFMA: A(N,256) @ [W2_0|res2_0|W2_1|res2_1](256,64) ----------
__global__ __launch_bounds__(256) void k_gemm2(
    const u16* __restrict__ A, const u16* __restrict__ Bp,
    const float* __restrict__ al2, const float* __restrict__ ar2,
    float* __restrict__ feat16, float* __restrict__ resb,
    float* __restrict__ el2, float* __restrict__ er2)
{
  int wv = threadIdx.x>>6, ln = threadIdx.x&63;
  int wt = blockIdx.x*4 + wv;
  if (wt >= NRT) return;
  int row0 = wt*16;
  int q = ln>>4, c = ln&15;
  f32x4 acc[4] = {};
  const u16* Ap = A + (size_t)(row0 + c)*256 + q*8;
  #pragma unroll
  for (int kb=0; kb<8; kb++){
    bf16x8 a = ld_frag(Ap + kb*32);
    #pragma unroll
    for (int t=0;t<4;t++){
      bf16x8 b = ld_frag(Bp + ((size_t)(t*8 + kb)*64 + ln)*8);
      acc[t] = __builtin_amdgcn_mfma_f32_16x16x32_bf16(a, b, acc[t], 0,0,0);
    }
  }
  #pragma unroll
  for (int i=0;i<2;i++){
    float alv = al2[i*16+c], arv = ar2[i*16+c];
    #pragma unroll
    for (int j=0;j<4;j++){
      float ep = acc[2*i][j]*alv, rp = acc[2*i][j]*arv;
      #pragma unroll
      for (int off=8; off; off>>=1){ ep += __shfl_xor(ep,off,16); rp += __shfl_xor(rp,off,16); }
      if (c==0){
        int row = row0 + q*4 + j;
        el2[(size_t)i*NN + row] = ep; er2[(size_t)i*NN + row] = rp;
      }
    }
    #pragma unroll
    for (int j=0;j<4;j++){
      int row = row0 + q*4 + j;
      feat16[(size_t)i*NN*16 + (size_t)row*16 + c] = acc[2*i][j];
      resb  [(size_t)i*NN*16 + (size_t)row*16 + c] = acc[2*i+1][j];
    }
  }
}

// ---------- layer-2 dual-graph aggregation (16 cols, H=1) + final mix ----------
__global__ __launch_bounds__(256) void k_agg2D(
    const int* __restrict__ row2, const u16* __restrict__ col2,
    const float* __restrict__ xb2, const float* __restrict__ invd1,
    const float* __restrict__ feat16, const float* __restrict__ resb,
    const float* __restrict__ b2, const float* __restrict__ wsoft,
    float* __restrict__ out)
{
  int t = threadIdx.x;
  int nl = t>>4, j = t&15;
  int n = blockIdx.x*16 + nl;
  int type = (n<NN0)?0:1;
  float o = 0.f;
  #pragma unroll
  for (int i=0;i<2;i++){
    const int* rw = row2 + (size_t)i*(NN+1);
    const u16* cl = col2 + (size_t)i*EE;
    const float* xb = xb2 + (size_t)i*EE;
    const float* f  = feat16 + (size_t)i*NN*16;
    int beg = rw[n], end = rw[n+1];
    float acc = 0.f;
    int k = beg;
    for (; k+4<=end; k+=4){
      int s0=cl[k], s1=cl[k+1], s2=cl[k+2], s3=cl[k+3];
      float x0 = xb[k], x1 = xb[k+1], x2 = xb[k+2], x3 = xb[k+3];
      float v0 = f[(size_t)s0*16 + j];
      float v1 = f[(size_t)s1*16 + j];
      float v2 = f[(size_t)s2*16 + j];
      float v3 = f[(size_t)s3*16 + j];
      acc += x0*v0 + x1*v1 + x2*v2 + x3*v3;
    }
    for (; k<end; k++){
      acc = fmaf(xb[k], f[(size_t)cl[k]*16 + j], acc);
    }
    float inv = invd1[(size_t)i*NN + n];
    float oi = acc*inv + b2[i*16+j] + resb[(size_t)i*NN*16 + (size_t)n*16 + j];
    o += oi * wsoft[type*6 + 4 + i];
  }
  out[(size_t)n*16 + j] = o;
}

extern "C" void kernel_launch(void* const* d_in, const int* in_sizes, int n_in,
                              void* d_out, int out_size, void* d_ws, size_t ws_size,
                              hipStream_t stream)
{
  const float* features0 = (const float*)d_in[0];
  const float* features1 = (const float*)d_in[1];
  const float* fc_w0 = (const float*)d_in[2];
  const float* fc_b0 = (const float*)d_in[3];
  const float* fc_w1 = (const float*)d_in[4];
  const float* fc_b1 = (const float*)d_in[5];
  const float* mix_w = (const float*)d_in[6];
  const float* W0  = (const float*)d_in[7];
  const float* al0 = (const float*)d_in[8];
  const float* ar0 = (const float*)d_in[9];
  const float* b0  = (const float*)d_in[10];
  const float* W1  = (const float*)d_in[11];
  const float* al1 = (const float*)d_in[12];
  const float* ar1 = (const float*)d_in[13];
  const float* b1  = (const float*)d_in[14];
  const float* W2  = (const float*)d_in[15];
  const float* al2 = (const float*)d_in[16];
  const float* ar2 = (const float*)d_in[17];
  const float* b2  = (const float*)d_in[18];
  const float* res2= (const float*)d_in[19];
  const int* src[2] = {(const int*)d_in[20], (const int*)d_in[22]};
  const int* dst[2] = {(const int*)d_in[21], (const int*)d_in[23]};
  (void)in_sizes; (void)n_in; (void)out_size; (void)ws_size;

  char* ws = (char*)d_ws;
  size_t off = 0;
  auto alloc = [&](size_t bytes)->char*{
    char* p = ws + off; off += (bytes + 255) & ~(size_t)255; return p;
  };
  float* wsoft = (float*)alloc(64*4);
  u16*   W0p   = (u16*)  alloc((size_t)2*64*256*2);
  u16*   W1p   = (u16*)  alloc((size_t)2*256*256*2);
  u16*   W2p   = (u16*)  alloc((size_t)256*64*2);
  u16*   Fp    = (u16*)  alloc((size_t)2*128*64*2);
  u16*   Vp    = (u16*)  alloc((size_t)64*16*2);
  int*   row2  = (int*)  alloc((size_t)2*(NN+1)*4);
  u16*   col2  = (u16*)  alloc((size_t)2*EE*2);
  int*   zeros = (int*)  alloc((size_t)4*NN*4);       // cnt2 + fill2, one memset
  int*   cnt2  = zeros;
  int*   fill2 = zeros + 2*NN;
  int*   bsum  = (int*)alloc((size_t)2*NB_SCAN*4);
  int*   boff  = (int*)alloc((size_t)2*NB_SCAN*4);
  u16*   h0    = (u16*)alloc((size_t)NN*64*2);
  u16*   h1    = (u16*)alloc((size_t)NN*256*2);
  u16*   h2    = (u16*)alloc((size_t)NN*256*2);
  float* elA   = (float*)alloc((size_t)2*NN*4*4);
  float* erA   = (float*)alloc((size_t)2*NN*4*4);
  float* invd  = (float*)alloc((size_t)2*NN*4*4);     // inv-den, H=4
  float* invd1 = (float*)alloc((size_t)2*NN*4);       // inv-den, H=1
  float* xbuf  = (float*)alloc((size_t)2*EE*4*4);     // 12.8 MB, reused L0/L1/L2
  // region D (51.2 MB): layer-1 featD; layer-2 outputs alias it afterwards
  size_t featStride = (size_t)NN*256;                 // u16 elements per graph
  size_t off_D = off;
  u16* featD = (u16*)alloc(2*featStride*2);
  float* feat16 = (float*)(ws + off_D);
  float* resb   = feat16 + (size_t)2*NN*16;
  float* el2    = resb   + (size_t)2*NN*16;
  float* er2    = el2    + (size_t)2*NN;

  // 1. prep: mixw + pack all weights + V = [W0*al0 | W0*ar0]
  k_prep<<<100,256,0,stream>>>(mix_w, wsoft, W0, W0p, W1, W1p, W2, res2, W2p,
                               fc_w0, fc_w1, Fp, al0, ar0, Vp);

  // 2. CSR build, both graphs
  hipMemsetAsync(zeros, 0, (size_t)4*NN*4, stream);
  {
    dim3 gE((EE+255)/256, 2), gS(NB_SCAN, 2);
    k_count2 <<<gE,256,0,stream>>>(dst[0], dst[1], cnt2);
    k_scan1  <<<gS,1024,0,stream>>>(cnt2, row2, bsum);
    k_scan2  <<<1,128,0,stream>>>(bsum, boff);
    k_scan3  <<<gS,1024,0,stream>>>(row2, boff);
    k_scatter2<<<gE,256,0,stream>>>(src[0], dst[0], src[1], dst[1], row2, fill2, col2);
  }

  // 3. input projection (MFMA) + layer-0 el/er
  k_inproj_m<<<NGRP,256,0,stream>>>(features0, features1, Fp, fc_b0, fc_b1, h0);
  k_eler0   <<<NGRP,256,0,stream>>>(h0, Vp, elA, erA);

  dim3 gN((NN+255)/256, 2);

  // 4. layer 0: alpha+invden, fused aggregate(LDS)+head-GEMM+ELU+mix -> h1
  k_alphaden4<<<gN,256,0,stream>>>(row2, col2, elA, erA, (size_t)NN*4, xbuf, invd);
  k_fused0<<<NRT,256,0,stream>>>(row2, col2, xbuf, invd, h0, W0p, b0, wsoft, h1);

  // 5. layer 1: feat = h1 @ W1 (MFMA), alpha+invden, fused aggregation -> h2
  k_gemm4<256><<<2*NGRP,256,0,stream>>>(h1, W1p, (size_t)256*256, al1, ar1, 256,
                                        featD, featStride, elA, erA, (size_t)NN*4);
  k_alphaden4<<<gN,256,0,stream>>>(row2, col2, elA, erA, (size_t)NN*4, xbuf, invd);
  k_aggNF<1><<<NN/4,256,0,stream>>>(row2, col2, xbuf, invd, featD, featStride,
                                    h1, b1, wsoft, 1, h2);

  // 6. layer 2 (both graphs fused; outputs alias region D — feat dead here)
  k_gemm2<<<NGRP,256,0,stream>>>(h2, W2p, al2, ar2, feat16, resb, el2, er2);
  k_alphaden1<<<gN,256,0,stream>>>(row2, col2, el2, er2, xbuf, invd1);
  k_agg2D<<<NN/16,256,0,stream>>>(row2, col2, xbuf, invd1, feat16, resb, b2, wsoft, (float*)d_out);
}

// Round 10
// 458.810 us; speedup vs baseline: 1.0642x; 1.0642x over previous
//
#include <hip/hip_runtime.h>
#include <hip/hip_bf16.h>

// Problem constants (match reference)
#define NN   50000   // N0+N1
#define NN0  30000
#define EE   400000
#define NB_SCAN ((NN + 1023) / 1024)   // 49
#define NRT   3125                     // row tiles (16 rows each)
#define NGRP  ((NRT + 3) / 4)          // 782 row groups (64 rows)
#define NT0   1875                     // type-0 row tiles (30000/16, exact)

typedef unsigned short u16;
typedef unsigned int   u32;

typedef __attribute__((ext_vector_type(8))) __bf16 bf16x8;
typedef __attribute__((ext_vector_type(4))) float  f32x4;

// ---------- bf16 storage helpers (fp32 math everywhere) ----------
__device__ __forceinline__ float bf2f(u16 u){ return __uint_as_float(((u32)u)<<16); }
__device__ __forceinline__ float lo16(u32 u){ return __uint_as_float(u<<16); }
__device__ __forceinline__ float hi16(u32 u){ return __uint_as_float(u & 0xffff0000u); }
__device__ __forceinline__ u16 f2bf(float f){
  u32 x = __float_as_uint(f);
  x += 0x7fffu + ((x>>16)&1u);      // round-to-nearest-even
  return (u16)(x>>16);
}
__device__ __forceinline__ float elu_f(float x){ return x>0.f ? x : __expf(x)-1.f; }
__device__ __forceinline__ float lrelu(float x){ return x>0.f ? x : 0.2f*x; }
__device__ __forceinline__ bf16x8 ld_frag(const u16* p){
  uint4 v = *(const uint4*)p;
  return __builtin_bit_cast(bf16x8, v);
}
__device__ __forceinline__ bf16x8 cvt8(const float* p){   // 8 f32 -> bf16x8
  float4 u = ((const float4*)p)[0];
  float4 v = ((const float4*)p)[1];
  u32 w0 = (u32)f2bf(u.x) | ((u32)f2bf(u.y)<<16);
  u32 w1 = (u32)f2bf(u.z) | ((u32)f2bf(u.w)<<16);
  u32 w2 = (u32)f2bf(v.x) | ((u32)f2bf(v.y)<<16);
  u32 w3 = (u32)f2bf(v.z) | ((u32)f2bf(v.w)<<16);
  uint4 r{w0,w1,w2,w3};
  return __builtin_bit_cast(bf16x8, r);
}

// ---------- fused prep: mixw softmax + all weight packing + V = [W*al | W*ar] --
__global__ __launch_bounds__(256) void k_prep(
    const float* __restrict__ mix_w, float* __restrict__ wsoft,
    const float* __restrict__ W0, u16* __restrict__ W0p,
    const float* __restrict__ W1, u16* __restrict__ W1p,
    const float* __restrict__ W2, const float* __restrict__ res2, u16* __restrict__ W2p,
    const float* __restrict__ fcw0, const float* __restrict__ fcw1, u16* __restrict__ Fp,
    const float* __restrict__ al0, const float* __restrict__ ar0, u16* __restrict__ Vp)
{
  int t = blockIdx.x*256 + threadIdx.x;
  if (t < 6){
    float a0 = mix_w[t*2+0], a1 = mix_w[t*2+1];
    float mx = fmaxf(a0,a1);
    float e0 = __expf(a0-mx), e1 = __expf(a1-mx);
    wsoft[t*2+0] = e0/(e0+e1); wsoft[t*2+1] = e1/(e0+e1);
  }
  if (t < 4096){                    // W0: per graph 2048 frags, KB=2, NCOL=256
    int gg = t>>11, fi = t&2047;
    int lane = fi&63, kb = (fi>>6)&1, ct = fi>>7;
    int q = lane>>4, c = lane&15;
    const float* src = W0 + (size_t)gg*16384;
    u16* o = W0p + (size_t)gg*16384 + (size_t)fi*8;
    #pragma unroll
    for (int j=0;j<8;j++) o[j] = f2bf(src[(size_t)(kb*32+q*8+j)*256 + ct*16 + c]);
  } else if (t < 20480){            // W1: per graph 8192 frags, KB=8, NCOL=256
    int u = t - 4096;
    int gg = u>>13, fi = u&8191;
    int lane = fi&63, kb = (fi>>6)&7, ct = fi>>9;
    int q = lane>>4, c = lane&15;
    const float* src = W1 + (size_t)gg*65536;
    u16* o = W1p + (size_t)gg*65536 + (size_t)fi*8;
    #pragma unroll
    for (int j=0;j<8;j++) o[j] = f2bf(src[(size_t)(kb*32+q*8+j)*256 + ct*16 + c]);
  } else if (t < 22528){            // W2cat: 2048 frags, KB=8, NCOL=64
    int fi = t - 20480;
    int lane = fi&63, kb = (fi>>6)&7, ct = fi>>9;
    int q = lane>>4, c = lane&15;
    int cl = ct*16 + c;
    int i = cl>>5, which = (cl>>4)&1;
    const float* src = which ? res2 : W2;
    u16* o = W2p + (size_t)fi*8;
    #pragma unroll
    for (int j=0;j<8;j++) o[j] = f2bf(src[(size_t)i*4096 + (size_t)(kb*32+q*8+j)*16 + (cl&15)]);
  } else if (t < 24576){            // fc_w: per type 1024 frags, KB=4, NCOL=64
    int u = t - 22528;
    int tt = u>>10, fi = u&1023;
    int lane = fi&63, kb = (fi>>6)&3, ct = fi>>8;
    int q = lane>>4, c = lane&15;
    const float* src = tt ? fcw1 : fcw0;
    u16* o = Fp + (size_t)tt*8192 + (size_t)fi*8;
    #pragma unroll
    for (int j=0;j<8;j++) o[j] = f2bf(src[(size_t)(kb*32+q*8+j)*64 + ct*16 + c]);
  } else if (t < 25600){            // Vp: 64x16, KB=2; col c: which=c>>3, g=(c>>2)&1, h=c&3
    int u = t - 24576;
    int fi = u>>3, j = u&7;
    int lane = fi&63, kb = fi>>6;
    int q = lane>>4, c = lane&15;
    int k = kb*32 + q*8 + j;
    int which = c>>3, g=(c>>2)&1, h=c&3;
    const float* sel = (which ? ar0 : al0) + (size_t)(g*4+h)*64;
    const float* Wrow = W0 + (size_t)g*16384 + (size_t)k*256 + h*64;
    float s=0.f;
    #pragma unroll 8
    for (int d=0;d<64;d++) s = fmaf(Wrow[d], sel[d], s);
    Vp[(size_t)fi*8 + j] = f2bf(s);
  }
}

// ================= CSR build (both graphs, rebuilt every launch) ===============
__global__ void k_count2(const int* __restrict__ d0, const int* __restrict__ d1,
                         int* __restrict__ cnt2){
  int t = blockIdx.x*256 + threadIdx.x;
  int g = blockIdx.y;
  if (t < EE) atomicAdd(&cnt2[g*NN + (g ? d1[t] : d0[t])], 1);
}

__global__ __launch_bounds__(1024) void k_scan1(const int* __restrict__ cnt2,
                                                int* __restrict__ row2, int* __restrict__ bsum){
  __shared__ int wsum[16];
  int g = blockIdx.y;
  int lane = threadIdx.x & 63, wid = threadIdx.x >> 6;
  int i = blockIdx.x*1024 + threadIdx.x;
  int v = (i < NN) ? cnt2[g*NN + i] : 0;
  int x = v;
  #pragma unroll
  for (int off = 1; off < 64; off <<= 1){
    int y = __shfl_up(x, off, 64);
    if (lane >= off) x += y;
  }
  if (lane == 63) wsum[wid] = x;
  __syncthreads();
  if (wid == 0 && lane < 16){
    int s = wsum[lane];
    #pragma unroll
    for (int off = 1; off < 16; off <<= 1){
      int y = __shfl_up(s, off, 16);
      if (lane >= off) s += y;
    }
    wsum[lane] = s;
  }
  __syncthreads();
  int incl = x + (wid ? wsum[wid-1] : 0);
  if (i < NN) row2[(size_t)g*(NN+1) + i] = incl - v;
  if (threadIdx.x == 1023) bsum[g*NB_SCAN + blockIdx.x] = incl;
}

__global__ __launch_bounds__(128) void k_scan2(const int* __restrict__ bsum, int* __restrict__ boff){
  int g = threadIdx.x >> 6, lane = threadIdx.x & 63;
  int v = (lane < NB_SCAN) ? bsum[g*NB_SCAN + lane] : 0;
  int x = v;
  #pragma unroll
  for (int off = 1; off < 64; off <<= 1){
    int y = __shfl_up(x, off, 64);
    if (lane >= off) x += y;
  }
  if (lane < NB_SCAN) boff[g*NB_SCAN + lane] = x - v;
}

__global__ __launch_bounds__(1024) void k_scan3(int* __restrict__ row2, const int* __restrict__ boff){
  int g = blockIdx.y;
  int i = blockIdx.x*1024 + threadIdx.x;
  if (i < NN) row2[(size_t)g*(NN+1) + i] += boff[g*NB_SCAN + blockIdx.x];
  if (blockIdx.x == 0 && threadIdx.x == 0) row2[(size_t)g*(NN+1) + NN] = EE;
}

// scatter: col2 (u16 src id) + dstOf (u16 dst id) per CSR slot
__global__ void k_scatter2(const int* __restrict__ s0, const int* __restrict__ d0,
                           const int* __restrict__ s1, const int* __restrict__ d1,
                           const int* __restrict__ row2, int* __restrict__ fill2,
                           u16* __restrict__ col2, u16* __restrict__ dstOf){
  int t = blockIdx.x*256 + threadIdx.x;
  int g = blockIdx.y;
  if (t >= EE) return;
  int d = g ? d1[t] : d0[t];
  int s = g ? s1[t] : s0[t];
  int pos = atomicAdd(&fill2[g*NN + d], 1);
  size_t slot = (size_t)g*EE + row2[(size_t)g*(NN+1) + d] + pos;
  col2[slot]  = (u16)s;
  dstOf[slot] = (u16)d;
}

// ---------- alpha precompute (H=4), edge-parallel ----------
__global__ void k_alpha4(const u16* __restrict__ col2, const u16* __restrict__ dstOf,
                         const float* __restrict__ el, const float* __restrict__ er,
                         size_t elStride, float* __restrict__ xbuf){
  int t = blockIdx.x*256 + threadIdx.x;
  int g = blockIdx.y;
  if (t >= EE) return;
  size_t slot = (size_t)g*EE + t;
  int s = col2[slot], d = dstOf[slot];
  const float* elg = el + (size_t)g*elStride;
  const float* erg = er + (size_t)g*elStride;
  float4 e4 = ((const float4*)elg)[s];
  float4 r4 = ((const float4*)erg)[d];
  float4 x;
  x.x = __expf(lrelu(e4.x + r4.x));
  x.y = __expf(lrelu(e4.y + r4.y));
  x.z = __expf(lrelu(e4.z + r4.z));
  x.w = __expf(lrelu(e4.w + r4.w));
  ((float4*)xbuf)[slot] = x;
}

// ---------- alpha precompute (H=1, layer 2) ----------
__global__ void k_alpha1(const u16* __restrict__ col2, const u16* __restrict__ dstOf,
                         const float* __restrict__ el2, const float* __restrict__ er2,
                         float* __restrict__ xb2){
  int t = blockIdx.x*256 + threadIdx.x;
  int g = blockIdx.y;
  if (t >= EE) return;
  size_t slot = (size_t)g*EE + t;
  int s = col2[slot], d = dstOf[slot];
  xb2[slot] = __expf(lrelu(el2[(size_t)g*NN + s] + er2[(size_t)g*NN + d]));
}

// ---------- input projection (MFMA): h0(N,64) = feat_t @ fc_w_t + fc_b_t -------
__global__ __launch_bounds__(256) void k_inproj_m(
    const float* __restrict__ f0, const float* __restrict__ f1,
    const u16* __restrict__ Fp, const float* __restrict__ fb0, const float* __restrict__ fb1,
    u16* __restrict__ h0)
{
  int wv = threadIdx.x>>6, ln = threadIdx.x&63;
  int ti = blockIdx.x*4 + wv;
  if (ti >= NRT) return;
  int q = ln>>4, c = ln&15;
  int type = (ti < NT0) ? 0 : 1;
  const float* F = type ? f1 : f0;
  int rbase = type ? (ti*16 - NN0) : ti*16;
  const u16* Bg = Fp + (size_t)type*8192;
  const float* bb = type ? fb1 : fb0;
  f32x4 acc[4] = {};
  const float* Ap = F + (size_t)(rbase + c)*128;
  #pragma unroll
  for (int kb=0; kb<4; kb++){
    bf16x8 a = cvt8(Ap + kb*32 + q*8);
    #pragma unroll
    for (int ct=0; ct<4; ct++){
      bf16x8 b = ld_frag(Bg + ((size_t)(ct*4+kb)*64 + ln)*8);
      acc[ct] = __builtin_amdgcn_mfma_f32_16x16x32_bf16(a, b, acc[ct], 0,0,0);
    }
  }
  #pragma unroll
  for (int ct=0; ct<4; ct++){
    float bv = bb[ct*16+c];
    #pragma unroll
    for (int j=0;j<4;j++){
      int row = ti*16 + q*4 + j;
      h0[(size_t)row*64 + ct*16 + c] = f2bf(acc[ct][j] + bv);
    }
  }
}

// ---------- layer-0 el/er: (N,64) @ Vp(64,16) ----------
__global__ __launch_bounds__(256) void k_eler0(
    const u16* __restrict__ h0, const u16* __restrict__ Vp,
    float* __restrict__ elA, float* __restrict__ erA)
{
  int wv = threadIdx.x>>6, ln = threadIdx.x&63;
  int ti = blockIdx.x*4 + wv;
  if (ti >= NRT) return;
  int q = ln>>4, c = ln&15;
  f32x4 acc = {};
  const u16* Ap = h0 + (size_t)(ti*16 + c)*64 + q*8;
  #pragma unroll
  for (int kb=0; kb<2; kb++){
    bf16x8 a = ld_frag(Ap + kb*32);
    bf16x8 b = ld_frag(Vp + ((size_t)(kb*64 + ln))*8);
    acc = __builtin_amdgcn_mfma_f32_16x16x32_bf16(a, b, acc, 0,0,0);
  }
  int which = c>>3, g = (c>>2)&1, h = c&3;
  float* dst = (which ? erA : elA) + (size_t)g*NN*4;
  #pragma unroll
  for (int j=0;j<4;j++){
    int row = ti*16 + q*4 + j;
    dst[row*4 + h] = acc[j];
  }
}

// ---------- layer-0 aggregation: gather h0 (64 cols), BOTH graphs interleaved --
// wave per node; joint loop keeps 4 gathers in flight (2 per graph).
__global__ __launch_bounds__(256) void k_agg0(
    const int* __restrict__ row2, const u16* __restrict__ col2,
    const float* __restrict__ xbuf, const u16* __restrict__ h0,
    u16* __restrict__ aggB, size_t aggStride)
{
  int wv = threadIdx.x>>6, ln = threadIdx.x&63;
  int n = blockIdx.x*4 + wv;
  const int* rw0 = row2;
  const int* rw1 = row2 + (NN+1);
  const u16* cl0 = col2;
  const u16* cl1 = col2 + EE;
  const float4* xb0 = (const float4*)xbuf;
  const float4* xb1 = xb0 + EE;
  int b0_ = rw0[n], e0_ = rw0[n+1];
  int b1_ = rw1[n], e1_ = rw1[n+1];
  int k0 = b0_, k1 = b1_;
  float d00=0.f,d01=0.f,d02=0.f,d03=0.f, a00=0.f,a01=0.f,a02=0.f,a03=0.f;
  float d10=0.f,d11=0.f,d12=0.f,d13=0.f, a10=0.f,a11=0.f,a12=0.f,a13=0.f;
  while (k0+2<=e0_ && k1+2<=e1_){
    int sA=cl0[k0], sB=cl0[k0+1], sC=cl1[k1], sD=cl1[k1+1];
    float4 xA=xb0[k0], xB=xb0[k0+1], xC=xb1[k1], xD=xb1[k1+1];
    float vA=bf2f(h0[(size_t)sA*64+ln]);
    float vB=bf2f(h0[(size_t)sB*64+ln]);
    float vC=bf2f(h0[(size_t)sC*64+ln]);
    float vD=bf2f(h0[(size_t)sD*64+ln]);
    d00+=xA.x+xB.x; d01+=xA.y+xB.y; d02+=xA.z+xB.z; d03+=xA.w+xB.w;
    a00+=xA.x*vA+xB.x*vB; a01+=xA.y*vA+xB.y*vB;
    a02+=xA.z*vA+xB.z*vB; a03+=xA.w*vA+xB.w*vB;
    d10+=xC.x+xD.x; d11+=xC.y+xD.y; d12+=xC.z+xD.z; d13+=xC.w+xD.w;
    a10+=xC.x*vC+xD.x*vD; a11+=xC.y*vC+xD.y*vD;
    a12+=xC.z*vC+xD.z*vD; a13+=xC.w*vC+xD.w*vD;
    k0+=2; k1+=2;
  }
  for (; k0+2<=e0_; k0+=2){
    int sA=cl0[k0], sB=cl0[k0+1];
    float4 xA=xb0[k0], xB=xb0[k0+1];
    float vA=bf2f(h0[(size_t)sA*64+ln]);
    float vB=bf2f(h0[(size_t)sB*64+ln]);
    d00+=xA.x+xB.x; d01+=xA.y+xB.y; d02+=xA.z+xB.z; d03+=xA.w+xB.w;
    a00+=xA.x*vA+xB.x*vB; a01+=xA.y*vA+xB.y*vB;
    a02+=xA.z*vA+xB.z*vB; a03+=xA.w*vA+xB.w*vB;
  }
  for (; k0<e0_; k0++){
    int s=cl0[k0]; float4 x=xb0[k0];
    float v=bf2f(h0[(size_t)s*64+ln]);
    d00+=x.x; d01+=x.y; d02+=x.z; d03+=x.w;
    a00+=x.x*v; a01+=x.y*v; a02+=x.z*v; a03+=x.w*v;
  }
  for (; k1+2<=e1_; k1+=2){
    int sC=cl1[k1], sD=cl1[k1+1];
    float4 xC=xb1[k1], xD=xb1[k1+1];
    float vC=bf2f(h0[(size_t)sC*64+ln]);
    float vD=bf2f(h0[(size_t)sD*64+ln]);
    d10+=xC.x+xD.x; d11+=xC.y+xD.y; d12+=xC.z+xD.z; d13+=xC.w+xD.w;
    a10+=xC.x*vC+xD.x*vD; a11+=xC.y*vC+xD.y*vD;
    a12+=xC.z*vC+xD.z*vD; a13+=xC.w*vC+xD.w*vD;
  }
  for (; k1<e1_; k1++){
    int s=cl1[k1]; float4 x=xb1[k1];
    float v=bf2f(h0[(size_t)s*64+ln]);
    d10+=x.x; d11+=x.y; d12+=x.z; d13+=x.w;
    a10+=x.x*v; a11+=x.y*v; a12+=x.z*v; a13+=x.w*v;
  }
  bool hg0 = e0_ > b0_, hg1 = e1_ > b1_;
  u16* og0 = aggB + (size_t)n*256 + ln;
  og0[0]   = f2bf(hg0 ? a00/d00 : 0.f);
  og0[64]  = f2bf(hg0 ? a01/d01 : 0.f);
  og0[128] = f2bf(hg0 ? a02/d02 : 0.f);
  og0[192] = f2bf(hg0 ? a03/d03 : 0.f);
  u16* og1 = aggB + aggStride + (size_t)n*256 + ln;
  og1[0]   = f2bf(hg1 ? a10/d10 : 0.f);
  og1[64]  = f2bf(hg1 ? a11/d11 : 0.f);
  og1[128] = f2bf(hg1 ? a12/d12 : 0.f);
  og1[192] = f2bf(hg1 ? a13/d13 : 0.f);
}

// ---------- layer-0 head GEMM: ELU(agg@W0_blockdiag + b) mixed -> h1 ----------
__global__ __launch_bounds__(256) void k_head0(
    const u16* __restrict__ aggB, size_t aggStride,
    const u16* __restrict__ W0p, const float* __restrict__ b0,
    const float* __restrict__ wsoft, u16* __restrict__ h1)
{
  int wv = threadIdx.x>>6, ln = threadIdx.x&63;
  int ti = blockIdx.x*4 + wv;
  if (ti >= NRT) return;
  int q = ln>>4, c = ln&15;
  int type = (ti < NT0) ? 0 : 1;
  float wg0 = wsoft[type*6 + 0];
  float wg1 = wsoft[type*6 + 1];
  for (int h=0; h<4; h++){
    f32x4 acc[2][4] = {};
    #pragma unroll
    for (int g=0; g<2; g++){
      const u16* Ap = aggB + (size_t)g*aggStride + (size_t)(ti*16 + c)*256 + h*64 + q*8;
      const u16* Bg = W0p + (size_t)g*16384;
      #pragma unroll
      for (int kb=0; kb<2; kb++){
        bf16x8 a = ld_frag(Ap + kb*32);
        #pragma unroll
        for (int ct=0; ct<4; ct++){
          int ctg = h*4 + ct;
          bf16x8 b = ld_frag(Bg + ((size_t)(ctg*2 + kb)*64 + ln)*8);
          acc[g][ct] = __builtin_amdgcn_mfma_f32_16x16x32_bf16(a, b, acc[g][ct], 0,0,0);
        }
      }
    }
    #pragma unroll
    for (int ct=0; ct<4; ct++){
      int colg = h*64 + ct*16 + c;
      float bb0 = b0[colg], bb1 = b0[256 + colg];
      #pragma unroll
      for (int j=0;j<4;j++){
        int row = ti*16 + q*4 + j;
        float o = wg0*elu_f(acc[0][ct][j] + bb0) + wg1*elu_f(acc[1][ct][j] + bb1);
        h1[(size_t)row*256 + colg] = f2bf(o);
      }
    }
  }
}

// ---------- MFMA GEMM, 4 row-tiles x 4 col-tiles per wave (layer 1) ------------
template<int K>
__global__ __launch_bounds__(256) void k_gemm4(
    const u16* __restrict__ A,
    const u16* __restrict__ Bp, size_t bpStride,
    const float* __restrict__ al, const float* __restrict__ ar, int alStride,
    u16* __restrict__ feat, size_t featStride,
    float* __restrict__ el, float* __restrict__ er, size_t elStride)
{
  constexpr int KB = K/32;
  int wv = threadIdx.x>>6, ln = threadIdx.x&63;
  int bid = blockIdx.x;
  int g = bid / NGRP, grp = bid % NGRP;
  int split = wv, q = ln>>4, c = ln&15;
  const u16* Bpg = Bp + (size_t)g*bpStride;
  const float* alg = al + (size_t)g*alStride;
  const float* arg = ar + (size_t)g*alStride;
  u16* featg = feat + (size_t)g*featStride;
  float* elg = el + (size_t)g*elStride;
  float* erg = er + (size_t)g*elStride;

  f32x4 acc[4][4] = {};
  int  tbase = grp*4;
  bool valid[4];
  const u16* Ap[4];
  #pragma unroll
  for (int rt=0; rt<4; rt++){
    int ti = tbase + rt;
    valid[rt] = (ti < NRT);
    if (!valid[rt]) ti = NRT-1;
    Ap[rt] = A + (size_t)(ti*16 + c)*K + q*8;
  }
  const u16* Bbase = Bpg + ((size_t)(split*4)*KB*64 + ln)*8;

  #pragma unroll 2
  for (int kb=0; kb<KB; kb++){
    bf16x8 b[4], a[4];
    #pragma unroll
    for (int ct=0; ct<4; ct++) b[ct] = ld_frag(Bbase + (size_t)(ct*KB + kb)*64*8);
    #pragma unroll
    for (int rt=0; rt<4; rt++) a[rt] = ld_frag(Ap[rt] + kb*32);
    #pragma unroll
    for (int rt=0; rt<4; rt++)
      #pragma unroll
      for (int ct=0; ct<4; ct++)
        acc[rt][ct] = __builtin_amdgcn_mfma_f32_16x16x32_bf16(a[rt], b[ct], acc[rt][ct], 0,0,0);
  }

  float alv[4], arv[4];
  #pragma unroll
  for (int ct=0;ct<4;ct++){
    int cg = (split*4+ct)*16 + c;
    alv[ct] = alg[cg]; arv[ct] = arg[cg];
  }
  #pragma unroll
  for (int rt=0; rt<4; rt++){
    if (!valid[rt]) continue;
    int row0 = (tbase+rt)*16;
    #pragma unroll
    for (int j=0;j<4;j++){
      float ep=0.f, rp=0.f;
      #pragma unroll
      for (int ct=0;ct<4;ct++){ ep += acc[rt][ct][j]*alv[ct]; rp += acc[rt][ct][j]*arv[ct]; }
      #pragma unroll
      for (int off=8; off; off>>=1){ ep += __shfl_xor(ep,off,16); rp += __shfl_xor(rp,off,16); }
      int row = row0 + q*4 + j;
      if (c==0){ elg[row*4+split]=ep; erg[row*4+split]=rp; }
      #pragma unroll
      for (int ct=0;ct<4;ct++)
        featg[(size_t)row*256 + (split*4+ct)*16 + c] = f2bf(acc[rt][ct][j]);
    }
  }
}

// ---------- fused dual-graph gather aggregation (256 cols, H=4), layer 1 -------
// BOTH graphs interleaved in the joint loop: 8 feat gathers in flight per wave.
template<int RES>
__global__ __launch_bounds__(256) void k_aggNF(
    const int* __restrict__ row2, const u16* __restrict__ col2,
    const float* __restrict__ xbuf,
    const u16* __restrict__ feat, size_t featStride,
    const u16* __restrict__ hres, const float* __restrict__ bias,
    const float* __restrict__ wsoft, int l,
    u16* __restrict__ hout)
{
  int wv = threadIdx.x>>6, ln = threadIdx.x&63;
  int n = blockIdx.x*4 + wv;
  int h = ln>>4;
  int type = (n<NN0)?0:1;
  float rx=0.f, ry=0.f, rz=0.f, rw_=0.f;
  if (RES){
    uint2 r = ((const uint2*)hres)[(size_t)n*64 + ln];
    rx=lo16(r.x); ry=hi16(r.x); rz=lo16(r.y); rw_=hi16(r.y);
  }
  const int* rw0 = row2;
  const int* rw1 = row2 + (NN+1);
  const u16* cl0 = col2;
  const u16* cl1 = col2 + EE;
  const float* x0p = xbuf;
  const float* x1p = xbuf + (size_t)EE*4;
  const uint2* fp0 = (const uint2*)feat;
  const uint2* fp1 = (const uint2*)(feat + featStride);
  int b0_ = rw0[n], e0_ = rw0[n+1];
  int b1_ = rw1[n], e1_ = rw1[n+1];
  int k0 = b0_, k1 = b1_;
  float den0=0.f, A0=0.f,A1=0.f,A2=0.f,A3=0.f;
  float den1=0.f, B0=0.f,B1=0.f,B2=0.f,B3=0.f;
  while (k0+4<=e0_ && k1+4<=e1_){
    int s0=cl0[k0], s1=cl0[k0+1], s2=cl0[k0+2], s3=cl0[k0+3];
    int t0=cl1[k1], t1=cl1[k1+1], t2=cl1[k1+2], t3=cl1[k1+3];
    float x0=x0p[(size_t)k0*4+h],     x1=x0p[(size_t)(k0+1)*4+h];
    float x2=x0p[(size_t)(k0+2)*4+h], x3=x0p[(size_t)(k0+3)*4+h];
    float y0=x1p[(size_t)k1*4+h],     y1=x1p[(size_t)(k1+1)*4+h];
    float y2=x1p[(size_t)(k1+2)*4+h], y3=x1p[(size_t)(k1+3)*4+h];
    uint2 f0=fp0[(size_t)s0*64+ln], f1=fp0[(size_t)s1*64+ln];
    uint2 f2=fp0[(size_t)s2*64+ln], f3=fp0[(size_t)s3*64+ln];
    uint2 g0=fp1[(size_t)t0*64+ln], g1=fp1[(size_t)t1*64+ln];
    uint2 g2=fp1[(size_t)t2*64+ln], g3=fp1[(size_t)t3*64+ln];
    den0 += (x0+x1) + (x2+x3);
    A0 += x0*lo16(f0.x)+x1*lo16(f1.x)+x2*lo16(f2.x)+x3*lo16(f3.x);
    A1 += x0*hi16(f0.x)+x1*hi16(f1.x)+x2*hi16(f2.x)+x3*hi16(f3.x);
    A2 += x0*lo16(f0.y)+x1*lo16(f1.y)+x2*lo16(f2.y)+x3*lo16(f3.y);
    A3 += x0*hi16(f0.y)+x1*hi16(f1.y)+x2*hi16(f2.y)+x3*hi16(f3.y);
    den1 += (y0+y1) + (y2+y3);
    B0 += y0*lo16(g0.x)+y1*lo16(g1.x)+y2*lo16(g2.x)+y3*lo16(g3.x);
    B1 += y0*hi16(g0.x)+y1*hi16(g1.x)+y2*hi16(g2.x)+y3*hi16(g3.x);
    B2 += y0*lo16(g0.y)+y1*lo16(g1.y)+y2*lo16(g2.y)+y3*lo16(g3.y);
    B3 += y0*hi16(g0.y)+y1*hi16(g1.y)+y2*hi16(g2.y)+y3*hi16(g3.y);
    k0+=4; k1+=4;
  }
  for (; k0+4<=e0_; k0+=4){
    int s0=cl0[k0], s1=cl0[k0+1], s2=cl0[k0+2], s3=cl0[k0+3];
    float x0=x0p[(size_t)k0*4+h],     x1=x0p[(size_t)(k0+1)*4+h];
    float x2=x0p[(size_t)(k0+2)*4+h], x3=x0p[(size_t)(k0+3)*4+h];
    uint2 f0=fp0[(size_t)s0*64+ln], f1=fp0[(size_t)s1*64+ln];
    uint2 f2=fp0[(size_t)s2*64+ln], f3=fp0[(size_t)s3*64+ln];
    den0 += (x0+x1) + (x2+x3);
    A0 += x0*lo16(f0.x)+x1*lo16(f1.x)+x2*lo16(f2.x)+x3*lo16(f3.x);
    A1 += x0*hi16(f0.x)+x1*hi16(f1.x)+x2*hi16(f2.x)+x3*hi16(f3.x);
    A2 += x0*lo16(f0.y)+x1*lo16(f1.y)+x2*lo16(f2.y)+x3*lo16(f3.y);
    A3 += x0*hi16(f0.y)+x1*hi16(f1.y)+x2*hi16(f2.y)+x3*hi16(f3.y);
  }
  for (; k0<e0_; k0++){
    int s=cl0[k0];
    float x=x0p[(size_t)k0*4+h];
    uint2 f=fp0[(size_t)s*64+ln];
    den0 += x;
    A0 += x*lo16(f.x); A1 += x*hi16(f.x); A2 += x*lo16(f.y); A3 += x*hi16(f.y);
  }
  for (; k1+4<=e1_; k1+=4){
    int t0=cl1[k1], t1=cl1[k1+1], t2=cl1[k1+2], t3=cl1[k1+3];
    float y0=x1p[(size_t)k1*4+h],     y1=x1p[(size_t)(k1+1)*4+h];
    float y2=x1p[(size_t)(k1+2)*4+h], y3=x1p[(size_t)(k1+3)*4+h];
    uint2 g0=fp1[(size_t)t0*64+ln], g1=fp1[(size_t)t1*64+ln];
    uint2 g2=fp1[(size_t)t2*64+ln], g3=fp1[(size_t)t3*64+ln];
    den1 += (y0+y1) + (y2+y3);
    B0 += y0*lo16(g0.x)+y1*lo16(g1.x)+y2*lo16(g2.x)+y3*lo16(g3.x);
    B1 += y0*hi16(g0.x)+y1*hi16(g1.x)+y2*hi16(g2.x)+y3*hi16(g3.x);
    B2 += y0*lo16(g0.y)+y1*lo16(g1.y)+y2*lo16(g2.y)+y3*lo16(g3.y);
    B3 += y0*hi16(g0.y)+y1*hi16(g1.y)+y2*hi16(g2.y)+y3*hi16(g3.y);
  }
  for (; k1<e1_; k1++){
    int t=cl1[k1];
    float y=x1p[(size_t)k1*4+h];
    uint2 g=fp1[(size_t)t*64+ln];
    den1 += y;
    B0 += y*lo16(g.x); B1 += y*hi16(g.x); B2 += y*lo16(g.y); B3 += y*hi16(g.y);
  }
  float inv0 = (e0_>b0_) ? 1.0f/den0 : 0.f;
  float inv1 = (e1_>b1_) ? 1.0f/den1 : 0.f;
  float4 bv0 = ((const float4*)(bias))[ln];
  float4 bv1 = ((const float4*)(bias + 256))[ln];
  float w0 = wsoft[type*6 + l*2 + 0];
  float w1 = wsoft[type*6 + l*2 + 1];
  float c0 = A0*inv0 + bv0.x, c1 = A1*inv0 + bv0.y, c2 = A2*inv0 + bv0.z, c3 = A3*inv0 + bv0.w;
  float e0 = B0*inv1 + bv1.x, e1 = B1*inv1 + bv1.y, e2 = B2*inv1 + bv1.z, e3 = B3*inv1 + bv1.w;
  if (RES){ c0+=rx; c1+=ry; c2+=rz; c3+=rw_; e0+=rx; e1+=ry; e2+=rz; e3+=rw_; }
  float o0 = w0*elu_f(c0) + w1*elu_f(e0);
  float o1 = w0*elu_f(c1) + w1*elu_f(e1);
  float o2 = w0*elu_f(c2) + w1*elu_f(e2);
  float o3 = w0*elu_f(c3) + w1*elu_f(e3);
  uint2 o;
  o.x = (u32)f2bf(o0) | ((u32)f2bf(o1)<<16);
  o.y = (u32)f2bf(o2) | ((u32)f2bf(o3)<<16);
  ((uint2*)hout)[(size_t)n*64 + ln] = o;
}

// ---------- layer-2 MFMA: A(N,256) @ [W2_0|res2_0|W2_1|res2_1](256,64) ----------
__global__ __launch_bounds__(256) void k_gemm2(
    const u16* __restrict__ A, const u16* __restrict__ Bp,
    const float* __restrict__ al2, const float* __restrict__ ar2,
    float* __restrict__ feat16, float* __restrict__ resb,
    float* __restrict__ el2, float* __restrict__ er2)
{
  int wv = threadIdx.x>>6, ln = threadIdx.x&63;
  int wt = blockIdx.x*4 + wv;
  if (wt >= NRT) return;
  int row0 = wt*16;
  int q = ln>>4, c = ln&15;
  f32x4 acc[4] = {};
  const u16* Ap = A + (size_t)(row0 + c)*256 + q*8;
  #pragma unroll
  for (int kb=0; kb<8; kb++){
    bf16x8 a = ld_frag(Ap + kb*32);
    #pragma unroll
    for (int t=0;t<4;t++){
      bf16x8 b = ld_frag(Bp + ((size_t)(t*8 + kb)*64 + ln)*8);
      acc[t] = __builtin_amdgcn_mfma_f32_16x16x32_bf16(a, b, acc[t], 0,0,0);
    }
  }
  #pragma unroll
  for (int i=0;i<2;i++){
    float alv = al2[i*16+c], arv = ar2[i*16+c];
    #pragma unroll
    for (int j=0;j<4;j++){
      float ep = acc[2*i][j]*alv, rp = acc[2*i][j]*arv;
      #pragma unroll
      for (int off=8; off; off>>=1){ ep += __shfl_xor(ep,off,16); rp += __shfl_xor(rp,off,16); }
      if (c==0){
        int row = row0 + q*4 + j;
        el2[(size_t)i*NN + row] = ep; er2[(size_t)i*NN + row] = rp;
      }
    }
    #pragma unroll
    for (int j=0;j<4;j++){
      int row = row0 + q*4 + j;
      feat16[(size_t)i*NN*16 + (size_t)row*16 + c] = acc[2*i][j];
      resb  [(size_t)i*NN*16 + (size_t)row*16 + c] = acc[2*i+1][j];
    }
  }
}

// ---------- layer-2 dual-graph aggregation (16 cols, H=1) + final mix ----------
__global__ __launch_bounds__(256) void k_agg2D(
    const int* __restrict__ row2, const u16* __restrict__ col2,
    const float* __restrict__ xb2,
    const float* __restrict__ feat16, const float* __restrict__ resb,
    const float* __restrict__ b2, const float* __restrict__ wsoft,
    float* __restrict__ out)
{
  int t = threadIdx.x;
  int nl = t>>4, j = t&15;
  int n = blockIdx.x*16 + nl;
  int type = (n<NN0)?0:1;
  float o = 0.f;
  #pragma unroll
  for (int i=0;i<2;i++){
    const int* rw = row2 + (size_t)i*(NN+1);
    const u16* cl = col2 + (size_t)i*EE;
    const float* xb = xb2 + (size_t)i*EE;
    const float* f  = feat16 + (size_t)i*NN*16;
    int beg = rw[n], end = rw[n+1];
    float den = 0.f, acc = 0.f;
    int k = beg;
    for (; k+4<=end; k+=4){
      int s0=cl[k], s1=cl[k+1], s2=cl[k+2], s3=cl[k+3];
      float x0 = xb[k], x1 = xb[k+1], x2 = xb[k+2], x3 = xb[k+3];
      float v0 = f[(size_t)s0*16 + j];
      float v1 = f[(size_t)s1*16 + j];
      float v2 = f[(size_t)s2*16 + j];
      float v3 = f[(size_t)s3*16 + j];
      den += (x0+x1) + (x2+x3);
      acc += x0*v0 + x1*v1 + x2*v2 + x3*v3;
    }
    for (; k<end; k++){
      float x = xb[k];
      den += x;
      acc = fmaf(x, f[(size_t)cl[k]*16 + j], acc);
    }
    float inv = (end>beg) ? 1.0f/den : 0.f;
    float oi = acc*inv + b2[i*16+j] + resb[(size_t)i*NN*16 + (size_t)n*16 + j];
    o += oi * wsoft[type*6 + 4 + i];
  }
  out[(size_t)n*16 + j] = o;
}

extern "C" void kernel_launch(void* const* d_in, const int* in_sizes, int n_in,
                              void* d_out, int out_size, void* d_ws, size_t ws_size,
                              hipStream_t stream)
{
  const float* features0 = (const float*)d_in[0];
  const float* features1 = (const float*)d_in[1];
  const float* fc_w0 = (const float*)d_in[2];
  const float* fc_b0 = (const float*)d_in[3];
  const float* fc_w1 = (const float*)d_in[4];
  const float* fc_b1 = (const float*)d_in[5];
  const float* mix_w = (const float*)d_in[6];
  const float* W0  = (const float*)d_in[7];
  const float* al0 = (const float*)d_in[8];
  const float* ar0 = (const float*)d_in[9];
  const float* b0  = (const float*)d_in[10];
  const float* W1  = (const float*)d_in[11];
  const float* al1 = (const float*)d_in[12];
  const float* ar1 = (const float*)d_in[13];
  const float* b1  = (const float*)d_in[14];
  const float* W2  = (const float*)d_in[15];
  const float* al2 = (const float*)d_in[16];
  const float* ar2 = (const float*)d_in[17];
  const float* b2  = (const float*)d_in[18];
  const float* res2= (const float*)d_in[19];
  const int* src[2] = {(const int*)d_in[20], (const int*)d_in[22]};
  const int* dst[2] = {(const int*)d_in[21], (const int*)d_in[23]};
  (void)in_sizes; (void)n_in; (void)out_size; (void)ws_size;

  char* ws = (char*)d_ws;
  size_t off = 0;
  auto alloc = [&](size_t bytes)->char*{
    char* p = ws + off; off += (bytes + 255) & ~(size_t)255; return p;
  };
  float* wsoft = (float*)alloc(64*4);
  u16*   W0p   = (u16*)  alloc((size_t)2*64*256*2);
  u16*   W1p   = (u16*)  alloc((size_t)2*256*256*2);
  u16*   W2p   = (u16*)  alloc((size_t)256*64*2);
  u16*   Fp    = (u16*)  alloc((size_t)2*128*64*2);
  u16*   Vp    = (u16*)  alloc((size_t)64*16*2);
  int*   row2  = (int*)  alloc((size_t)2*(NN+1)*4);
  u16*   col2  = (u16*)  alloc((size_t)2*EE*2);
  u16*   dstOf = (u16*)  alloc((size_t)2*EE*2);
  int*   zeros = (int*)  alloc((size_t)4*NN*4);       // cnt2 + fill2, one memset
  int*   cnt2  = zeros;
  int*   fill2 = zeros + 2*NN;
  int*   bsum  = (int*)alloc((size_t)2*NB_SCAN*4);
  int*   boff  = (int*)alloc((size_t)2*NB_SCAN*4);
  u16*   h0    = (u16*)alloc((size_t)NN*64*2);
  u16*   h1    = (u16*)alloc((size_t)NN*256*2);
  u16*   h2    = (u16*)alloc((size_t)NN*256*2);
  float* elA   = (float*)alloc((size_t)2*NN*4*4);
  float* erA   = (float*)alloc((size_t)2*NN*4*4);
  float* xbuf  = (float*)alloc((size_t)2*EE*4*4);     // 12.8 MB, reused L0/L1/L2
  // region D (51.2 MB): layer-0 aggB -> layer-1 featD -> layer-2 outputs
  size_t featStride = (size_t)NN*256;                 // u16 elements per graph
  size_t off_D = off;
  u16* regionD = (u16*)alloc(2*featStride*2);
  u16* aggB  = regionD;
  u16* featD = regionD;
  float* feat16 = (float*)(ws + off_D);
  float* resb   = feat16 + (size_t)2*NN*16;
  float* el2    = resb   + (size_t)2*NN*16;
  float* er2    = el2    + (size_t)2*NN;

  // 1. prep: mixw + pack all weights + V = [W0*al0 | W0*ar0]
  k_prep<<<100,256,0,stream>>>(mix_w, wsoft, W0, W0p, W1, W1p, W2, res2, W2p,
                               fc_w0, fc_w1, Fp, al0, ar0, Vp);

  // 2. CSR build, both graphs
  hipMemsetAsync(zeros, 0, (size_t)4*NN*4, stream);
  {
    dim3 gEb((EE+255)/256, 2), gS(NB_SCAN, 2);
    k_count2 <<<gEb,256,0,stream>>>(dst[0], dst[1], cnt2);
    k_scan1  <<<gS,1024,0,stream>>>(cnt2, row2, bsum);
    k_scan2  <<<1,128,0,stream>>>(bsum, boff);
    k_scan3  <<<gS,1024,0,stream>>>(row2, boff);
    k_scatter2<<<gEb,256,0,stream>>>(src[0], dst[0], src[1], dst[1], row2, fill2, col2, dstOf);
  }

  // 3. input projection (MFMA) + layer-0 el/er
  k_inproj_m<<<NGRP,256,0,stream>>>(features0, features1, Fp, fc_b0, fc_b1, h0);
  k_eler0   <<<NGRP,256,0,stream>>>(h0, Vp, elA, erA);

  dim3 gE((EE+255)/256, 2);

  // 4. layer 0: alpha, interleaved dual-graph aggregate, head GEMM + ELU + mix
  k_alpha4<<<gE,256,0,stream>>>(col2, dstOf, elA, erA, (size_t)NN*4, xbuf);
  k_agg0 <<<NN/4,256,0,stream>>>(row2, col2, xbuf, h0, aggB, featStride);
  k_head0<<<NGRP,256,0,stream>>>(aggB, featStride, W0p, b0, wsoft, h1);

  // 5. layer 1: feat = h1 @ W1 (MFMA), alpha, interleaved fused aggregation -> h2
  k_gemm4<256><<<2*NGRP,256,0,stream>>>(h1, W1p, (size_t)256*256, al1, ar1, 256,
                                        featD, featStride, elA, erA, (size_t)NN*4);
  k_alpha4<<<gE,256,0,stream>>>(col2, dstOf, elA, erA, (size_t)NN*4, xbuf);
  k_aggNF<1><<<NN/4,256,0,stream>>>(row2, col2, xbuf, featD, featStride,
                                    h1, b1, wsoft, 1, h2);

  // 6. layer 2 (both graphs fused; outputs alias region D — feat dead here)
  k_gemm2<<<NGRP,256,0,stream>>>(h2, W2p, al2, ar2, feat16, resb, el2, er2);
  k_alpha1<<<gE,256,0,stream>>>(col2, dstOf, el2, er2, xbuf);
  k_agg2D<<<NN/16,256,0,stream>>>(row2, col2, xbuf, feat16, resb, b2, wsoft, (float*)d_out);
}

// Round 11
// 455.434 us; speedup vs baseline: 1.0721x; 1.0074x over previous
//
#include <hip/hip_runtime.h>
#include <hip/hip_bf16.h>

// Problem constants (match reference)
#define NN   50000   // N0+N1
#define NN0  30000
#define EE   400000
#define NB_SCAN ((NN + 1023) / 1024)   // 49
#define NRT   3125                     // row tiles (16 rows each)
#define NGRP  ((NRT + 3) / 4)          // 782 row groups (64 rows)
#define NT0   1875                     // type-0 row tiles (30000/16, exact)

typedef unsigned short u16;
typedef unsigned int   u32;

typedef __attribute__((ext_vector_type(8))) __bf16 bf16x8;
typedef __attribute__((ext_vector_type(4))) float  f32x4;

// ---------- bf16 storage helpers (fp32 math everywhere) ----------
__device__ __forceinline__ float bf2f(u16 u){ return __uint_as_float(((u32)u)<<16); }
__device__ __forceinline__ float lo16(u32 u){ return __uint_as_float(u<<16); }
__device__ __forceinline__ float hi16(u32 u){ return __uint_as_float(u & 0xffff0000u); }
__device__ __forceinline__ u16 f2bf(float f){
  u32 x = __float_as_uint(f);
  x += 0x7fffu + ((x>>16)&1u);      // round-to-nearest-even
  return (u16)(x>>16);
}
__device__ __forceinline__ float elu_f(float x){ return x>0.f ? x : __expf(x)-1.f; }
__device__ __forceinline__ float lrelu(float x){ return x>0.f ? x : 0.2f*x; }
__device__ __forceinline__ bf16x8 ld_frag(const u16* p){
  uint4 v = *(const uint4*)p;
  return __builtin_bit_cast(bf16x8, v);
}
__device__ __forceinline__ bf16x8 cvt8(const float* p){   // 8 f32 -> bf16x8
  float4 u = ((const float4*)p)[0];
  float4 v = ((const float4*)p)[1];
  u32 w0 = (u32)f2bf(u.x) | ((u32)f2bf(u.y)<<16);
  u32 w1 = (u32)f2bf(u.z) | ((u32)f2bf(u.w)<<16);
  u32 w2 = (u32)f2bf(v.x) | ((u32)f2bf(v.y)<<16);
  u32 w3 = (u32)f2bf(v.z) | ((u32)f2bf(v.w)<<16);
  uint4 r{w0,w1,w2,w3};
  return __builtin_bit_cast(bf16x8, r);
}

// ---------- prep: zero counters + mixw softmax + all weight packing ----------
__global__ __launch_bounds__(256) void k_prep(
    const float* __restrict__ mix_w, float* __restrict__ wsoft,
    const float* __restrict__ W0, u16* __restrict__ W0p,
    const float* __restrict__ W1, u16* __restrict__ W1p,
    const float* __restrict__ W2, const float* __restrict__ res2, u16* __restrict__ W2p,
    const float* __restrict__ fcw0, const float* __restrict__ fcw1, u16* __restrict__ Fp,
    int* __restrict__ zeros)
{
  int t = blockIdx.x*256 + threadIdx.x;
  for (int z = t; z < 4*NN; z += gridDim.x*256) zeros[z] = 0;
  if (t < 6){
    float a0 = mix_w[t*2+0], a1 = mix_w[t*2+1];
    float mx = fmaxf(a0,a1);
    float e0 = __expf(a0-mx), e1 = __expf(a1-mx);
    wsoft[t*2+0] = e0/(e0+e1); wsoft[t*2+1] = e1/(e0+e1);
  }
  if (t < 4096){                    // W0: per graph 2048 frags, KB=2, NCOL=256
    int gg = t>>11, fi = t&2047;
    int lane = fi&63, kb = (fi>>6)&1, ct = fi>>7;
    int q = lane>>4, c = lane&15;
    const float* src = W0 + (size_t)gg*16384;
    u16* o = W0p + (size_t)gg*16384 + (size_t)fi*8;
    #pragma unroll
    for (int j=0;j<8;j++) o[j] = f2bf(src[(size_t)(kb*32+q*8+j)*256 + ct*16 + c]);
  } else if (t < 20480){            // W1: per graph 8192 frags, KB=8, NCOL=256
    int u = t - 4096;
    int gg = u>>13, fi = u&8191;
    int lane = fi&63, kb = (fi>>6)&7, ct = fi>>9;
    int q = lane>>4, c = lane&15;
    const float* src = W1 + (size_t)gg*65536;
    u16* o = W1p + (size_t)gg*65536 + (size_t)fi*8;
    #pragma unroll
    for (int j=0;j<8;j++) o[j] = f2bf(src[(size_t)(kb*32+q*8+j)*256 + ct*16 + c]);
  } else if (t < 22528){            // W2cat: 2048 frags, KB=8, NCOL=64
    int fi = t - 20480;
    int lane = fi&63, kb = (fi>>6)&7, ct = fi>>9;
    int q = lane>>4, c = lane&15;
    int cl = ct*16 + c;
    int i = cl>>5, which = (cl>>4)&1;
    const float* src = which ? res2 : W2;
    u16* o = W2p + (size_t)fi*8;
    #pragma unroll
    for (int j=0;j<8;j++) o[j] = f2bf(src[(size_t)i*4096 + (size_t)(kb*32+q*8+j)*16 + (cl&15)]);
  } else if (t < 24576){            // fc_w: per type 1024 frags, KB=4, NCOL=64
    int u = t - 22528;
    int tt = u>>10, fi = u&1023;
    int lane = fi&63, kb = (fi>>6)&3, ct = fi>>8;
    int q = lane>>4, c = lane&15;
    const float* src = tt ? fcw1 : fcw0;
    u16* o = Fp + (size_t)tt*8192 + (size_t)fi*8;
    #pragma unroll
    for (int j=0;j<8;j++) o[j] = f2bf(src[(size_t)(kb*32+q*8+j)*64 + ct*16 + c]);
  }
}

// ---------- prep2: V2 = fc_w @ [W0*al | W0*ar] (128x16 per type) + bV ----------
// block = (type, col): col c decodes which=c>>3, g=(c>>2)&1, h=c&3
__global__ __launch_bounds__(128) void k_prep2(
    const float* __restrict__ W0,
    const float* __restrict__ al0, const float* __restrict__ ar0,
    const float* __restrict__ fcw0, const float* __restrict__ fcw1,
    const float* __restrict__ fcb0, const float* __restrict__ fcb1,
    u16* __restrict__ V2p, float* __restrict__ bV)
{
  __shared__ float V[64];
  int b = blockIdx.x;
  int tt = b>>4, cl = b&15;
  int which = cl>>3, g = (cl>>2)&1, h = cl&3;
  int t = threadIdx.x;
  const float* sel = (which ? ar0 : al0) + (size_t)(g*4+h)*64;
  if (t < 64){
    const float* Wrow = W0 + (size_t)g*16384 + (size_t)t*256 + h*64;
    float s = 0.f;
    #pragma unroll 8
    for (int d=0; d<64; d++) s = fmaf(Wrow[d], sel[d], s);
    V[t] = s;
  }
  __syncthreads();
  const float* fw = tt ? fcw1 : fcw0;   // 128 x 64
  float s = 0.f;
  #pragma unroll 8
  for (int d=0; d<64; d++) s = fmaf(fw[(size_t)t*64 + d], V[d], s);
  int kb = t>>5, q = (t>>3)&3, j = t&7;
  V2p[(size_t)tt*2048 + ((size_t)kb*64 + q*16 + cl)*8 + j] = f2bf(s);
  if (t == 0){
    const float* fbp = tt ? fcb1 : fcb0;
    float sb = 0.f;
    #pragma unroll 8
    for (int d=0; d<64; d++) sb = fmaf(fbp[d], V[d], sb);
    bV[tt*16 + cl] = sb;
  }
}

// ================= CSR build (both graphs, rebuilt every launch) ===============
__global__ void k_count2(const int* __restrict__ d0, const int* __restrict__ d1,
                         int* __restrict__ cnt2){
  int t = blockIdx.x*256 + threadIdx.x;
  int g = blockIdx.y;
  if (t < EE) atomicAdd(&cnt2[g*NN + (g ? d1[t] : d0[t])], 1);
}

__global__ __launch_bounds__(1024) void k_scan1(const int* __restrict__ cnt2,
                                                int* __restrict__ row2, int* __restrict__ bsum){
  __shared__ int wsum[16];
  int g = blockIdx.y;
  int lane = threadIdx.x & 63, wid = threadIdx.x >> 6;
  int i = blockIdx.x*1024 + threadIdx.x;
  int v = (i < NN) ? cnt2[g*NN + i] : 0;
  int x = v;
  #pragma unroll
  for (int off = 1; off < 64; off <<= 1){
    int y = __shfl_up(x, off, 64);
    if (lane >= off) x += y;
  }
  if (lane == 63) wsum[wid] = x;
  __syncthreads();
  if (wid == 0 && lane < 16){
    int s = wsum[lane];
    #pragma unroll
    for (int off = 1; off < 16; off <<= 1){
      int y = __shfl_up(s, off, 16);
      if (lane >= off) s += y;
    }
    wsum[lane] = s;
  }
  __syncthreads();
  int incl = x + (wid ? wsum[wid-1] : 0);
  if (i < NN) row2[(size_t)g*(NN+1) + i] = incl - v;
  if (threadIdx.x == 1023) bsum[g*NB_SCAN + blockIdx.x] = incl;
}

// scan3: add block offset (computed inline from bsum via one wave reduction)
__global__ __launch_bounds__(1024) void k_scan3(int* __restrict__ row2,
                                                const int* __restrict__ bsum){
  __shared__ int base;
  int g = blockIdx.y;
  if (threadIdx.x < 64){
    int lane = threadIdx.x;
    int v = (lane < (int)blockIdx.x) ? bsum[g*NB_SCAN + lane] : 0;
    #pragma unroll
    for (int off = 32; off; off >>= 1) v += __shfl_xor(v, off, 64);
    if (lane == 0) base = v;
  }
  __syncthreads();
  int i = blockIdx.x*1024 + threadIdx.x;
  if (i < NN) row2[(size_t)g*(NN+1) + i] += base;
  if (blockIdx.x == 0 && threadIdx.x == 0) row2[(size_t)g*(NN+1) + NN] = EE;
}

// scatter: col2 (u16 src id) + dstOf (u16 dst id) per CSR slot
__global__ void k_scatter2(const int* __restrict__ s0, const int* __restrict__ d0,
                           const int* __restrict__ s1, const int* __restrict__ d1,
                           const int* __restrict__ row2, int* __restrict__ fill2,
                           u16* __restrict__ col2, u16* __restrict__ dstOf){
  int t = blockIdx.x*256 + threadIdx.x;
  int g = blockIdx.y;
  if (t >= EE) return;
  int d = g ? d1[t] : d0[t];
  int s = g ? s1[t] : s0[t];
  int pos = atomicAdd(&fill2[g*NN + d], 1);
  size_t slot = (size_t)g*EE + row2[(size_t)g*(NN+1) + d] + pos;
  col2[slot]  = (u16)s;
  dstOf[slot] = (u16)d;
}

// ---------- alpha precompute (H=4), edge-parallel ----------
__global__ void k_alpha4(const u16* __restrict__ col2, const u16* __restrict__ dstOf,
                         const float* __restrict__ el, const float* __restrict__ er,
                         size_t elStride, float* __restrict__ xbuf){
  int t = blockIdx.x*256 + threadIdx.x;
  int g = blockIdx.y;
  if (t >= EE) return;
  size_t slot = (size_t)g*EE + t;
  int s = col2[slot], d = dstOf[slot];
  const float* elg = el + (size_t)g*elStride;
  const float* erg = er + (size_t)g*elStride;
  float4 e4 = ((const float4*)elg)[s];
  float4 r4 = ((const float4*)erg)[d];
  float4 x;
  x.x = __expf(lrelu(e4.x + r4.x));
  x.y = __expf(lrelu(e4.y + r4.y));
  x.z = __expf(lrelu(e4.z + r4.z));
  x.w = __expf(lrelu(e4.w + r4.w));
  ((float4*)xbuf)[slot] = x;
}

// ---------- input projection (MFMA) + fused layer-0 el/er ----------
// h0 = feats @ fc_w + fc_b;  el/er = feats @ V2 + bV  (V2 = fc_w @ [W0*al|W0*ar])
__global__ __launch_bounds__(256) void k_inproj_m(
    const float* __restrict__ f0, const float* __restrict__ f1,
    const u16* __restrict__ Fp, const float* __restrict__ fb0, const float* __restrict__ fb1,
    const u16* __restrict__ V2p, const float* __restrict__ bV,
    u16* __restrict__ h0, float* __restrict__ elA, float* __restrict__ erA)
{
  int wv = threadIdx.x>>6, ln = threadIdx.x&63;
  int ti = blockIdx.x*4 + wv;
  if (ti >= NRT) return;
  int q = ln>>4, c = ln&15;
  int type = (ti < NT0) ? 0 : 1;
  const float* F = type ? f1 : f0;
  int rbase = type ? (ti*16 - NN0) : ti*16;
  const u16* Bg = Fp + (size_t)type*8192;
  const u16* Vg = V2p + (size_t)type*2048;
  const float* bb = type ? fb1 : fb0;
  f32x4 acc[4] = {};
  f32x4 accE = {};
  const float* Ap = F + (size_t)(rbase + c)*128;
  #pragma unroll
  for (int kb=0; kb<4; kb++){
    bf16x8 a = cvt8(Ap + kb*32 + q*8);
    #pragma unroll
    for (int ct=0; ct<4; ct++){
      bf16x8 b = ld_frag(Bg + ((size_t)(ct*4+kb)*64 + ln)*8);
      acc[ct] = __builtin_amdgcn_mfma_f32_16x16x32_bf16(a, b, acc[ct], 0,0,0);
    }
    bf16x8 bv_ = ld_frag(Vg + ((size_t)kb*64 + ln)*8);
    accE = __builtin_amdgcn_mfma_f32_16x16x32_bf16(a, bv_, accE, 0,0,0);
  }
  #pragma unroll
  for (int ct=0; ct<4; ct++){
    float bvs = bb[ct*16+c];
    #pragma unroll
    for (int j=0;j<4;j++){
      int row = ti*16 + q*4 + j;
      h0[(size_t)row*64 + ct*16 + c] = f2bf(acc[ct][j] + bvs);
    }
  }
  // el/er epilogue: col c -> which=c>>3, g=(c>>2)&1, h=c&3
  int which = c>>3, gg = (c>>2)&1, hh = c&3;
  float bVv = bV[type*16 + c];
  float* dst = (which ? erA : elA) + (size_t)gg*NN*4;
  #pragma unroll
  for (int j=0;j<4;j++){
    int row = ti*16 + q*4 + j;
    dst[row*4 + hh] = accE[j] + bVv;
  }
}

// ---------- layer-0 aggregation: gather h0 (64 cols), BOTH graphs interleaved --
__global__ __launch_bounds__(256) void k_agg0(
    const int* __restrict__ row2, const u16* __restrict__ col2,
    const float* __restrict__ xbuf, const u16* __restrict__ h0,
    u16* __restrict__ aggB, size_t aggStride)
{
  int wv = threadIdx.x>>6, ln = threadIdx.x&63;
  int n = blockIdx.x*4 + wv;
  const int* rw0 = row2;
  const int* rw1 = row2 + (NN+1);
  const u16* cl0 = col2;
  const u16* cl1 = col2 + EE;
  const float4* xb0 = (const float4*)xbuf;
  const float4* xb1 = xb0 + EE;
  int b0_ = rw0[n], e0_ = rw0[n+1];
  int b1_ = rw1[n], e1_ = rw1[n+1];
  int k0 = b0_, k1 = b1_;
  float d00=0.f,d01=0.f,d02=0.f,d03=0.f, a00=0.f,a01=0.f,a02=0.f,a03=0.f;
  float d10=0.f,d11=0.f,d12=0.f,d13=0.f, a10=0.f,a11=0.f,a12=0.f,a13=0.f;
  while (k0+2<=e0_ && k1+2<=e1_){
    int sA=cl0[k0], sB=cl0[k0+1], sC=cl1[k1], sD=cl1[k1+1];
    float4 xA=xb0[k0], xB=xb0[k0+1], xC=xb1[k1], xD=xb1[k1+1];
    float vA=bf2f(h0[(size_t)sA*64+ln]);
    float vB=bf2f(h0[(size_t)sB*64+ln]);
    float vC=bf2f(h0[(size_t)sC*64+ln]);
    float vD=bf2f(h0[(size_t)sD*64+ln]);
    d00+=xA.x+xB.x; d01+=xA.y+xB.y; d02+=xA.z+xB.z; d03+=xA.w+xB.w;
    a00+=xA.x*vA+xB.x*vB; a01+=xA.y*vA+xB.y*vB;
    a02+=xA.z*vA+xB.z*vB; a03+=xA.w*vA+xB.w*vB;
    d10+=xC.x+xD.x; d11+=xC.y+xD.y; d12+=xC.z+xD.z; d13+=xC.w+xD.w;
    a10+=xC.x*vC+xD.x*vD; a11+=xC.y*vC+xD.y*vD;
    a12+=xC.z*vC+xD.z*vD; a13+=xC.w*vC+xD.w*vD;
    k0+=2; k1+=2;
  }
  for (; k0+2<=e0_; k0+=2){
    int sA=cl0[k0], sB=cl0[k0+1];
    float4 xA=xb0[k0], xB=xb0[k0+1];
    float vA=bf2f(h0[(size_t)sA*64+ln]);
    float vB=bf2f(h0[(size_t)sB*64+ln]);
    d00+=xA.x+xB.x; d01+=xA.y+xB.y; d02+=xA.z+xB.z; d03+=xA.w+xB.w;
    a00+=xA.x*vA+xB.x*vB; a01+=xA.y*vA+xB.y*vB;
    a02+=xA.z*vA+xB.z*vB; a03+=xA.w*vA+xB.w*vB;
  }
  for (; k0<e0_; k0++){
    int s=cl0[k0]; float4 x=xb0[k0];
    float v=bf2f(h0[(size_t)s*64+ln]);
    d00+=x.x; d01+=x.y; d02+=x.z; d03+=x.w;
    a00+=x.x*v; a01+=x.y*v; a02+=x.z*v; a03+=x.w*v;
  }
  for (; k1+2<=e1_; k1+=2){
    int sC=cl1[k1], sD=cl1[k1+1];
    float4 xC=xb1[k1], xD=xb1[k1+1];
    float vC=bf2f(h0[(size_t)sC*64+ln]);
    float vD=bf2f(h0[(size_t)sD*64+ln]);
    d10+=xC.x+xD.x; d11+=xC.y+xD.y; d12+=xC.z+xD.z; d13+=xC.w+xD.w;
    a10+=xC.x*vC+xD.x*vD; a11+=xC.y*vC+xD.y*vD;
    a12+=xC.z*vC+xD.z*vD; a13+=xC.w*vC+xD.w*vD;
  }
  for (; k1<e1_; k1++){
    int s=cl1[k1]; float4 x=xb1[k1];
    float v=bf2f(h0[(size_t)s*64+ln]);
    d10+=x.x; d11+=x.y; d12+=x.z; d13+=x.w;
    a10+=x.x*v; a11+=x.y*v; a12+=x.z*v; a13+=x.w*v;
  }
  bool hg0 = e0_ > b0_, hg1 = e1_ > b1_;
  u16* og0 = aggB + (size_t)n*256 + ln;
  og0[0]   = f2bf(hg0 ? a00/d00 : 0.f);
  og0[64]  = f2bf(hg0 ? a01/d01 : 0.f);
  og0[128] = f2bf(hg0 ? a02/d02 : 0.f);
  og0[192] = f2bf(hg0 ? a03/d03 : 0.f);
  u16* og1 = aggB + aggStride + (size_t)n*256 + ln;
  og1[0]   = f2bf(hg1 ? a10/d10 : 0.f);
  og1[64]  = f2bf(hg1 ? a11/d11 : 0.f);
  og1[128] = f2bf(hg1 ? a12/d12 : 0.f);
  og1[192] = f2bf(hg1 ? a13/d13 : 0.f);
}

// ---------- layer-0 head GEMM: ELU(agg@W0_blockdiag + b) mixed -> h1 ----------
__global__ __launch_bounds__(256) void k_head0(
    const u16* __restrict__ aggB, size_t aggStride,
    const u16* __restrict__ W0p, const float* __restrict__ b0,
    const float* __restrict__ wsoft, u16* __restrict__ h1)
{
  int wv = threadIdx.x>>6, ln = threadIdx.x&63;
  int ti = blockIdx.x*4 + wv;
  if (ti >= NRT) return;
  int q = ln>>4, c = ln&15;
  int type = (ti < NT0) ? 0 : 1;
  float wg0 = wsoft[type*6 + 0];
  float wg1 = wsoft[type*6 + 1];
  for (int h=0; h<4; h++){
    f32x4 acc[2][4] = {};
    #pragma unroll
    for (int g=0; g<2; g++){
      const u16* Ap = aggB + (size_t)g*aggStride + (size_t)(ti*16 + c)*256 + h*64 + q*8;
      const u16* Bg = W0p + (size_t)g*16384;
      #pragma unroll
      for (int kb=0; kb<2; kb++){
        bf16x8 a = ld_frag(Ap + kb*32);
        #pragma unroll
        for (int ct=0; ct<4; ct++){
          int ctg = h*4 + ct;
          bf16x8 b = ld_frag(Bg + ((size_t)(ctg*2 + kb)*64 + ln)*8);
          acc[g][ct] = __builtin_amdgcn_mfma_f32_16x16x32_bf16(a, b, acc[g][ct], 0,0,0);
        }
      }
    }
    #pragma unroll
    for (int ct=0; ct<4; ct++){
      int colg = h*64 + ct*16 + c;
      float bb0 = b0[colg], bb1 = b0[256 + colg];
      #pragma unroll
      for (int j=0;j<4;j++){
        int row = ti*16 + q*4 + j;
        float o = wg0*elu_f(acc[0][ct][j] + bb0) + wg1*elu_f(acc[1][ct][j] + bb1);
        h1[(size_t)row*256 + colg] = f2bf(o);
      }
    }
  }
}

// ---------- MFMA GEMM, 4 row-tiles x 4 col-tiles per wave (layer 1) ------------
template<int K>
__global__ __launch_bounds__(256) void k_gemm4(
    const u16* __restrict__ A,
    const u16* __restrict__ Bp, size_t bpStride,
    const float* __restrict__ al, const float* __restrict__ ar, int alStride,
    u16* __restrict__ feat, size_t featStride,
    float* __restrict__ el, float* __restrict__ er, size_t elStride)
{
  constexpr int KB = K/32;
  int wv = threadIdx.x>>6, ln = threadIdx.x&63;
  int bid = blockIdx.x;
  int g = bid / NGRP, grp = bid % NGRP;
  int split = wv, q = ln>>4, c = ln&15;
  const u16* Bpg = Bp + (size_t)g*bpStride;
  const float* alg = al + (size_t)g*alStride;
  const float* arg = ar + (size_t)g*alStride;
  u16* featg = feat + (size_t)g*featStride;
  float* elg = el + (size_t)g*elStride;
  float* erg = er + (size_t)g*elStride;

  f32x4 acc[4][4] = {};
  int  tbase = grp*4;
  bool valid[4];
  const u16* Ap[4];
  #pragma unroll
  for (int rt=0; rt<4; rt++){
    int ti = tbase + rt;
    valid[rt] = (ti < NRT);
    if (!valid[rt]) ti = NRT-1;
    Ap[rt] = A + (size_t)(ti*16 + c)*K + q*8;
  }
  const u16* Bbase = Bpg + ((size_t)(split*4)*KB*64 + ln)*8;

  #pragma unroll 2
  for (int kb=0; kb<KB; kb++){
    bf16x8 b[4], a[4];
    #pragma unroll
    for (int ct=0; ct<4; ct++) b[ct] = ld_frag(Bbase + (size_t)(ct*KB + kb)*64*8);
    #pragma unroll
    for (int rt=0; rt<4; rt++) a[rt] = ld_frag(Ap[rt] + kb*32);
    #pragma unroll
    for (int rt=0; rt<4; rt++)
      #pragma unroll
      for (int ct=0; ct<4; ct++)
        acc[rt][ct] = __builtin_amdgcn_mfma_f32_16x16x32_bf16(a[rt], b[ct], acc[rt][ct], 0,0,0);
  }

  float alv[4], arv[4];
  #pragma unroll
  for (int ct=0;ct<4;ct++){
    int cg = (split*4+ct)*16 + c;
    alv[ct] = alg[cg]; arv[ct] = arg[cg];
  }
  #pragma unroll
  for (int rt=0; rt<4; rt++){
    if (!valid[rt]) continue;
    int row0 = (tbase+rt)*16;
    #pragma unroll
    for (int j=0;j<4;j++){
      float ep=0.f, rp=0.f;
      #pragma unroll
      for (int ct=0;ct<4;ct++){ ep += acc[rt][ct][j]*alv[ct]; rp += acc[rt][ct][j]*arv[ct]; }
      #pragma unroll
      for (int off=8; off; off>>=1){ ep += __shfl_xor(ep,off,16); rp += __shfl_xor(rp,off,16); }
      int row = row0 + q*4 + j;
      if (c==0){ elg[row*4+split]=ep; erg[row*4+split]=rp; }
      #pragma unroll
      for (int ct=0;ct<4;ct++)
        featg[(size_t)row*256 + (split*4+ct)*16 + c] = f2bf(acc[rt][ct][j]);
    }
  }
}

// ---------- fused dual-graph gather aggregation (256 cols, H=4), layer 1 -------
template<int RES>
__global__ __launch_bounds__(256) void k_aggNF(
    const int* __restrict__ row2, const u16* __restrict__ col2,
    const float* __restrict__ xbuf,
    const u16* __restrict__ feat, size_t featStride,
    const u16* __restrict__ hres, const float* __restrict__ bias,
    const float* __restrict__ wsoft, int l,
    u16* __restrict__ hout)
{
  int wv = threadIdx.x>>6, ln = threadIdx.x&63;
  int n = blockIdx.x*4 + wv;
  int h = ln>>4;
  int type = (n<NN0)?0:1;
  float rx=0.f, ry=0.f, rz=0.f, rw_=0.f;
  if (RES){
    uint2 r = ((const uint2*)hres)[(size_t)n*64 + ln];
    rx=lo16(r.x); ry=hi16(r.x); rz=lo16(r.y); rw_=hi16(r.y);
  }
  const int* rw0 = row2;
  const int* rw1 = row2 + (NN+1);
  const u16* cl0 = col2;
  const u16* cl1 = col2 + EE;
  const float* x0p = xbuf;
  const float* x1p = xbuf + (size_t)EE*4;
  const uint2* fp0 = (const uint2*)feat;
  const uint2* fp1 = (const uint2*)(feat + featStride);
  int b0_ = rw0[n], e0_ = rw0[n+1];
  int b1_ = rw1[n], e1_ = rw1[n+1];
  int k0 = b0_, k1 = b1_;
  float den0=0.f, A0=0.f,A1=0.f,A2=0.f,A3=0.f;
  float den1=0.f, B0=0.f,B1=0.f,B2=0.f,B3=0.f;
  while (k0+4<=e0_ && k1+4<=e1_){
    int s0=cl0[k0], s1=cl0[k0+1], s2=cl0[k0+2], s3=cl0[k0+3];
    int t0=cl1[k1], t1=cl1[k1+1], t2=cl1[k1+2], t3=cl1[k1+3];
    float x0=x0p[(size_t)k0*4+h],     x1=x0p[(size_t)(k0+1)*4+h];
    float x2=x0p[(size_t)(k0+2)*4+h], x3=x0p[(size_t)(k0+3)*4+h];
    float y0=x1p[(size_t)k1*4+h],     y1=x1p[(size_t)(k1+1)*4+h];
    float y2=x1p[(size_t)(k1+2)*4+h], y3=x1p[(size_t)(k1+3)*4+h];
    uint2 f0=fp0[(size_t)s0*64+ln], f1=fp0[(size_t)s1*64+ln];
    uint2 f2=fp0[(size_t)s2*64+ln], f3=fp0[(size_t)s3*64+ln];
    uint2 g0=fp1[(size_t)t0*64+ln], g1=fp1[(size_t)t1*64+ln];
    uint2 g2=fp1[(size_t)t2*64+ln], g3=fp1[(size_t)t3*64+ln];
    den0 += (x0+x1) + (x2+x3);
    A0 += x0*lo16(f0.x)+x1*lo16(f1.x)+x2*lo16(f2.x)+x3*lo16(f3.x);
    A1 += x0*hi16(f0.x)+x1*hi16(f1.x)+x2*hi16(f2.x)+x3*hi16(f3.x);
    A2 += x0*lo16(f0.y)+x1*lo16(f1.y)+x2*lo16(f2.y)+x3*lo16(f3.y);
    A3 += x0*hi16(f0.y)+x1*hi16(f1.y)+x2*hi16(f2.y)+x3*hi16(f3.y);
    den1 += (y0+y1) + (y2+y3);
    B0 += y0*lo16(g0.x)+y1*lo16(g1.x)+y2*lo16(g2.x)+y3*lo16(g3.x);
    B1 += y0*hi16(g0.x)+y1*hi16(g1.x)+y2*hi16(g2.x)+y3*hi16(g3.x);
    B2 += y0*lo16(g0.y)+y1*lo16(g1.y)+y2*lo16(g2.y)+y3*lo16(g3.y);
    B3 += y0*hi16(g0.y)+y1*hi16(g1.y)+y2*hi16(g2.y)+y3*hi16(g3.y);
    k0+=4; k1+=4;
  }
  for (; k0+4<=e0_; k0+=4){
    int s0=cl0[k0], s1=cl0[k0+1], s2=cl0[k0+2], s3=cl0[k0+3];
    float x0=x0p[(size_t)k0*4+h],     x1=x0p[(size_t)(k0+1)*4+h];
    float x2=x0p[(size_t)(k0+2)*4+h], x3=x0p[(size_t)(k0+3)*4+h];
    uint2 f0=fp0[(size_t)s0*64+ln], f1=fp0[(size_t)s1*64+ln];
    uint2 f2=fp0[(size_t)s2*64+ln], f3=fp0[(size_t)s3*64+ln];
    den0 += (x0+x1) + (x2+x3);
    A0 += x0*lo16(f0.x)+x1*lo16(f1.x)+x2*lo16(f2.x)+x3*lo16(f3.x);
    A1 += x0*hi16(f0.x)+x1*hi16(f1.x)+x2*hi16(f2.x)+x3*hi16(f3.x);
    A2 += x0*lo16(f0.y)+x1*lo16(f1.y)+x2*lo16(f2.y)+x3*lo16(f3.y);
    A3 += x0*hi16(f0.y)+x1*hi16(f1.y)+x2*hi16(f2.y)+x3*hi16(f3.y);
  }
  for (; k0<e0_; k0++){
    int s=cl0[k0];
    float x=x0p[(size_t)k0*4+h];
    uint2 f=fp0[(size_t)s*64+ln];
    den0 += x;
    A0 += x*lo16(f.x); A1 += x*hi16(f.x); A2 += x*lo16(f.y); A3 += x*hi16(f.y);
  }
  for (; k1+4<=e1_; k1+=4){
    int t0=cl1[k1], t1=cl1[k1+1], t2=cl1[k1+2], t3=cl1[k1+3];
    float y0=x1p[(size_t)k1*4+h],     y1=x1p[(size_t)(k1+1)*4+h];
    float y2=x1p[(size_t)(k1+2)*4+h], y3=x1p[(size_t)(k1+3)*4+h];
    uint2 g0=fp1[(size_t)t0*64+ln], g1=fp1[(size_t)t1*64+ln];
    uint2 g2=fp1[(size_t)t2*64+ln], g3=fp1[(size_t)t3*64+ln];
    den1 += (y0+y1) + (y2+y3);
    B0 += y0*lo16(g0.x)+y1*lo16(g1.x)+y2*lo16(g2.x)+y3*lo16(g3.x);
    B1 += y0*hi16(g0.x)+y1*hi16(g1.x)+y2*hi16(g2.x)+y3*hi16(g3.x);
    B2 += y0*lo16(g0.y)+y1*lo16(g1.y)+y2*lo16(g2.y)+y3*lo16(g3.y);
    B3 += y0*hi16(g0.y)+y1*hi16(g1.y)+y2*hi16(g2.y)+y3*hi16(g3.y);
  }
  for (; k1<e1_; k1++){
    int t=cl1[k1];
    float y=x1p[(size_t)k1*4+h];
    uint2 g=fp1[(size_t)t*64+ln];
    den1 += y;
    B0 += y*lo16(g.x); B1 += y*hi16(g.x); B2 += y*lo16(g.y); B3 += y*hi16(g.y);
  }
  float inv0 = (e0_>b0_) ? 1.0f/den0 : 0.f;
  float inv1 = (e1_>b1_) ? 1.0f/den1 : 0.f;
  float4 bv0 = ((const float4*)(bias))[ln];
  float4 bv1 = ((const float4*)(bias + 256))[ln];
  float w0 = wsoft[type*6 + l*2 + 0];
  float w1 = wsoft[type*6 + l*2 + 1];
  float c0 = A0*inv0 + bv0.x, c1 = A1*inv0 + bv0.y, c2 = A2*inv0 + bv0.z, c3 = A3*inv0 + bv0.w;
  float e0 = B0*inv1 + bv1.x, e1 = B1*inv1 + bv1.y, e2 = B2*inv1 + bv1.z, e3 = B3*inv1 + bv1.w;
  if (RES){ c0+=rx; c1+=ry; c2+=rz; c3+=rw_; e0+=rx; e1+=ry; e2+=rz; e3+=rw_; }
  float o0 = w0*elu_f(c0) + w1*elu_f(e0);
  float o1 = w0*elu_f(c1) + w1*elu_f(e1);
  float o2 = w0*elu_f(c2) + w1*elu_f(e2);
  float o3 = w0*elu_f(c3) + w1*elu_f(e3);
  uint2 o;
  o.x = (u32)f2bf(o0) | ((u32)f2bf(o1)<<16);
  o.y = (u32)f2bf(o2) | ((u32)f2bf(o3)<<16);
  ((uint2*)hout)[(size_t)n*64 + ln] = o;
}

// ---------- layer-2 MFMA: A(N,256) @ [W2_0|res2_0|W2_1|res2_1](256,64) ----------
__global__ __launch_bounds__(256) void k_gemm2(
    const u16* __restrict__ A, const u16* __restrict__ Bp,
    const float* __restrict__ al2, const float* __restrict__ ar2,
    float* __restrict__ feat16, float* __restrict__ resb,
    float* __restrict__ el2, float* __restrict__ er2)
{
  int wv = threadIdx.x>>6, ln = threadIdx.x&63;
  int wt = blockIdx.x*4 + wv;
  if (wt >= NRT) return;
  int row0 = wt*16;
  int q = ln>>4, c = ln&15;
  f32x4 acc[4] = {};
  const u16* Ap = A + (size_t)(row0 + c)*256 + q*8;
  #pragma unroll
  for (int kb=0; kb<8; kb++){
    bf16x8 a = ld_frag(Ap + kb*32);
    #pragma unroll
    for (int t=0;t<4;t++){
      bf16x8 b = ld_frag(Bp + ((size_t)(t*8 + kb)*64 + ln)*8);
      acc[t] = __builtin_amdgcn_mfma_f32_16x16x32_bf16(a, b, acc[t], 0,0,0);
    }
  }
  #pragma unroll
  for (int i=0;i<2;i++){
    float alv = al2[i*16+c], arv = ar2[i*16+c];
    #pragma unroll
    for (int j=0;j<4;j++){
      float ep = acc[2*i][j]*alv, rp = acc[2*i][j]*arv;
      #pragma unroll
      for (int off=8; off; off>>=1){ ep += __shfl_xor(ep,off,16); rp += __shfl_xor(rp,off,16); }
      if (c==0){
        int row = row0 + q*4 + j;
        el2[(size_t)i*NN + row] = ep; er2[(size_t)i*NN + row] = rp;
      }
    }
    #pragma unroll
    for (int j=0;j<4;j++){
      int row = row0 + q*4 + j;
      feat16[(size_t)i*NN*16 + (size_t)row*16 + c] = acc[2*i][j];
      resb  [(size_t)i*NN*16 + (size_t)row*16 + c] = acc[2*i+1][j];
    }
  }
}

// ---------- layer-2 dual-graph aggregation + inline alpha + final mix ----------
__global__ __launch_bounds__(256) void k_agg2D(
    const int* __restrict__ row2, const u16* __restrict__ col2,
    const float* __restrict__ el2, const float* __restrict__ er2,
    const float* __restrict__ feat16, const float* __restrict__ resb,
    const float* __restrict__ b2, const float* __restrict__ wsoft,
    float* __restrict__ out)
{
  int t = threadIdx.x;
  int nl = t>>4, j = t&15;
  int n = blockIdx.x*16 + nl;
  int type = (n<NN0)?0:1;
  float o = 0.f;
  #pragma unroll
  for (int i=0;i<2;i++){
    const int* rw = row2 + (size_t)i*(NN+1);
    const u16* cl = col2 + (size_t)i*EE;
    const float* elg = el2 + (size_t)i*NN;
    float ern = er2[(size_t)i*NN + n];
    const float* f  = feat16 + (size_t)i*NN*16;
    int beg = rw[n], end = rw[n+1];
    float den = 0.f, acc = 0.f;
    int k = beg;
    for (; k+4<=end; k+=4){
      int s0=cl[k], s1=cl[k+1], s2=cl[k+2], s3=cl[k+3];
      float x0 = __expf(lrelu(elg[s0] + ern));
      float x1 = __expf(lrelu(elg[s1] + ern));
      float x2 = __expf(lrelu(elg[s2] + ern));
      float x3 = __expf(lrelu(elg[s3] + ern));
      float v0 = f[(size_t)s0*16 + j];
      float v1 = f[(size_t)s1*16 + j];
      float v2 = f[(size_t)s2*16 + j];
      float v3 = f[(size_t)s3*16 + j];
      den += (x0+x1) + (x2+x3);
      acc += x0*v0 + x1*v1 + x2*v2 + x3*v3;
    }
    for (; k<end; k++){
      int s = cl[k];
      float x = __expf(lrelu(elg[s] + ern));
      den += x;
      acc = fmaf(x, f[(size_t)s*16 + j], acc);
    }
    float inv = (end>beg) ? 1.0f/den : 0.f;
    float oi = acc*inv + b2[i*16+j] + resb[(size_t)i*NN*16 + (size_t)n*16 + j];
    o += oi * wsoft[type*6 + 4 + i];
  }
  out[(size_t)n*16 + j] = o;
}

extern "C" void kernel_launch(void* const* d_in, const int* in_sizes, int n_in,
                              void* d_out, int out_size, void* d_ws, size_t ws_size,
                              hipStream_t stream)
{
  const float* features0 = (const float*)d_in[0];
  const float* features1 = (const float*)d_in[1];
  const float* fc_w0 = (const float*)d_in[2];
  const float* fc_b0 = (const float*)d_in[3];
  const float* fc_w1 = (const float*)d_in[4];
  const float* fc_b1 = (const float*)d_in[5];
  const float* mix_w = (const float*)d_in[6];
  const float* W0  = (const float*)d_in[7];
  const float* al0 = (const float*)d_in[8];
  const float* ar0 = (const float*)d_in[9];
  const float* b0  = (const float*)d_in[10];
  const float* W1  = (const float*)d_in[11];
  const float* al1 = (const float*)d_in[12];
  const float* ar1 = (const float*)d_in[13];
  const float* b1  = (const float*)d_in[14];
  const float* W2  = (const float*)d_in[15];
  const float* al2 = (const float*)d_in[16];
  const float* ar2 = (const float*)d_in[17];
  const float* b2  = (const float*)d_in[18];
  const float* res2= (const float*)d_in[19];
  const int* src[2] = {(const int*)d_in[20], (const int*)d_in[22]};
  const int* dst[2] = {(const int*)d_in[21], (const int*)d_in[23]};
  (void)in_sizes; (void)n_in; (void)out_size; (void)ws_size;

  char* ws = (char*)d_ws;
  size_t off = 0;
  auto alloc = [&](size_t bytes)->char*{
    char* p = ws + off; off += (bytes + 255) & ~(size_t)255; return p;
  };
  float* wsoft = (float*)alloc(64*4);
  u16*   W0p   = (u16*)  alloc((size_t)2*64*256*2);
  u16*   W1p   = (u16*)  alloc((size_t)2*256*256*2);
  u16*   W2p   = (u16*)  alloc((size_t)256*64*2);
  u16*   Fp    = (u16*)  alloc((size_t)2*128*64*2);
  u16*   V2p   = (u16*)  alloc((size_t)2*128*16*2);
  float* bV    = (float*)alloc((size_t)32*4);
  int*   row2  = (int*)  alloc((size_t)2*(NN+1)*4);
  u16*   col2  = (u16*)  alloc((size_t)2*EE*2);
  u16*   dstOf = (u16*)  alloc((size_t)2*EE*2);
  int*   zeros = (int*)  alloc((size_t)4*NN*4);       // cnt2 + fill2, zeroed in prep
  int*   cnt2  = zeros;
  int*   fill2 = zeros + 2*NN;
  int*   bsum  = (int*)alloc((size_t)2*NB_SCAN*4);
  u16*   h0    = (u16*)alloc((size_t)NN*64*2);
  u16*   h1    = (u16*)alloc((size_t)NN*256*2);
  u16*   h2    = (u16*)alloc((size_t)NN*256*2);
  float* elA   = (float*)alloc((size_t)2*NN*4*4);
  float* erA   = (float*)alloc((size_t)2*NN*4*4);
  float* xbuf  = (float*)alloc((size_t)2*EE*4*4);     // 12.8 MB, reused L0/L1
  // region D (51.2 MB): layer-0 aggB -> layer-1 featD -> layer-2 outputs
  size_t featStride = (size_t)NN*256;                 // u16 elements per graph
  size_t off_D = off;
  u16* regionD = (u16*)alloc(2*featStride*2);
  u16* aggB  = regionD;
  u16* featD = regionD;
  float* feat16 = (float*)(ws + off_D);
  float* resb   = feat16 + (size_t)2*NN*16;
  float* el2    = resb   + (size_t)2*NN*16;
  float* er2    = el2    + (size_t)2*NN;

  // 1. prep: zero counters + mixw + pack all weights; prep2: V2 = fc_w@[W0*al|W0*ar]
  k_prep<<<100,256,0,stream>>>(mix_w, wsoft, W0, W0p, W1, W1p, W2, res2, W2p,
                               fc_w0, fc_w1, Fp, zeros);
  k_prep2<<<32,128,0,stream>>>(W0, al0, ar0, fc_w0, fc_w1, fc_b0, fc_b1, V2p, bV);

  // 2. CSR build, both graphs
  {
    dim3 gEb((EE+255)/256, 2), gS(NB_SCAN, 2);
    k_count2 <<<gEb,256,0,stream>>>(dst[0], dst[1], cnt2);
    k_scan1  <<<gS,1024,0,stream>>>(cnt2, row2, bsum);
    k_scan3  <<<gS,1024,0,stream>>>(row2, bsum);
    k_scatter2<<<gEb,256,0,stream>>>(src[0], dst[0], src[1], dst[1], row2, fill2, col2, dstOf);
  }

  // 3. input projection (MFMA) with fused layer-0 el/er
  k_inproj_m<<<NGRP,256,0,stream>>>(features0, features1, Fp, fc_b0, fc_b1,
                                    V2p, bV, h0, elA, erA);

  dim3 gE((EE+255)/256, 2);

  // 4. layer 0: alpha, interleaved dual-graph aggregate, head GEMM + ELU + mix
  k_alpha4<<<gE,256,0,stream>>>(col2, dstOf, elA, erA, (size_t)NN*4, xbuf);
  k_agg0 <<<NN/4,256,0,stream>>>(row2, col2, xbuf, h0, aggB, featStride);
  k_head0<<<NGRP,256,0,stream>>>(aggB, featStride, W0p, b0, wsoft, h1);

  // 5. layer 1: feat = h1 @ W1 (MFMA), alpha, interleaved fused aggregation -> h2
  k_gemm4<256><<<2*NGRP,256,0,stream>>>(h1, W1p, (size_t)256*256, al1, ar1, 256,
                                        featD, featStride, elA, erA, (size_t)NN*4);
  k_alpha4<<<gE,256,0,stream>>>(col2, dstOf, elA, erA, (size_t)NN*4, xbuf);
  k_aggNF<1><<<NN/4,256,0,stream>>>(row2, col2, xbuf, featD, featStride,
                                    h1, b1, wsoft, 1, h2);

  // 6. layer 2 (both graphs fused; alpha inline in agg2D)
  k_gemm2<<<NGRP,256,0,stream>>>(h2, W2p, al2, ar2, feat16, resb, el2, er2);
  k_agg2D<<<NN/16,256,0,stream>>>(row2, col2, el2, er2, feat16, resb, b2, wsoft, (float*)d_out);
}

// Round 12
// 453.437 us; speedup vs baseline: 1.0768x; 1.0044x over previous
//
#include <hip/hip_runtime.h>
#include <hip/hip_bf16.h>

// Problem constants (match reference)
#define NN   50000   // N0+N1
#define NN0  30000
#define EE   400000
#define NB_SCAN ((NN + 1023) / 1024)   // 49
#define NRT   3125                     // row tiles (16 rows each)
#define NGRP  ((NRT + 3) / 4)          // 782 row groups (64 rows)
#define NT0   1875                     // type-0 row tiles (30000/16, exact)

typedef unsigned short u16;
typedef unsigned int   u32;

typedef __attribute__((ext_vector_type(8))) __bf16 bf16x8;
typedef __attribute__((ext_vector_type(4))) float  f32x4;

// ---------- bf16 storage helpers (fp32 math everywhere) ----------
__device__ __forceinline__ float bf2f(u16 u){ return __uint_as_float(((u32)u)<<16); }
__device__ __forceinline__ float lo16(u32 u){ return __uint_as_float(u<<16); }
__device__ __forceinline__ float hi16(u32 u){ return __uint_as_float(u & 0xffff0000u); }
__device__ __forceinline__ u16 f2bf(float f){
  u32 x = __float_as_uint(f);
  x += 0x7fffu + ((x>>16)&1u);      // round-to-nearest-even
  return (u16)(x>>16);
}
__device__ __forceinline__ float elu_f(float x){ return x>0.f ? x : __expf(x)-1.f; }
__device__ __forceinline__ float lrelu(float x){ return x>0.f ? x : 0.2f*x; }
__device__ __forceinline__ bf16x8 ld_frag(const u16* p){
  uint4 v = *(const uint4*)p;
  return __builtin_bit_cast(bf16x8, v);
}
__device__ __forceinline__ bf16x8 cvt8(const float* p){   // 8 f32 -> bf16x8
  float4 u = ((const float4*)p)[0];
  float4 v = ((const float4*)p)[1];
  u32 w0 = (u32)f2bf(u.x) | ((u32)f2bf(u.y)<<16);
  u32 w1 = (u32)f2bf(u.z) | ((u32)f2bf(u.w)<<16);
  u32 w2 = (u32)f2bf(v.x) | ((u32)f2bf(v.y)<<16);
  u32 w3 = (u32)f2bf(v.z) | ((u32)f2bf(v.w)<<16);
  uint4 r{w0,w1,w2,w3};
  return __builtin_bit_cast(bf16x8, r);
}

// ---------- prep: zero counters + mixw softmax + all weight packing ----------
__global__ __launch_bounds__(256) void k_prep(
    const float* __restrict__ mix_w, float* __restrict__ wsoft,
    const float* __restrict__ W0, u16* __restrict__ W0p,
    const float* __restrict__ W1, u16* __restrict__ W1p,
    const float* __restrict__ W2, const float* __restrict__ res2, u16* __restrict__ W2p,
    const float* __restrict__ fcw0, const float* __restrict__ fcw1, u16* __restrict__ Fp,
    int* __restrict__ zeros)
{
  int t = blockIdx.x*256 + threadIdx.x;
  for (int z = t; z < 4*NN; z += gridDim.x*256) zeros[z] = 0;
  if (t < 6){
    float a0 = mix_w[t*2+0], a1 = mix_w[t*2+1];
    float mx = fmaxf(a0,a1);
    float e0 = __expf(a0-mx), e1 = __expf(a1-mx);
    wsoft[t*2+0] = e0/(e0+e1); wsoft[t*2+1] = e1/(e0+e1);
  }
  if (t < 4096){                    // W0: per graph 2048 frags, KB=2, NCOL=256
    int gg = t>>11, fi = t&2047;
    int lane = fi&63, kb = (fi>>6)&1, ct = fi>>7;
    int q = lane>>4, c = lane&15;
    const float* src = W0 + (size_t)gg*16384;
    u16* o = W0p + (size_t)gg*16384 + (size_t)fi*8;
    #pragma unroll
    for (int j=0;j<8;j++) o[j] = f2bf(src[(size_t)(kb*32+q*8+j)*256 + ct*16 + c]);
  } else if (t < 20480){            // W1: per graph 8192 frags, KB=8, NCOL=256
    int u = t - 4096;
    int gg = u>>13, fi = u&8191;
    int lane = fi&63, kb = (fi>>6)&7, ct = fi>>9;
    int q = lane>>4, c = lane&15;
    const float* src = W1 + (size_t)gg*65536;
    u16* o = W1p + (size_t)gg*65536 + (size_t)fi*8;
    #pragma unroll
    for (int j=0;j<8;j++) o[j] = f2bf(src[(size_t)(kb*32+q*8+j)*256 + ct*16 + c]);
  } else if (t < 22528){            // W2cat: 2048 frags, KB=8, NCOL=64
    int fi = t - 20480;
    int lane = fi&63, kb = (fi>>6)&7, ct = fi>>9;
    int q = lane>>4, c = lane&15;
    int cl = ct*16 + c;
    int i = cl>>5, which = (cl>>4)&1;
    const float* src = which ? res2 : W2;
    u16* o = W2p + (size_t)fi*8;
    #pragma unroll
    for (int j=0;j<8;j++) o[j] = f2bf(src[(size_t)i*4096 + (size_t)(kb*32+q*8+j)*16 + (cl&15)]);
  } else if (t < 24576){            // fc_w: per type 1024 frags, KB=4, NCOL=64
    int u = t - 22528;
    int tt = u>>10, fi = u&1023;
    int lane = fi&63, kb = (fi>>6)&3, ct = fi>>8;
    int q = lane>>4, c = lane&15;
    const float* src = tt ? fcw1 : fcw0;
    u16* o = Fp + (size_t)tt*8192 + (size_t)fi*8;
    #pragma unroll
    for (int j=0;j<8;j++) o[j] = f2bf(src[(size_t)(kb*32+q*8+j)*64 + ct*16 + c]);
  }
}

// ---------- prep2: V2 = fc_w @ [W0*al | W0*ar] (128x16 per type) + bV ----------
__global__ __launch_bounds__(128) void k_prep2(
    const float* __restrict__ W0,
    const float* __restrict__ al0, const float* __restrict__ ar0,
    const float* __restrict__ fcw0, const float* __restrict__ fcw1,
    const float* __restrict__ fcb0, const float* __restrict__ fcb1,
    u16* __restrict__ V2p, float* __restrict__ bV)
{
  __shared__ float V[64];
  int b = blockIdx.x;
  int tt = b>>4, cl = b&15;
  int which = cl>>3, g = (cl>>2)&1, h = cl&3;
  int t = threadIdx.x;
  const float* sel = (which ? ar0 : al0) + (size_t)(g*4+h)*64;
  if (t < 64){
    const float* Wrow = W0 + (size_t)g*16384 + (size_t)t*256 + h*64;
    float s = 0.f;
    #pragma unroll 8
    for (int d=0; d<64; d++) s = fmaf(Wrow[d], sel[d], s);
    V[t] = s;
  }
  __syncthreads();
  const float* fw = tt ? fcw1 : fcw0;   // 128 x 64
  float s = 0.f;
  #pragma unroll 8
  for (int d=0; d<64; d++) s = fmaf(fw[(size_t)t*64 + d], V[d], s);
  int kb = t>>5, q = (t>>3)&3, j = t&7;
  V2p[(size_t)tt*2048 + ((size_t)kb*64 + q*16 + cl)*8 + j] = f2bf(s);
  if (t == 0){
    const float* fbp = tt ? fcb1 : fcb0;
    float sb = 0.f;
    #pragma unroll 8
    for (int d=0; d<64; d++) sb = fmaf(fbp[d], V[d], sb);
    bV[tt*16 + cl] = sb;
  }
}

// ================= CSR build (both graphs, rebuilt every launch) ===============
__global__ void k_count2(const int* __restrict__ d0, const int* __restrict__ d1,
                         int* __restrict__ cnt2){
  int t = blockIdx.x*256 + threadIdx.x;
  int g = blockIdx.y;
  if (t < EE) atomicAdd(&cnt2[g*NN + (g ? d1[t] : d0[t])], 1);
}

__global__ __launch_bounds__(1024) void k_scan1(const int* __restrict__ cnt2,
                                                int* __restrict__ row2, int* __restrict__ bsum){
  __shared__ int wsum[16];
  int g = blockIdx.y;
  int lane = threadIdx.x & 63, wid = threadIdx.x >> 6;
  int i = blockIdx.x*1024 + threadIdx.x;
  int v = (i < NN) ? cnt2[g*NN + i] : 0;
  int x = v;
  #pragma unroll
  for (int off = 1; off < 64; off <<= 1){
    int y = __shfl_up(x, off, 64);
    if (lane >= off) x += y;
  }
  if (lane == 63) wsum[wid] = x;
  __syncthreads();
  if (wid == 0 && lane < 16){
    int s = wsum[lane];
    #pragma unroll
    for (int off = 1; off < 16; off <<= 1){
      int y = __shfl_up(s, off, 16);
      if (lane >= off) s += y;
    }
    wsum[lane] = s;
  }
  __syncthreads();
  int incl = x + (wid ? wsum[wid-1] : 0);
  if (i < NN) row2[(size_t)g*(NN+1) + i] = incl - v;
  if (threadIdx.x == 1023) bsum[g*NB_SCAN + blockIdx.x] = incl;
}

// scan3: add block offset (computed inline from bsum via one wave reduction)
__global__ __launch_bounds__(1024) void k_scan3(int* __restrict__ row2,
                                                const int* __restrict__ bsum){
  __shared__ int base;
  int g = blockIdx.y;
  if (threadIdx.x < 64){
    int lane = threadIdx.x;
    int v = (lane < (int)blockIdx.x) ? bsum[g*NB_SCAN + lane] : 0;
    #pragma unroll
    for (int off = 32; off; off >>= 1) v += __shfl_xor(v, off, 64);
    if (lane == 0) base = v;
  }
  __syncthreads();
  int i = blockIdx.x*1024 + threadIdx.x;
  if (i < NN) row2[(size_t)g*(NN+1) + i] += base;
  if (blockIdx.x == 0 && threadIdx.x == 0) row2[(size_t)g*(NN+1) + NN] = EE;
}

// scatter: col2 (u16 src id) + dstOf (u16 dst id) per CSR slot
__global__ void k_scatter2(const int* __restrict__ s0, const int* __restrict__ d0,
                           const int* __restrict__ s1, const int* __restrict__ d1,
                           const int* __restrict__ row2, int* __restrict__ fill2,
                           u16* __restrict__ col2, u16* __restrict__ dstOf){
  int t = blockIdx.x*256 + threadIdx.x;
  int g = blockIdx.y;
  if (t >= EE) return;
  int d = g ? d1[t] : d0[t];
  int s = g ? s1[t] : s0[t];
  int pos = atomicAdd(&fill2[g*NN + d], 1);
  size_t slot = (size_t)g*EE + row2[(size_t)g*(NN+1) + d] + pos;
  col2[slot]  = (u16)s;
  dstOf[slot] = (u16)d;
}

// ---------- alpha precompute (H=4), edge-parallel ----------
__global__ void k_alpha4(const u16* __restrict__ col2, const u16* __restrict__ dstOf,
                         const float* __restrict__ el, const float* __restrict__ er,
                         size_t elStride, float* __restrict__ xbuf){
  int t = blockIdx.x*256 + threadIdx.x;
  int g = blockIdx.y;
  if (t >= EE) return;
  size_t slot = (size_t)g*EE + t;
  int s = col2[slot], d = dstOf[slot];
  const float* elg = el + (size_t)g*elStride;
  const float* erg = er + (size_t)g*elStride;
  float4 e4 = ((const float4*)elg)[s];
  float4 r4 = ((const float4*)erg)[d];
  float4 x;
  x.x = __expf(lrelu(e4.x + r4.x));
  x.y = __expf(lrelu(e4.y + r4.y));
  x.z = __expf(lrelu(e4.z + r4.z));
  x.w = __expf(lrelu(e4.w + r4.w));
  ((float4*)xbuf)[slot] = x;
}

// ---------- input projection (MFMA) + fused layer-0 el/er ----------
__global__ __launch_bounds__(256) void k_inproj_m(
    const float* __restrict__ f0, const float* __restrict__ f1,
    const u16* __restrict__ Fp, const float* __restrict__ fb0, const float* __restrict__ fb1,
    const u16* __restrict__ V2p, const float* __restrict__ bV,
    u16* __restrict__ h0, float* __restrict__ elA, float* __restrict__ erA)
{
  int wv = threadIdx.x>>6, ln = threadIdx.x&63;
  int ti = blockIdx.x*4 + wv;
  if (ti >= NRT) return;
  int q = ln>>4, c = ln&15;
  int type = (ti < NT0) ? 0 : 1;
  const float* F = type ? f1 : f0;
  int rbase = type ? (ti*16 - NN0) : ti*16;
  const u16* Bg = Fp + (size_t)type*8192;
  const u16* Vg = V2p + (size_t)type*2048;
  const float* bb = type ? fb1 : fb0;
  f32x4 acc[4] = {};
  f32x4 accE = {};
  const float* Ap = F + (size_t)(rbase + c)*128;
  #pragma unroll
  for (int kb=0; kb<4; kb++){
    bf16x8 a = cvt8(Ap + kb*32 + q*8);
    #pragma unroll
    for (int ct=0; ct<4; ct++){
      bf16x8 b = ld_frag(Bg + ((size_t)(ct*4+kb)*64 + ln)*8);
      acc[ct] = __builtin_amdgcn_mfma_f32_16x16x32_bf16(a, b, acc[ct], 0,0,0);
    }
    bf16x8 bv_ = ld_frag(Vg + ((size_t)kb*64 + ln)*8);
    accE = __builtin_amdgcn_mfma_f32_16x16x32_bf16(a, bv_, accE, 0,0,0);
  }
  #pragma unroll
  for (int ct=0; ct<4; ct++){
    float bvs = bb[ct*16+c];
    #pragma unroll
    for (int j=0;j<4;j++){
      int row = ti*16 + q*4 + j;
      h0[(size_t)row*64 + ct*16 + c] = f2bf(acc[ct][j] + bvs);
    }
  }
  int which = c>>3, gg = (c>>2)&1, hh = c&3;
  float bVv = bV[type*16 + c];
  float* dst = (which ? erA : elA) + (size_t)gg*NN*4;
  #pragma unroll
  for (int j=0;j<4;j++){
    int row = ti*16 + q*4 + j;
    dst[row*4 + hh] = accE[j] + bVv;
  }
}

// ---------- layer-0 aggregation: gather h0 (64 cols), BOTH graphs interleaved --
// 2-wave blocks: finer scheduling granularity, less tail imbalance.
__global__ __launch_bounds__(128) void k_agg0(
    const int* __restrict__ row2, const u16* __restrict__ col2,
    const float* __restrict__ xbuf, const u16* __restrict__ h0,
    u16* __restrict__ aggB, size_t aggStride)
{
  int wv = threadIdx.x>>6, ln = threadIdx.x&63;
  int n = blockIdx.x*2 + wv;
  const int* rw0 = row2;
  const int* rw1 = row2 + (NN+1);
  const u16* cl0 = col2;
  const u16* cl1 = col2 + EE;
  const float4* xb0 = (const float4*)xbuf;
  const float4* xb1 = xb0 + EE;
  int b0_ = rw0[n], e0_ = rw0[n+1];
  int b1_ = rw1[n], e1_ = rw1[n+1];
  int k0 = b0_, k1 = b1_;
  float d00=0.f,d01=0.f,d02=0.f,d03=0.f, a00=0.f,a01=0.f,a02=0.f,a03=0.f;
  float d10=0.f,d11=0.f,d12=0.f,d13=0.f, a10=0.f,a11=0.f,a12=0.f,a13=0.f;
  while (k0+2<=e0_ && k1+2<=e1_){
    int sA=cl0[k0], sB=cl0[k0+1], sC=cl1[k1], sD=cl1[k1+1];
    float4 xA=xb0[k0], xB=xb0[k0+1], xC=xb1[k1], xD=xb1[k1+1];
    float vA=bf2f(h0[(size_t)sA*64+ln]);
    float vB=bf2f(h0[(size_t)sB*64+ln]);
    float vC=bf2f(h0[(size_t)sC*64+ln]);
    float vD=bf2f(h0[(size_t)sD*64+ln]);
    d00+=xA.x+xB.x; d01+=xA.y+xB.y; d02+=xA.z+xB.z; d03+=xA.w+xB.w;
    a00+=xA.x*vA+xB.x*vB; a01+=xA.y*vA+xB.y*vB;
    a02+=xA.z*vA+xB.z*vB; a03+=xA.w*vA+xB.w*vB;
    d10+=xC.x+xD.x; d11+=xC.y+xD.y; d12+=xC.z+xD.z; d13+=xC.w+xD.w;
    a10+=xC.x*vC+xD.x*vD; a11+=xC.y*vC+xD.y*vD;
    a12+=xC.z*vC+xD.z*vD; a13+=xC.w*vC+xD.w*vD;
    k0+=2; k1+=2;
  }
  for (; k0+2<=e0_; k0+=2){
    int sA=cl0[k0], sB=cl0[k0+1];
    float4 xA=xb0[k0], xB=xb0[k0+1];
    float vA=bf2f(h0[(size_t)sA*64+ln]);
    float vB=bf2f(h0[(size_t)sB*64+ln]);
    d00+=xA.x+xB.x; d01+=xA.y+xB.y; d02+=xA.z+xB.z; d03+=xA.w+xB.w;
    a00+=xA.x*vA+xB.x*vB; a01+=xA.y*vA+xB.y*vB;
    a02+=xA.z*vA+xB.z*vB; a03+=xA.w*vA+xB.w*vB;
  }
  for (; k0<e0_; k0++){
    int s=cl0[k0]; float4 x=xb0[k0];
    float v=bf2f(h0[(size_t)s*64+ln]);
    d00+=x.x; d01+=x.y; d02+=x.z; d03+=x.w;
    a00+=x.x*v; a01+=x.y*v; a02+=x.z*v; a03+=x.w*v;
  }
  for (; k1+2<=e1_; k1+=2){
    int sC=cl1[k1], sD=cl1[k1+1];
    float4 xC=xb1[k1], xD=xb1[k1+1];
    float vC=bf2f(h0[(size_t)sC*64+ln]);
    float vD=bf2f(h0[(size_t)sD*64+ln]);
    d10+=xC.x+xD.x; d11+=xC.y+xD.y; d12+=xC.z+xD.z; d13+=xC.w+xD.w;
    a10+=xC.x*vC+xD.x*vD; a11+=xC.y*vC+xD.y*vD;
    a12+=xC.z*vC+xD.z*vD; a13+=xC.w*vC+xD.w*vD;
  }
  for (; k1<e1_; k1++){
    int s=cl1[k1]; float4 x=xb1[k1];
    float v=bf2f(h0[(size_t)s*64+ln]);
    d10+=x.x; d11+=x.y; d12+=x.z; d13+=x.w;
    a10+=x.x*v; a11+=x.y*v; a12+=x.z*v; a13+=x.w*v;
  }
  bool hg0 = e0_ > b0_, hg1 = e1_ > b1_;
  u16* og0 = aggB + (size_t)n*256 + ln;
  og0[0]   = f2bf(hg0 ? a00/d00 : 0.f);
  og0[64]  = f2bf(hg0 ? a01/d01 : 0.f);
  og0[128] = f2bf(hg0 ? a02/d02 : 0.f);
  og0[192] = f2bf(hg0 ? a03/d03 : 0.f);
  u16* og1 = aggB + aggStride + (size_t)n*256 + ln;
  og1[0]   = f2bf(hg1 ? a10/d10 : 0.f);
  og1[64]  = f2bf(hg1 ? a11/d11 : 0.f);
  og1[128] = f2bf(hg1 ? a12/d12 : 0.f);
  og1[192] = f2bf(hg1 ? a13/d13 : 0.f);
}

// ---------- layer-0 head GEMM: ELU(agg@W0_blockdiag + b) mixed -> h1 ----------
__global__ __launch_bounds__(256) void k_head0(
    const u16* __restrict__ aggB, size_t aggStride,
    const u16* __restrict__ W0p, const float* __restrict__ b0,
    const float* __restrict__ wsoft, u16* __restrict__ h1)
{
  int wv = threadIdx.x>>6, ln = threadIdx.x&63;
  int ti = blockIdx.x*4 + wv;
  if (ti >= NRT) return;
  int q = ln>>4, c = ln&15;
  int type = (ti < NT0) ? 0 : 1;
  float wg0 = wsoft[type*6 + 0];
  float wg1 = wsoft[type*6 + 1];
  for (int h=0; h<4; h++){
    f32x4 acc[2][4] = {};
    #pragma unroll
    for (int g=0; g<2; g++){
      const u16* Ap = aggB + (size_t)g*aggStride + (size_t)(ti*16 + c)*256 + h*64 + q*8;
      const u16* Bg = W0p + (size_t)g*16384;
      #pragma unroll
      for (int kb=0; kb<2; kb++){
        bf16x8 a = ld_frag(Ap + kb*32);
        #pragma unroll
        for (int ct=0; ct<4; ct++){
          int ctg = h*4 + ct;
          bf16x8 b = ld_frag(Bg + ((size_t)(ctg*2 + kb)*64 + ln)*8);
          acc[g][ct] = __builtin_amdgcn_mfma_f32_16x16x32_bf16(a, b, acc[g][ct], 0,0,0);
        }
      }
    }
    #pragma unroll
    for (int ct=0; ct<4; ct++){
      int colg = h*64 + ct*16 + c;
      float bb0 = b0[colg], bb1 = b0[256 + colg];
      #pragma unroll
      for (int j=0;j<4;j++){
        int row = ti*16 + q*4 + j;
        float o = wg0*elu_f(acc[0][ct][j] + bb0) + wg1*elu_f(acc[1][ct][j] + bb1);
        h1[(size_t)row*256 + colg] = f2bf(o);
      }
    }
  }
}

// ---------- MFMA GEMM, 4 row-tiles x 4 col-tiles per wave (layer 1) ------------
template<int K>
__global__ __launch_bounds__(256) void k_gemm4(
    const u16* __restrict__ A,
    const u16* __restrict__ Bp, size_t bpStride,
    const float* __restrict__ al, const float* __restrict__ ar, int alStride,
    u16* __restrict__ feat, size_t featStride,
    float* __restrict__ el, float* __restrict__ er, size_t elStride)
{
  constexpr int KB = K/32;
  int wv = threadIdx.x>>6, ln = threadIdx.x&63;
  int bid = blockIdx.x;
  int g = bid / NGRP, grp = bid % NGRP;
  int split = wv, q = ln>>4, c = ln&15;
  const u16* Bpg = Bp + (size_t)g*bpStride;
  const float* alg = al + (size_t)g*alStride;
  const float* arg = ar + (size_t)g*alStride;
  u16* featg = feat + (size_t)g*featStride;
  float* elg = el + (size_t)g*elStride;
  float* erg = er + (size_t)g*elStride;

  f32x4 acc[4][4] = {};
  int  tbase = grp*4;
  bool valid[4];
  const u16* Ap[4];
  #pragma unroll
  for (int rt=0; rt<4; rt++){
    int ti = tbase + rt;
    valid[rt] = (ti < NRT);
    if (!valid[rt]) ti = NRT-1;
    Ap[rt] = A + (size_t)(ti*16 + c)*K + q*8;
  }
  const u16* Bbase = Bpg + ((size_t)(split*4)*KB*64 + ln)*8;

  #pragma unroll 2
  for (int kb=0; kb<KB; kb++){
    bf16x8 b[4], a[4];
    #pragma unroll
    for (int ct=0; ct<4; ct++) b[ct] = ld_frag(Bbase + (size_t)(ct*KB + kb)*64*8);
    #pragma unroll
    for (int rt=0; rt<4; rt++) a[rt] = ld_frag(Ap[rt] + kb*32);
    #pragma unroll
    for (int rt=0; rt<4; rt++)
      #pragma unroll
      for (int ct=0; ct<4; ct++)
        acc[rt][ct] = __builtin_amdgcn_mfma_f32_16x16x32_bf16(a[rt], b[ct], acc[rt][ct], 0,0,0);
  }

  float alv[4], arv[4];
  #pragma unroll
  for (int ct=0;ct<4;ct++){
    int cg = (split*4+ct)*16 + c;
    alv[ct] = alg[cg]; arv[ct] = arg[cg];
  }
  #pragma unroll
  for (int rt=0; rt<4; rt++){
    if (!valid[rt]) continue;
    int row0 = (tbase+rt)*16;
    #pragma unroll
    for (int j=0;j<4;j++){
      float ep=0.f, rp=0.f;
      #pragma unroll
      for (int ct=0;ct<4;ct++){ ep += acc[rt][ct][j]*alv[ct]; rp += acc[rt][ct][j]*arv[ct]; }
      #pragma unroll
      for (int off=8; off; off>>=1){ ep += __shfl_xor(ep,off,16); rp += __shfl_xor(rp,off,16); }
      int row = row0 + q*4 + j;
      if (c==0){ elg[row*4+split]=ep; erg[row*4+split]=rp; }
      #pragma unroll
      for (int ct=0;ct<4;ct++)
        featg[(size_t)row*256 + (split*4+ct)*16 + c] = f2bf(acc[rt][ct][j]);
    }
  }
}

// ---------- fused dual-graph gather aggregation (256 cols, H=4), layer 1 -------
// 2-wave blocks; both graphs interleaved (8 gathers in flight per wave).
template<int RES>
__global__ __launch_bounds__(128) void k_aggNF(
    const int* __restrict__ row2, const u16* __restrict__ col2,
    const float* __restrict__ xbuf,
    const u16* __restrict__ feat, size_t featStride,
    const u16* __restrict__ hres, const float* __restrict__ bias,
    const float* __restrict__ wsoft, int l,
    u16* __restrict__ hout)
{
  int wv = threadIdx.x>>6, ln = threadIdx.x&63;
  int n = blockIdx.x*2 + wv;
  int h = ln>>4;
  int type = (n<NN0)?0:1;
  float rx=0.f, ry=0.f, rz=0.f, rw_=0.f;
  if (RES){
    uint2 r = ((const uint2*)hres)[(size_t)n*64 + ln];
    rx=lo16(r.x); ry=hi16(r.x); rz=lo16(r.y); rw_=hi16(r.y);
  }
  const int* rw0 = row2;
  const int* rw1 = row2 + (NN+1);
  const u16* cl0 = col2;
  const u16* cl1 = col2 + EE;
  const float* x0p = xbuf;
  const float* x1p = xbuf + (size_t)EE*4;
  const uint2* fp0 = (const uint2*)feat;
  const uint2* fp1 = (const uint2*)(feat + featStride);
  int b0_ = rw0[n], e0_ = rw0[n+1];
  int b1_ = rw1[n], e1_ = rw1[n+1];
  int k0 = b0_, k1 = b1_;
  float den0=0.f, A0=0.f,A1=0.f,A2=0.f,A3=0.f;
  float den1=0.f, B0=0.f,B1=0.f,B2=0.f,B3=0.f;
  while (k0+4<=e0_ && k1+4<=e1_){
    int s0=cl0[k0], s1=cl0[k0+1], s2=cl0[k0+2], s3=cl0[k0+3];
    int t0=cl1[k1], t1=cl1[k1+1], t2=cl1[k1+2], t3=cl1[k1+3];
    float x0=x0p[(size_t)k0*4+h],     x1=x0p[(size_t)(k0+1)*4+h];
    float x2=x0p[(size_t)(k0+2)*4+h], x3=x0p[(size_t)(k0+3)*4+h];
    float y0=x1p[(size_t)k1*4+h],     y1=x1p[(size_t)(k1+1)*4+h];
    float y2=x1p[(size_t)(k1+2)*4+h], y3=x1p[(size_t)(k1+3)*4+h];
    uint2 f0=fp0[(size_t)s0*64+ln], f1=fp0[(size_t)s1*64+ln];
    uint2 f2=fp0[(size_t)s2*64+ln], f3=fp0[(size_t)s3*64+ln];
    uint2 g0=fp1[(size_t)t0*64+ln], g1=fp1[(size_t)t1*64+ln];
    uint2 g2=fp1[(size_t)t2*64+ln], g3=fp1[(size_t)t3*64+ln];
    den0 += (x0+x1) + (x2+x3);
    A0 += x0*lo16(f0.x)+x1*lo16(f1.x)+x2*lo16(f2.x)+x3*lo16(f3.x);
    A1 += x0*hi16(f0.x)+x1*hi16(f1.x)+x2*hi16(f2.x)+x3*hi16(f3.x);
    A2 += x0*lo16(f0.y)+x1*lo16(f1.y)+x2*lo16(f2.y)+x3*lo16(f3.y);
    A3 += x0*hi16(f0.y)+x1*hi16(f1.y)+x2*hi16(f2.y)+x3*hi16(f3.y);
    den1 += (y0+y1) + (y2+y3);
    B0 += y0*lo16(g0.x)+y1*lo16(g1.x)+y2*lo16(g2.x)+y3*lo16(g3.x);
    B1 += y0*hi16(g0.x)+y1*hi16(g1.x)+y2*hi16(g2.x)+y3*hi16(g3.x);
    B2 += y0*lo16(g0.y)+y1*lo16(g1.y)+y2*lo16(g2.y)+y3*lo16(g3.y);
    B3 += y0*hi16(g0.y)+y1*hi16(g1.y)+y2*hi16(g2.y)+y3*hi16(g3.y);
    k0+=4; k1+=4;
  }
  for (; k0+4<=e0_; k0+=4){
    int s0=cl0[k0], s1=cl0[k0+1], s2=cl0[k0+2], s3=cl0[k0+3];
    float x0=x0p[(size_t)k0*4+h],     x1=x0p[(size_t)(k0+1)*4+h];
    float x2=x0p[(size_t)(k0+2)*4+h], x3=x0p[(size_t)(k0+3)*4+h];
    uint2 f0=fp0[(size_t)s0*64+ln], f1=fp0[(size_t)s1*64+ln];
    uint2 f2=fp0[(size_t)s2*64+ln], f3=fp0[(size_t)s3*64+ln];
    den0 += (x0+x1) + (x2+x3);
    A0 += x0*lo16(f0.x)+x1*lo16(f1.x)+x2*lo16(f2.x)+x3*lo16(f3.x);
    A1 += x0*hi16(f0.x)+x1*hi16(f1.x)+x2*hi16(f2.x)+x3*hi16(f3.x);
    A2 += x0*lo16(f0.y)+x1*lo16(f1.y)+x2*lo16(f2.y)+x3*lo16(f3.y);
    A3 += x0*hi16(f0.y)+x1*hi16(f1.y)+x2*hi16(f2.y)+x3*hi16(f3.y);
  }
  for (; k0<e0_; k0++){
    int s=cl0[k0];
    float x=x0p[(size_t)k0*4+h];
    uint2 f=fp0[(size_t)s*64+ln];
    den0 += x;
    A0 += x*lo16(f.x); A1 += x*hi16(f.x); A2 += x*lo16(f.y); A3 += x*hi16(f.y);
  }
  for (; k1+4<=e1_; k1+=4){
    int t0=cl1[k1], t1=cl1[k1+1], t2=cl1[k1+2], t3=cl1[k1+3];
    float y0=x1p[(size_t)k1*4+h],     y1=x1p[(size_t)(k1+1)*4+h];
    float y2=x1p[(size_t)(k1+2)*4+h], y3=x1p[(size_t)(k1+3)*4+h];
    uint2 g0=fp1[(size_t)t0*64+ln], g1=fp1[(size_t)t1*64+ln];
    uint2 g2=fp1[(size_t)t2*64+ln], g3=fp1[(size_t)t3*64+ln];
    den1 += (y0+y1) + (y2+y3);
    B0 += y0*lo16(g0.x)+y1*lo16(g1.x)+y2*lo16(g2.x)+y3*lo16(g3.x);
    B1 += y0*hi16(g0.x)+y1*hi16(g1.x)+y2*hi16(g2.x)+y3*hi16(g3.x);
    B2 += y0*lo16(g0.y)+y1*lo16(g1.y)+y2*lo16(g2.y)+y3*lo16(g3.y);
    B3 += y0*hi16(g0.y)+y1*hi16(g1.y)+y2*hi16(g2.y)+y3*hi16(g3.y);
  }
  for (; k1<e1_; k1++){
    int t=cl1[k1];
    float y=x1p[(size_t)k1*4+h];
    uint2 g=fp1[(size_t)t*64+ln];
    den1 += y;
    B0 += y*lo16(g.x); B1 += y*hi16(g.x); B2 += y*lo16(g.y); B3 += y*hi16(g.y);
  }
  float inv0 = (e0_>b0_) ? 1.0f/den0 : 0.f;
  float inv1 = (e1_>b1_) ? 1.0f/den1 : 0.f;
  float4 bv0 = ((const float4*)(bias))[ln];
  float4 bv1 = ((const float4*)(bias + 256))[ln];
  float w0 = wsoft[type*6 + l*2 + 0];
  float w1 = wsoft[type*6 + l*2 + 1];
  float c0 = A0*inv0 + bv0.x, c1 = A1*inv0 + bv0.y, c2 = A2*inv0 + bv0.z, c3 = A3*inv0 + bv0.w;
  float e0 = B0*inv1 + bv1.x, e1 = B1*inv1 + bv1.y, e2 = B2*inv1 + bv1.z, e3 = B3*inv1 + bv1.w;
  if (RES){ c0+=rx; c1+=ry; c2+=rz; c3+=rw_; e0+=rx; e1+=ry; e2+=rz; e3+=rw_; }
  float o0 = w0*elu_f(c0) + w1*elu_f(e0);
  float o1 = w0*elu_f(c1) + w1*elu_f(e1);
  float o2 = w0*elu_f(c2) + w1*elu_f(e2);
  float o3 = w0*elu_f(c3) + w1*elu_f(e3);
  uint2 o;
  o.x = (u32)f2bf(o0) | ((u32)f2bf(o1)<<16);
  o.y = (u32)f2bf(o2) | ((u32)f2bf(o3)<<16);
  ((uint2*)hout)[(size_t)n*64 + ln] = o;
}

// ---------- layer-2 MFMA: A(N,256) @ [W2_0|res2_0|W2_1|res2_1](256,64) ----------
// feat16 stored bf16 (halves layer-2 gather footprint); resb stays f32.
__global__ __launch_bounds__(256) void k_gemm2(
    const u16* __restrict__ A, const u16* __restrict__ Bp,
    const float* __restrict__ al2, const float* __restrict__ ar2,
    u16* __restrict__ feat16, float* __restrict__ resb,
    float* __restrict__ el2, float* __restrict__ er2)
{
  int wv = threadIdx.x>>6, ln = threadIdx.x&63;
  int wt = blockIdx.x*4 + wv;
  if (wt >= NRT) return;
  int row0 = wt*16;
  int q = ln>>4, c = ln&15;
  f32x4 acc[4] = {};
  const u16* Ap = A + (size_t)(row0 + c)*256 + q*8;
  #pragma unroll
  for (int kb=0; kb<8; kb++){
    bf16x8 a = ld_frag(Ap + kb*32);
    #pragma unroll
    for (int t=0;t<4;t++){
      bf16x8 b = ld_frag(Bp + ((size_t)(t*8 + kb)*64 + ln)*8);
      acc[t] = __builtin_amdgcn_mfma_f32_16x16x32_bf16(a, b, acc[t], 0,0,0);
    }
  }
  #pragma unroll
  for (int i=0;i<2;i++){
    float alv = al2[i*16+c], arv = ar2[i*16+c];
    #pragma unroll
    for (int j=0;j<4;j++){
      float ep = acc[2*i][j]*alv, rp = acc[2*i][j]*arv;
      #pragma unroll
      for (int off=8; off; off>>=1){ ep += __shfl_xor(ep,off,16); rp += __shfl_xor(rp,off,16); }
      if (c==0){
        int row = row0 + q*4 + j;
        el2[(size_t)i*NN + row] = ep; er2[(size_t)i*NN + row] = rp;
      }
    }
    #pragma unroll
    for (int j=0;j<4;j++){
      int row = row0 + q*4 + j;
      feat16[(size_t)i*NN*16 + (size_t)row*16 + c] = f2bf(acc[2*i][j]);
      resb  [(size_t)i*NN*16 + (size_t)row*16 + c] = acc[2*i+1][j];
    }
  }
}

// ---------- layer-2 dual-graph aggregation + inline alpha + final mix ----------
__global__ __launch_bounds__(256) void k_agg2D(
    const int* __restrict__ row2, const u16* __restrict__ col2,
    const float* __restrict__ el2, const float* __restrict__ er2,
    const u16* __restrict__ feat16, const float* __restrict__ resb,
    const float* __restrict__ b2, const float* __restrict__ wsoft,
    float* __restrict__ out)
{
  int t = threadIdx.x;
  int nl = t>>4, j = t&15;
  int n = blockIdx.x*16 + nl;
  int type = (n<NN0)?0:1;
  float o = 0.f;
  #pragma unroll
  for (int i=0;i<2;i++){
    const int* rw = row2 + (size_t)i*(NN+1);
    const u16* cl = col2 + (size_t)i*EE;
    const float* elg = el2 + (size_t)i*NN;
    float ern = er2[(size_t)i*NN + n];
    const u16* f = feat16 + (size_t)i*NN*16;
    int beg = rw[n], end = rw[n+1];
    float den = 0.f, acc = 0.f;
    int k = beg;
    for (; k+4<=end; k+=4){
      int s0=cl[k], s1=cl[k+1], s2=cl[k+2], s3=cl[k+3];
      float x0 = __expf(lrelu(elg[s0] + ern));
      float x1 = __expf(lrelu(elg[s1] + ern));
      float x2 = __expf(lrelu(elg[s2] + ern));
      float x3 = __expf(lrelu(elg[s3] + ern));
      float v0 = bf2f(f[(size_t)s0*16 + j]);
      float v1 = bf2f(f[(size_t)s1*16 + j]);
      float v2 = bf2f(f[(size_t)s2*16 + j]);
      float v3 = bf2f(f[(size_t)s3*16 + j]);
      den += (x0+x1) + (x2+x3);
      acc += x0*v0 + x1*v1 + x2*v2 + x3*v3;
    }
    for (; k<end; k++){
      int s = cl[k];
      float x = __expf(lrelu(elg[s] + ern));
      den += x;
      acc = fmaf(x, bf2f(f[(size_t)s*16 + j]), acc);
    }
    float inv = (end>beg) ? 1.0f/den : 0.f;
    float oi = acc*inv + b2[i*16+j] + resb[(size_t)i*NN*16 + (size_t)n*16 + j];
    o += oi * wsoft[type*6 + 4 + i];
  }
  out[(size_t)n*16 + j] = o;
}

extern "C" void kernel_launch(void* const* d_in, const int* in_sizes, int n_in,
                              void* d_out, int out_size, void* d_ws, size_t ws_size,
                              hipStream_t stream)
{
  const float* features0 = (const float*)d_in[0];
  const float* features1 = (const float*)d_in[1];
  const float* fc_w0 = (const float*)d_in[2];
  const float* fc_b0 = (const float*)d_in[3];
  const float* fc_w1 = (const float*)d_in[4];
  const float* fc_b1 = (const float*)d_in[5];
  const float* mix_w = (const float*)d_in[6];
  const float* W0  = (const float*)d_in[7];
  const float* al0 = (const float*)d_in[8];
  const float* ar0 = (const float*)d_in[9];
  const float* b0  = (const float*)d_in[10];
  const float* W1  = (const float*)d_in[11];
  const float* al1 = (const float*)d_in[12];
  const float* ar1 = (const float*)d_in[13];
  const float* b1  = (const float*)d_in[14];
  const float* W2  = (const float*)d_in[15];
  const float* al2 = (const float*)d_in[16];
  const float* ar2 = (const float*)d_in[17];
  const float* b2  = (const float*)d_in[18];
  const float* res2= (const float*)d_in[19];
  const int* src[2] = {(const int*)d_in[20], (const int*)d_in[22]};
  const int* dst[2] = {(const int*)d_in[21], (const int*)d_in[23]};
  (void)in_sizes; (void)n_in; (void)out_size; (void)ws_size;

  char* ws = (char*)d_ws;
  size_t off = 0;
  auto alloc = [&](size_t bytes)->char*{
    char* p = ws + off; off += (bytes + 255) & ~(size_t)255; return p;
  };
  float* wsoft = (float*)alloc(64*4);
  u16*   W0p   = (u16*)  alloc((size_t)2*64*256*2);
  u16*   W1p   = (u16*)  alloc((size_t)2*256*256*2);
  u16*   W2p   = (u16*)  alloc((size_t)256*64*2);
  u16*   Fp    = (u16*)  alloc((size_t)2*128*64*2);
  u16*   V2p   = (u16*)  alloc((size_t)2*128*16*2);
  float* bV    = (float*)alloc((size_t)32*4);
  int*   row2  = (int*)  alloc((size_t)2*(NN+1)*4);
  u16*   col2  = (u16*)  alloc((size_t)2*EE*2);
  u16*   dstOf = (u16*)  alloc((size_t)2*EE*2);
  int*   zeros = (int*)  alloc((size_t)4*NN*4);       // cnt2 + fill2, zeroed in prep
  int*   cnt2  = zeros;
  int*   fill2 = zeros + 2*NN;
  int*   bsum  = (int*)alloc((size_t)2*NB_SCAN*4);
  u16*   h0    = (u16*)alloc((size_t)NN*64*2);
  u16*   h1    = (u16*)alloc((size_t)NN*256*2);
  u16*   h2    = (u16*)alloc((size_t)NN*256*2);
  float* elA   = (float*)alloc((size_t)2*NN*4*4);
  float* erA   = (float*)alloc((size_t)2*NN*4*4);
  float* xbuf  = (float*)alloc((size_t)2*EE*4*4);     // 12.8 MB, reused L0/L1
  // region D (51.2 MB): layer-0 aggB -> layer-1 featD -> layer-2 outputs
  size_t featStride = (size_t)NN*256;                 // u16 elements per graph
  size_t off_D = off;
  u16* regionD = (u16*)alloc(2*featStride*2);
  u16* aggB  = regionD;
  u16* featD = regionD;
  u16*   feat16 = (u16*)(ws + off_D);                          // 2*NN*16 u16 (3.2 MB)
  float* resb   = (float*)(ws + off_D + (size_t)2*NN*16*2);    // 2*NN*16 f32
  float* el2    = resb + (size_t)2*NN*16;
  float* er2    = el2  + (size_t)2*NN;

  // 1. prep: zero counters + mixw + pack all weights; prep2: V2 = fc_w@[W0*al|W0*ar]
  k_prep<<<100,256,0,stream>>>(mix_w, wsoft, W0, W0p, W1, W1p, W2, res2, W2p,
                               fc_w0, fc_w1, Fp, zeros);
  k_prep2<<<32,128,0,stream>>>(W0, al0, ar0, fc_w0, fc_w1, fc_b0, fc_b1, V2p, bV);

  // 2. CSR build, both graphs
  {
    dim3 gEb((EE+255)/256, 2), gS(NB_SCAN, 2);
    k_count2 <<<gEb,256,0,stream>>>(dst[0], dst[1], cnt2);
    k_scan1  <<<gS,1024,0,stream>>>(cnt2, row2, bsum);
    k_scan3  <<<gS,1024,0,stream>>>(row2, bsum);
    k_scatter2<<<gEb,256,0,stream>>>(src[0], dst[0], src[1], dst[1], row2, fill2, col2, dstOf);
  }

  // 3. input projection (MFMA) with fused layer-0 el/er
  k_inproj_m<<<NGRP,256,0,stream>>>(features0, features1, Fp, fc_b0, fc_b1,
                                    V2p, bV, h0, elA, erA);

  dim3 gE((EE+255)/256, 2);

  // 4. layer 0: alpha, interleaved dual-graph aggregate (2-wave blocks), head GEMM
  k_alpha4<<<gE,256,0,stream>>>(col2, dstOf, elA, erA, (size_t)NN*4, xbuf);
  k_agg0 <<<NN/2,128,0,stream>>>(row2, col2, xbuf, h0, aggB, featStride);
  k_head0<<<NGRP,256,0,stream>>>(aggB, featStride, W0p, b0, wsoft, h1);

  // 5. layer 1: feat = h1 @ W1 (MFMA), alpha, fused aggregation (2-wave blocks)
  k_gemm4<256><<<2*NGRP,256,0,stream>>>(h1, W1p, (size_t)256*256, al1, ar1, 256,
                                        featD, featStride, elA, erA, (size_t)NN*4);
  k_alpha4<<<gE,256,0,stream>>>(col2, dstOf, elA, erA, (size_t)NN*4, xbuf);
  k_aggNF<1><<<NN/2,128,0,stream>>>(row2, col2, xbuf, featD, featStride,
                                    h1, b1, wsoft, 1, h2);

  // 6. layer 2 (both graphs fused; alpha inline in agg2D; feat16 bf16)
  k_gemm2<<<NGRP,256,0,stream>>>(h2, W2p, al2, ar2, feat16, resb, el2, er2);
  k_agg2D<<<NN/16,256,0,stream>>>(row2, col2, el2, er2, feat16, resb, b2, wsoft, (float*)d_out);
}

// Round 13
// 436.110 us; speedup vs baseline: 1.1196x; 1.0397x over previous
//
#include <hip/hip_runtime.h>
#include <hip/hip_bf16.h>

// Problem constants (match reference)
#define NN   50000   // N0+N1
#define NN0  30000
#define EE   400000
#define NB_SCAN ((NN + 1023) / 1024)   // 49
#define NB_E  ((EE + 255) / 256)       // 1563
#define NRT   3125                     // row tiles (16 rows each)
#define NGRP  ((NRT + 3) / 4)          // 782 row groups (64 rows)
#define NT0   1875                     // type-0 row tiles (30000/16, exact)

typedef unsigned short u16;
typedef unsigned int   u32;

typedef __attribute__((ext_vector_type(8))) __bf16 bf16x8;
typedef __attribute__((ext_vector_type(4))) float  f32x4;

// ---------- bf16 storage helpers (fp32 math everywhere) ----------
__device__ __forceinline__ float bf2f(u16 u){ return __uint_as_float(((u32)u)<<16); }
__device__ __forceinline__ float lo16(u32 u){ return __uint_as_float(u<<16); }
__device__ __forceinline__ float hi16(u32 u){ return __uint_as_float(u & 0xffff0000u); }
__device__ __forceinline__ u16 f2bf(float f){
  u32 x = __float_as_uint(f);
  x += 0x7fffu + ((x>>16)&1u);      // round-to-nearest-even
  return (u16)(x>>16);
}
__device__ __forceinline__ float elu_f(float x){ return x>0.f ? x : __expf(x)-1.f; }
__device__ __forceinline__ float lrelu(float x){ return x>0.f ? x : 0.2f*x; }
__device__ __forceinline__ bf16x8 ld_frag(const u16* p){
  uint4 v = *(const uint4*)p;
  return __builtin_bit_cast(bf16x8, v);
}
__device__ __forceinline__ bf16x8 cvt8(const float* p){   // 8 f32 -> bf16x8
  float4 u = ((const float4*)p)[0];
  float4 v = ((const float4*)p)[1];
  u32 w0 = (u32)f2bf(u.x) | ((u32)f2bf(u.y)<<16);
  u32 w1 = (u32)f2bf(u.z) | ((u32)f2bf(u.w)<<16);
  u32 w2 = (u32)f2bf(v.x) | ((u32)f2bf(v.y)<<16);
  u32 w3 = (u32)f2bf(v.z) | ((u32)f2bf(v.w)<<16);
  uint4 r{w0,w1,w2,w3};
  return __builtin_bit_cast(bf16x8, r);
}

// ---------- prep (blocks 0..99) ∪ prep2 (blocks 100..131) ----------
// prep: zero counters + mixw softmax + all weight packing
// prep2: V2 = fc_w @ [W0*al | W0*ar] (128x16 per type) + bV
__global__ __launch_bounds__(256) void k_prepAll(
    const float* __restrict__ mix_w, float* __restrict__ wsoft,
    const float* __restrict__ W0, u16* __restrict__ W0p,
    const float* __restrict__ W1, u16* __restrict__ W1p,
    const float* __restrict__ W2, const float* __restrict__ res2, u16* __restrict__ W2p,
    const float* __restrict__ fcw0, const float* __restrict__ fcw1, u16* __restrict__ Fp,
    const float* __restrict__ al0, const float* __restrict__ ar0,
    const float* __restrict__ fcb0, const float* __restrict__ fcb1,
    u16* __restrict__ V2p, float* __restrict__ bV,
    int* __restrict__ zeros)
{
  __shared__ float V[64];
  if (blockIdx.x >= 100){
    // ---- prep2 part: 32 blocks ----
    int b = blockIdx.x - 100;
    int tt = b>>4, cl = b&15;
    int which = cl>>3, g = (cl>>2)&1, h = cl&3;
    int t = threadIdx.x;
    const float* sel = (which ? ar0 : al0) + (size_t)(g*4+h)*64;
    if (t < 64){
      const float* Wrow = W0 + (size_t)g*16384 + (size_t)t*256 + h*64;
      float s = 0.f;
      #pragma unroll 8
      for (int d=0; d<64; d++) s = fmaf(Wrow[d], sel[d], s);
      V[t] = s;
    }
    __syncthreads();
    if (t < 128){
      const float* fw = tt ? fcw1 : fcw0;   // 128 x 64
      float s = 0.f;
      #pragma unroll 8
      for (int d=0; d<64; d++) s = fmaf(fw[(size_t)t*64 + d], V[d], s);
      int kb = t>>5, q = (t>>3)&3, j = t&7;
      V2p[(size_t)tt*2048 + ((size_t)kb*64 + q*16 + cl)*8 + j] = f2bf(s);
      if (t == 0){
        const float* fbp = tt ? fcb1 : fcb0;
        float sb = 0.f;
        #pragma unroll 8
        for (int d=0; d<64; d++) sb = fmaf(fbp[d], V[d], sb);
        bV[tt*16 + cl] = sb;
      }
    }
    return;
  }
  // ---- prep part: 100 blocks ----
  int t = blockIdx.x*256 + threadIdx.x;
  for (int z = t; z < 4*NN; z += 100*256) zeros[z] = 0;
  if (t < 6){
    float a0 = mix_w[t*2+0], a1 = mix_w[t*2+1];
    float mx = fmaxf(a0,a1);
    float e0 = __expf(a0-mx), e1 = __expf(a1-mx);
    wsoft[t*2+0] = e0/(e0+e1); wsoft[t*2+1] = e1/(e0+e1);
  }
  if (t < 4096){                    // W0: per graph 2048 frags, KB=2, NCOL=256
    int gg = t>>11, fi = t&2047;
    int lane = fi&63, kb = (fi>>6)&1, ct = fi>>7;
    int q = lane>>4, c = lane&15;
    const float* src = W0 + (size_t)gg*16384;
    u16* o = W0p + (size_t)gg*16384 + (size_t)fi*8;
    #pragma unroll
    for (int j=0;j<8;j++) o[j] = f2bf(src[(size_t)(kb*32+q*8+j)*256 + ct*16 + c]);
  } else if (t < 20480){            // W1: per graph 8192 frags, KB=8, NCOL=256
    int u = t - 4096;
    int gg = u>>13, fi = u&8191;
    int lane = fi&63, kb = (fi>>6)&7, ct = fi>>9;
    int q = lane>>4, c = lane&15;
    const float* src = W1 + (size_t)gg*65536;
    u16* o = W1p + (size_t)gg*65536 + (size_t)fi*8;
    #pragma unroll
    for (int j=0;j<8;j++) o[j] = f2bf(src[(size_t)(kb*32+q*8+j)*256 + ct*16 + c]);
  } else if (t < 22528){            // W2cat: 2048 frags, KB=8, NCOL=64
    int fi = t - 20480;
    int lane = fi&63, kb = (fi>>6)&7, ct = fi>>9;
    int q = lane>>4, c = lane&15;
    int cl = ct*16 + c;
    int i = cl>>5, which = (cl>>4)&1;
    const float* src = which ? res2 : W2;
    u16* o = W2p + (size_t)fi*8;
    #pragma unroll
    for (int j=0;j<8;j++) o[j] = f2bf(src[(size_t)i*4096 + (size_t)(kb*32+q*8+j)*16 + (cl&15)]);
  } else if (t < 24576){            // fc_w: per type 1024 frags, KB=4, NCOL=64
    int u = t - 22528;
    int tt = u>>10, fi = u&1023;
    int lane = fi&63, kb = (fi>>6)&3, ct = fi>>8;
    int q = lane>>4, c = lane&15;
    const float* src = tt ? fcw1 : fcw0;
    u16* o = Fp + (size_t)tt*8192 + (size_t)fi*8;
    #pragma unroll
    for (int j=0;j<8;j++) o[j] = f2bf(src[(size_t)(kb*32+q*8+j)*64 + ct*16 + c]);
  }
}

// ---------- fused: input projection MFMA (blocks 0..NGRP-1) ∪ edge count ------
// inproj: h0 = feats @ fc_w + fc_b;  el/er = feats @ V2 + bV
// count : cnt2[g][dst] += 1  (blocks NGRP .. NGRP+2*NB_E-1)
__global__ __launch_bounds__(256) void k_inpcnt(
    const float* __restrict__ f0, const float* __restrict__ f1,
    const u16* __restrict__ Fp, const float* __restrict__ fb0, const float* __restrict__ fb1,
    const u16* __restrict__ V2p, const float* __restrict__ bV,
    u16* __restrict__ h0, float* __restrict__ elA, float* __restrict__ erA,
    const int* __restrict__ d0, const int* __restrict__ d1, int* __restrict__ cnt2)
{
  if (blockIdx.x >= NGRP){
    int u = blockIdx.x - NGRP;
    int g = u / NB_E;
    int t = (u % NB_E)*256 + threadIdx.x;
    if (t < EE) atomicAdd(&cnt2[g*NN + (g ? d1[t] : d0[t])], 1);
    return;
  }
  int wv = threadIdx.x>>6, ln = threadIdx.x&63;
  int ti = blockIdx.x*4 + wv;
  if (ti >= NRT) return;
  int q = ln>>4, c = ln&15;
  int type = (ti < NT0) ? 0 : 1;
  const float* F = type ? f1 : f0;
  int rbase = type ? (ti*16 - NN0) : ti*16;
  const u16* Bg = Fp + (size_t)type*8192;
  const u16* Vg = V2p + (size_t)type*2048;
  const float* bb = type ? fb1 : fb0;
  f32x4 acc[4] = {};
  f32x4 accE = {};
  const float* Ap = F + (size_t)(rbase + c)*128;
  #pragma unroll
  for (int kb=0; kb<4; kb++){
    bf16x8 a = cvt8(Ap + kb*32 + q*8);
    #pragma unroll
    for (int ct=0; ct<4; ct++){
      bf16x8 b = ld_frag(Bg + ((size_t)(ct*4+kb)*64 + ln)*8);
      acc[ct] = __builtin_amdgcn_mfma_f32_16x16x32_bf16(a, b, acc[ct], 0,0,0);
    }
    bf16x8 bv_ = ld_frag(Vg + ((size_t)kb*64 + ln)*8);
    accE = __builtin_amdgcn_mfma_f32_16x16x32_bf16(a, bv_, accE, 0,0,0);
  }
  #pragma unroll
  for (int ct=0; ct<4; ct++){
    float bvs = bb[ct*16+c];
    #pragma unroll
    for (int j=0;j<4;j++){
      int row = ti*16 + q*4 + j;
      h0[(size_t)row*64 + ct*16 + c] = f2bf(acc[ct][j] + bvs);
    }
  }
  int which = c>>3, gg = (c>>2)&1, hh = c&3;
  float bVv = bV[type*16 + c];
  float* dst = (which ? erA : elA) + (size_t)gg*NN*4;
  #pragma unroll
  for (int j=0;j<4;j++){
    int row = ti*16 + q*4 + j;
    dst[row*4 + hh] = accE[j] + bVv;
  }
}

// ================= CSR build (both graphs, rebuilt every launch) ===============
__global__ __launch_bounds__(1024) void k_scan1(const int* __restrict__ cnt2,
                                                int* __restrict__ row2, int* __restrict__ bsum){
  __shared__ int wsum[16];
  int g = blockIdx.y;
  int lane = threadIdx.x & 63, wid = threadIdx.x >> 6;
  int i = blockIdx.x*1024 + threadIdx.x;
  int v = (i < NN) ? cnt2[g*NN + i] : 0;
  int x = v;
  #pragma unroll
  for (int off = 1; off < 64; off <<= 1){
    int y = __shfl_up(x, off, 64);
    if (lane >= off) x += y;
  }
  if (lane == 63) wsum[wid] = x;
  __syncthreads();
  if (wid == 0 && lane < 16){
    int s = wsum[lane];
    #pragma unroll
    for (int off = 1; off < 16; off <<= 1){
      int y = __shfl_up(s, off, 16);
      if (lane >= off) s += y;
    }
    wsum[lane] = s;
  }
  __syncthreads();
  int incl = x + (wid ? wsum[wid-1] : 0);
  if (i < NN) row2[(size_t)g*(NN+1) + i] = incl - v;
  if (threadIdx.x == 1023) bsum[g*NB_SCAN + blockIdx.x] = incl;
}

__global__ __launch_bounds__(1024) void k_scan3(int* __restrict__ row2,
                                                const int* __restrict__ bsum){
  __shared__ int base;
  int g = blockIdx.y;
  if (threadIdx.x < 64){
    int lane = threadIdx.x;
    int v = (lane < (int)blockIdx.x) ? bsum[g*NB_SCAN + lane] : 0;
    #pragma unroll
    for (int off = 32; off; off >>= 1) v += __shfl_xor(v, off, 64);
    if (lane == 0) base = v;
  }
  __syncthreads();
  int i = blockIdx.x*1024 + threadIdx.x;
  if (i < NN) row2[(size_t)g*(NN+1) + i] += base;
  if (blockIdx.x == 0 && threadIdx.x == 0) row2[(size_t)g*(NN+1) + NN] = EE;
}

__global__ void k_scatter2(const int* __restrict__ s0, const int* __restrict__ d0,
                           const int* __restrict__ s1, const int* __restrict__ d1,
                           const int* __restrict__ row2, int* __restrict__ fill2,
                           u16* __restrict__ col2, u16* __restrict__ dstOf){
  int t = blockIdx.x*256 + threadIdx.x;
  int g = blockIdx.y;
  if (t >= EE) return;
  int d = g ? d1[t] : d0[t];
  int s = g ? s1[t] : s0[t];
  int pos = atomicAdd(&fill2[g*NN + d], 1);
  size_t slot = (size_t)g*EE + row2[(size_t)g*(NN+1) + d] + pos;
  col2[slot]  = (u16)s;
  dstOf[slot] = (u16)d;
}

// ---------- alpha precompute (H=4), edge-parallel ----------
__global__ void k_alpha4(const u16* __restrict__ col2, const u16* __restrict__ dstOf,
                         const float* __restrict__ el, const float* __restrict__ er,
                         size_t elStride, float* __restrict__ xbuf){
  int t = blockIdx.x*256 + threadIdx.x;
  int g = blockIdx.y;
  if (t >= EE) return;
  size_t slot = (size_t)g*EE + t;
  int s = col2[slot], d = dstOf[slot];
  const float* elg = el + (size_t)g*elStride;
  const float* erg = er + (size_t)g*elStride;
  float4 e4 = ((const float4*)elg)[s];
  float4 r4 = ((const float4*)erg)[d];
  float4 x;
  x.x = __expf(lrelu(e4.x + r4.x));
  x.y = __expf(lrelu(e4.y + r4.y));
  x.z = __expf(lrelu(e4.z + r4.z));
  x.w = __expf(lrelu(e4.w + r4.w));
  ((float4*)xbuf)[slot] = x;
}

// ---------- layer-0 aggregation: gather h0 (64 cols), BOTH graphs interleaved --
__global__ __launch_bounds__(128) void k_agg0(
    const int* __restrict__ row2, const u16* __restrict__ col2,
    const float* __restrict__ xbuf, const u16* __restrict__ h0,
    u16* __restrict__ aggB, size_t aggStride)
{
  int wv = threadIdx.x>>6, ln = threadIdx.x&63;
  int n = blockIdx.x*2 + wv;
  const int* rw0 = row2;
  const int* rw1 = row2 + (NN+1);
  const u16* cl0 = col2;
  const u16* cl1 = col2 + EE;
  const float4* xb0 = (const float4*)xbuf;
  const float4* xb1 = xb0 + EE;
  int b0_ = rw0[n], e0_ = rw0[n+1];
  int b1_ = rw1[n], e1_ = rw1[n+1];
  int k0 = b0_, k1 = b1_;
  float d00=0.f,d01=0.f,d02=0.f,d03=0.f, a00=0.f,a01=0.f,a02=0.f,a03=0.f;
  float d10=0.f,d11=0.f,d12=0.f,d13=0.f, a10=0.f,a11=0.f,a12=0.f,a13=0.f;
  while (k0+2<=e0_ && k1+2<=e1_){
    int sA=cl0[k0], sB=cl0[k0+1], sC=cl1[k1], sD=cl1[k1+1];
    float4 xA=xb0[k0], xB=xb0[k0+1], xC=xb1[k1], xD=xb1[k1+1];
    float vA=bf2f(h0[(size_t)sA*64+ln]);
    float vB=bf2f(h0[(size_t)sB*64+ln]);
    float vC=bf2f(h0[(size_t)sC*64+ln]);
    float vD=bf2f(h0[(size_t)sD*64+ln]);
    d00+=xA.x+xB.x; d01+=xA.y+xB.y; d02+=xA.z+xB.z; d03+=xA.w+xB.w;
    a00+=xA.x*vA+xB.x*vB; a01+=xA.y*vA+xB.y*vB;
    a02+=xA.z*vA+xB.z*vB; a03+=xA.w*vA+xB.w*vB;
    d10+=xC.x+xD.x; d11+=xC.y+xD.y; d12+=xC.z+xD.z; d13+=xC.w+xD.w;
    a10+=xC.x*vC+xD.x*vD; a11+=xC.y*vC+xD.y*vD;
    a12+=xC.z*vC+xD.z*vD; a13+=xC.w*vC+xD.w*vD;
    k0+=2; k1+=2;
  }
  for (; k0+2<=e0_; k0+=2){
    int sA=cl0[k0], sB=cl0[k0+1];
    float4 xA=xb0[k0], xB=xb0[k0+1];
    float vA=bf2f(h0[(size_t)sA*64+ln]);
    float vB=bf2f(h0[(size_t)sB*64+ln]);
    d00+=xA.x+xB.x; d01+=xA.y+xB.y; d02+=xA.z+xB.z; d03+=xA.w+xB.w;
    a00+=xA.x*vA+xB.x*vB; a01+=xA.y*vA+xB.y*vB;
    a02+=xA.z*vA+xB.z*vB; a03+=xA.w*vA+xB.w*vB;
  }
  for (; k0<e0_; k0++){
    int s=cl0[k0]; float4 x=xb0[k0];
    float v=bf2f(h0[(size_t)s*64+ln]);
    d00+=x.x; d01+=x.y; d02+=x.z; d03+=x.w;
    a00+=x.x*v; a01+=x.y*v; a02+=x.z*v; a03+=x.w*v;
  }
  for (; k1+2<=e1_; k1+=2){
    int sC=cl1[k1], sD=cl1[k1+1];
    float4 xC=xb1[k1], xD=xb1[k1+1];
    float vC=bf2f(h0[(size_t)sC*64+ln]);
    float vD=bf2f(h0[(size_t)sD*64+ln]);
    d10+=xC.x+xD.x; d11+=xC.y+xD.y; d12+=xC.z+xD.z; d13+=xC.w+xD.w;
    a10+=xC.x*vC+xD.x*vD; a11+=xC.y*vC+xD.y*vD;
    a12+=xC.z*vC+xD.z*vD; a13+=xC.w*vC+xD.w*vD;
  }
  for (; k1<e1_; k1++){
    int s=cl1[k1]; float4 x=xb1[k1];
    float v=bf2f(h0[(size_t)s*64+ln]);
    d10+=x.x; d11+=x.y; d12+=x.z; d13+=x.w;
    a10+=x.x*v; a11+=x.y*v; a12+=x.z*v; a13+=x.w*v;
  }
  bool hg0 = e0_ > b0_, hg1 = e1_ > b1_;
  u16* og0 = aggB + (size_t)n*256 + ln;
  og0[0]   = f2bf(hg0 ? a00/d00 : 0.f);
  og0[64]  = f2bf(hg0 ? a01/d01 : 0.f);
  og0[128] = f2bf(hg0 ? a02/d02 : 0.f);
  og0[192] = f2bf(hg0 ? a03/d03 : 0.f);
  u16* og1 = aggB + aggStride + (size_t)n*256 + ln;
  og1[0]   = f2bf(hg1 ? a10/d10 : 0.f);
  og1[64]  = f2bf(hg1 ? a11/d11 : 0.f);
  og1[128] = f2bf(hg1 ? a12/d12 : 0.f);
  og1[192] = f2bf(hg1 ? a13/d13 : 0.f);
}

// ---------- layer-0 head GEMM: ELU(agg@W0_blockdiag + b) mixed -> h1 ----------
__global__ __launch_bounds__(256) void k_head0(
    const u16* __restrict__ aggB, size_t aggStride,
    const u16* __restrict__ W0p, const float* __restrict__ b0,
    const float* __restrict__ wsoft, u16* __restrict__ h1)
{
  int wv = threadIdx.x>>6, ln = threadIdx.x&63;
  int ti = blockIdx.x*4 + wv;
  if (ti >= NRT) return;
  int q = ln>>4, c = ln&15;
  int type = (ti < NT0) ? 0 : 1;
  float wg0 = wsoft[type*6 + 0];
  float wg1 = wsoft[type*6 + 1];
  for (int h=0; h<4; h++){
    f32x4 acc[2][4] = {};
    #pragma unroll
    for (int g=0; g<2; g++){
      const u16* Ap = aggB + (size_t)g*aggStride + (size_t)(ti*16 + c)*256 + h*64 + q*8;
      const u16* Bg = W0p + (size_t)g*16384;
      #pragma unroll
      for (int kb=0; kb<2; kb++){
        bf16x8 a = ld_frag(Ap + kb*32);
        #pragma unroll
        for (int ct=0; ct<4; ct++){
          int ctg = h*4 + ct;
          bf16x8 b = ld_frag(Bg + ((size_t)(ctg*2 + kb)*64 + ln)*8);
          acc[g][ct] = __builtin_amdgcn_mfma_f32_16x16x32_bf16(a, b, acc[g][ct], 0,0,0);
        }
      }
    }
    #pragma unroll
    for (int ct=0; ct<4; ct++){
      int colg = h*64 + ct*16 + c;
      float bb0 = b0[colg], bb1 = b0[256 + colg];
      #pragma unroll
      for (int j=0;j<4;j++){
        int row = ti*16 + q*4 + j;
        float o = wg0*elu_f(acc[0][ct][j] + bb0) + wg1*elu_f(acc[1][ct][j] + bb1);
        h1[(size_t)row*256 + colg] = f2bf(o);
      }
    }
  }
}

// ---------- MFMA GEMM, 4 row-tiles x 4 col-tiles per wave (layer 1) ------------
template<int K>
__global__ __launch_bounds__(256) void k_gemm4(
    const u16* __restrict__ A,
    const u16* __restrict__ Bp, size_t bpStride,
    const float* __restrict__ al, const float* __restrict__ ar, int alStride,
    u16* __restrict__ feat, size_t featStride,
    float* __restrict__ el, float* __restrict__ er, size_t elStride)
{
  constexpr int KB = K/32;
  int wv = threadIdx.x>>6, ln = threadIdx.x&63;
  int bid = blockIdx.x;
  int g = bid / NGRP, grp = bid % NGRP;
  int split = wv, q = ln>>4, c = ln&15;
  const u16* Bpg = Bp + (size_t)g*bpStride;
  const float* alg = al + (size_t)g*alStride;
  const float* arg = ar + (size_t)g*alStride;
  u16* featg = feat + (size_t)g*featStride;
  float* elg = el + (size_t)g*elStride;
  float* erg = er + (size_t)g*elStride;

  f32x4 acc[4][4] = {};
  int  tbase = grp*4;
  bool valid[4];
  const u16* Ap[4];
  #pragma unroll
  for (int rt=0; rt<4; rt++){
    int ti = tbase + rt;
    valid[rt] = (ti < NRT);
    if (!valid[rt]) ti = NRT-1;
    Ap[rt] = A + (size_t)(ti*16 + c)*K + q*8;
  }
  const u16* Bbase = Bpg + ((size_t)(split*4)*KB*64 + ln)*8;

  #pragma unroll 2
  for (int kb=0; kb<KB; kb++){
    bf16x8 b[4], a[4];
    #pragma unroll
    for (int ct=0; ct<4; ct++) b[ct] = ld_frag(Bbase + (size_t)(ct*KB + kb)*64*8);
    #pragma unroll
    for (int rt=0; rt<4; rt++) a[rt] = ld_frag(Ap[rt] + kb*32);
    #pragma unroll
    for (int rt=0; rt<4; rt++)
      #pragma unroll
      for (int ct=0; ct<4; ct++)
        acc[rt][ct] = __builtin_amdgcn_mfma_f32_16x16x32_bf16(a[rt], b[ct], acc[rt][ct], 0,0,0);
  }

  float alv[4], arv[4];
  #pragma unroll
  for (int ct=0;ct<4;ct++){
    int cg = (split*4+ct)*16 + c;
    alv[ct] = alg[cg]; arv[ct] = arg[cg];
  }
  #pragma unroll
  for (int rt=0; rt<4; rt++){
    if (!valid[rt]) continue;
    int row0 = (tbase+rt)*16;
    #pragma unroll
    for (int j=0;j<4;j++){
      float ep=0.f, rp=0.f;
      #pragma unroll
      for (int ct=0;ct<4;ct++){ ep += acc[rt][ct][j]*alv[ct]; rp += acc[rt][ct][j]*arv[ct]; }
      #pragma unroll
      for (int off=8; off; off>>=1){ ep += __shfl_xor(ep,off,16); rp += __shfl_xor(rp,off,16); }
      int row = row0 + q*4 + j;
      if (c==0){ elg[row*4+split]=ep; erg[row*4+split]=rp; }
      #pragma unroll
      for (int ct=0;ct<4;ct++)
        featg[(size_t)row*256 + (split*4+ct)*16 + c] = f2bf(acc[rt][ct][j]);
    }
  }
}

// ---------- fused dual-graph gather aggregation (256 cols, H=4), layer 1 -------
template<int RES>
__global__ __launch_bounds__(128) void k_aggNF(
    const int* __restrict__ row2, const u16* __restrict__ col2,
    const float* __restrict__ xbuf,
    const u16* __restrict__ feat, size_t featStride,
    const u16* __restrict__ hres, const float* __restrict__ bias,
    const float* __restrict__ wsoft, int l,
    u16* __restrict__ hout)
{
  int wv = threadIdx.x>>6, ln = threadIdx.x&63;
  int n = blockIdx.x*2 + wv;
  int h = ln>>4;
  int type = (n<NN0)?0:1;
  float rx=0.f, ry=0.f, rz=0.f, rw_=0.f;
  if (RES){
    uint2 r = ((const uint2*)hres)[(size_t)n*64 + ln];
    rx=lo16(r.x); ry=hi16(r.x); rz=lo16(r.y); rw_=hi16(r.y);
  }
  const int* rw0 = row2;
  const int* rw1 = row2 + (NN+1);
  const u16* cl0 = col2;
  const u16* cl1 = col2 + EE;
  const float* x0p = xbuf;
  const float* x1p = xbuf + (size_t)EE*4;
  const uint2* fp0 = (const uint2*)feat;
  const uint2* fp1 = (const uint2*)(feat + featStride);
  int b0_ = rw0[n], e0_ = rw0[n+1];
  int b1_ = rw1[n], e1_ = rw1[n+1];
  int k0 = b0_, k1 = b1_;
  float den0=0.f, A0=0.f,A1=0.f,A2=0.f,A3=0.f;
  float den1=0.f, B0=0.f,B1=0.f,B2=0.f,B3=0.f;
  while (k0+4<=e0_ && k1+4<=e1_){
    int s0=cl0[k0], s1=cl0[k0+1], s2=cl0[k0+2], s3=cl0[k0+3];
    int t0=cl1[k1], t1=cl1[k1+1], t2=cl1[k1+2], t3=cl1[k1+3];
    float x0=x0p[(size_t)k0*4+h],     x1=x0p[(size_t)(k0+1)*4+h];
    float x2=x0p[(size_t)(k0+2)*4+h], x3=x0p[(size_t)(k0+3)*4+h];
    float y0=x1p[(size_t)k1*4+h],     y1=x1p[(size_t)(k1+1)*4+h];
    float y2=x1p[(size_t)(k1+2)*4+h], y3=x1p[(size_t)(k1+3)*4+h];
    uint2 f0=fp0[(size_t)s0*64+ln], f1=fp0[(size_t)s1*64+ln];
    uint2 f2=fp0[(size_t)s2*64+ln], f3=fp0[(size_t)s3*64+ln];
    uint2 g0=fp1[(size_t)t0*64+ln], g1=fp1[(size_t)t1*64+ln];
    uint2 g2=fp1[(size_t)t2*64+ln], g3=fp1[(size_t)t3*64+ln];
    den0 += (x0+x1) + (x2+x3);
    A0 += x0*lo16(f0.x)+x1*lo16(f1.x)+x2*lo16(f2.x)+x3*lo16(f3.x);
    A1 += x0*hi16(f0.x)+x1*hi16(f1.x)+x2*hi16(f2.x)+x3*hi16(f3.x);
    A2 += x0*lo16(f0.y)+x1*lo16(f1.y)+x2*lo16(f2.y)+x3*lo16(f3.y);
    A3 += x0*hi16(f0.y)+x1*hi16(f1.y)+x2*hi16(f2.y)+x3*hi16(f3.y);
    den1 += (y0+y1) + (y2+y3);
    B0 += y0*lo16(g0.x)+y1*lo16(g1.x)+y2*lo16(g2.x)+y3*lo16(g3.x);
    B1 += y0*hi16(g0.x)+y1*hi16(g1.x)+y2*hi16(g2.x)+y3*hi16(g3.x);
    B2 += y0*lo16(g0.y)+y1*lo16(g1.y)+y2*lo16(g2.y)+y3*lo16(g3.y);
    B3 += y0*hi16(g0.y)+y1*hi16(g1.y)+y2*hi16(g2.y)+y3*hi16(g3.y);
    k0+=4; k1+=4;
  }
  for (; k0+4<=e0_; k0+=4){
    int s0=cl0[k0], s1=cl0[k0+1], s2=cl0[k0+2], s3=cl0[k0+3];
    float x0=x0p[(size_t)k0*4+h],     x1=x0p[(size_t)(k0+1)*4+h];
    float x2=x0p[(size_t)(k0+2)*4+h], x3=x0p[(size_t)(k0+3)*4+h];
    uint2 f0=fp0[(size_t)s0*64+ln], f1=fp0[(size_t)s1*64+ln];
    uint2 f2=fp0[(size_t)s2*64+ln], f3=fp0[(size_t)s3*64+ln];
    den0 += (x0+x1) + (x2+x3);
    A0 += x0*lo16(f0.x)+x1*lo16(f1.x)+x2*lo16(f2.x)+x3*lo16(f3.x);
    A1 += x0*hi16(f0.x)+x1*hi16(f1.x)+x2*hi16(f2.x)+x3*hi16(f3.x);
    A2 += x0*lo16(f0.y)+x1*lo16(f1.y)+x2*lo16(f2.y)+x3*lo16(f3.y);
    A3 += x0*hi16(f0.y)+x1*hi16(f1.y)+x2*hi16(f2.y)+x3*hi16(f3.y);
  }
  for (; k0<e0_; k0++){
    int s=cl0[k0];
    float x=x0p[(size_t)k0*4+h];
    uint2 f=fp0[(size_t)s*64+ln];
    den0 += x;
    A0 += x*lo16(f.x); A1 += x*hi16(f.x); A2 += x*lo16(f.y); A3 += x*hi16(f.y);
  }
  for (; k1+4<=e1_; k1+=4){
    int t0=cl1[k1], t1=cl1[k1+1], t2=cl1[k1+2], t3=cl1[k1+3];
    float y0=x1p[(size_t)k1*4+h],     y1=x1p[(size_t)(k1+1)*4+h];
    float y2=x1p[(size_t)(k1+2)*4+h], y3=x1p[(size_t)(k1+3)*4+h];
    uint2 g0=fp1[(size_t)t0*64+ln], g1=fp1[(size_t)t1*64+ln];
    uint2 g2=fp1[(size_t)t2*64+ln], g3=fp1[(size_t)t3*64+ln];
    den1 += (y0+y1) + (y2+y3);
    B0 += y0*lo16(g0.x)+y1*lo16(g1.x)+y2*lo16(g2.x)+y3*lo16(g3.x);
    B1 += y0*hi16(g0.x)+y1*hi16(g1.x)+y2*hi16(g2.x)+y3*hi16(g3.x);
    B2 += y0*lo16(g0.y)+y1*lo16(g1.y)+y2*lo16(g2.y)+y3*lo16(g3.y);
    B3 += y0*hi16(g0.y)+y1*hi16(g1.y)+y2*hi16(g2.y)+y3*hi16(g3.y);
  }
  for (; k1<e1_; k1++){
    int t=cl1[k1];
    float y=x1p[(size_t)k1*4+h];
    uint2 g=fp1[(size_t)t*64+ln];
    den1 += y;
    B0 += y*lo16(g.x); B1 += y*hi16(g.x); B2 += y*lo16(g.y); B3 += y*hi16(g.y);
  }
  float inv0 = (e0_>b0_) ? 1.0f/den0 : 0.f;
  float inv1 = (e1_>b1_) ? 1.0f/den1 : 0.f;
  float4 bv0 = ((const float4*)(bias))[ln];
  float4 bv1 = ((const float4*)(bias + 256))[ln];
  float w0 = wsoft[type*6 + l*2 + 0];
  float w1 = wsoft[type*6 + l*2 + 1];
  float c0 = A0*inv0 + bv0.x, c1 = A1*inv0 + bv0.y, c2 = A2*inv0 + bv0.z, c3 = A3*inv0 + bv0.w;
  float e0 = B0*inv1 + bv1.x, e1 = B1*inv1 + bv1.y, e2 = B2*inv1 + bv1.z, e3 = B3*inv1 + bv1.w;
  if (RES){ c0+=rx; c1+=ry; c2+=rz; c3+=rw_; e0+=rx; e1+=ry; e2+=rz; e3+=rw_; }
  float o0 = w0*elu_f(c0) + w1*elu_f(e0);
  float o1 = w0*elu_f(c1) + w1*elu_f(e1);
  float o2 = w0*elu_f(c2) + w1*elu_f(e2);
  float o3 = w0*elu_f(c3) + w1*elu_f(e3);
  uint2 o;
  o.x = (u32)f2bf(o0) | ((u32)f2bf(o1)<<16);
  o.y = (u32)f2bf(o2) | ((u32)f2bf(o3)<<16);
  ((uint2*)hout)[(size_t)n*64 + ln] = o;
}

// ---------- layer-2 MFMA: A(N,256) @ [W2_0|res2_0|W2_1|res2_1](256,64) ----------
__global__ __launch_bounds__(256) void k_gemm2(
    const u16* __restrict__ A, const u16* __restrict__ Bp,
    const float* __restrict__ al2, const float* __restrict__ ar2,
    u16* __restrict__ feat16, float* __restrict__ resb,
    float* __restrict__ el2, float* __restrict__ er2)
{
  int wv = threadIdx.x>>6, ln = threadIdx.x&63;
  int wt = blockIdx.x*4 + wv;
  if (wt >= NRT) return;
  int row0 = wt*16;
  int q = ln>>4, c = ln&15;
  f32x4 acc[4] = {};
  const u16* Ap = A + (size_t)(row0 + c)*256 + q*8;
  #pragma unroll
  for (int kb=0; kb<8; kb++){
    bf16x8 a = ld_frag(Ap + kb*32);
    #pragma unroll
    for (int t=0;t<4;t++){
      bf16x8 b = ld_frag(Bp + ((size_t)(t*8 + kb)*64 + ln)*8);
      acc[t] = __builtin_amdgcn_mfma_f32_16x16x32_bf16(a, b, acc[t], 0,0,0);
    }
  }
  #pragma unroll
  for (int i=0;i<2;i++){
    float alv = al2[i*16+c], arv = ar2[i*16+c];
    #pragma unroll
    for (int j=0;j<4;j++){
      float ep = acc[2*i][j]*alv, rp = acc[2*i][j]*arv;
      #pragma unroll
      for (int off=8; off; off>>=1){ ep += __shfl_xor(ep,off,16); rp += __shfl_xor(rp,off,16); }
      if (c==0){
        int row = row0 + q*4 + j;
        el2[(size_t)i*NN + row] = ep; er2[(size_t)i*NN + row] = rp;
      }
    }
    #pragma unroll
    for (int j=0;j<4;j++){
      int row = row0 + q*4 + j;
      feat16[(size_t)i*NN*16 + (size_t)row*16 + c] = f2bf(acc[2*i][j]);
      resb  [(size_t)i*NN*16 + (size_t)row*16 + c] = acc[2*i+1][j];
    }
  }
}

// ---------- layer-2 dual-graph aggregation + inline alpha + final mix ----------
__global__ __launch_bounds__(256) void k_agg2D(
    const int* __restrict__ row2, const u16* __restrict__ col2,
    const float* __restrict__ el2, const float* __restrict__ er2,
    const u16* __restrict__ feat16, const float* __restrict__ resb,
    const float* __restrict__ b2, const float* __restrict__ wsoft,
    float* __restrict__ out)
{
  int t = threadIdx.x;
  int nl = t>>4, j = t&15;
  int n = blockIdx.x*16 + nl;
  int type = (n<NN0)?0:1;
  float o = 0.f;
  #pragma unroll
  for (int i=0;i<2;i++){
    const int* rw = row2 + (size_t)i*(NN+1);
    const u16* cl = col2 + (size_t)i*EE;
    const float* elg = el2 + (size_t)i*NN;
    float ern = er2[(size_t)i*NN + n];
    const u16* f = feat16 + (size_t)i*NN*16;
    int beg = rw[n], end = rw[n+1];
    float den = 0.f, acc = 0.f;
    int k = beg;
    for (; k+4<=end; k+=4){
      int s0=cl[k], s1=cl[k+1], s2=cl[k+2], s3=cl[k+3];
      float x0 = __expf(lrelu(elg[s0] + ern));
      float x1 = __expf(lrelu(elg[s1] + ern));
      float x2 = __expf(lrelu(elg[s2] + ern));
      float x3 = __expf(lrelu(elg[s3] + ern));
      float v0 = bf2f(f[(size_t)s0*16 + j]);
      float v1 = bf2f(f[(size_t)s1*16 + j]);
      float v2 = bf2f(f[(size_t)s2*16 + j]);
      float v3 = bf2f(f[(size_t)s3*16 + j]);
      den += (x0+x1) + (x2+x3);
      acc += x0*v0 + x1*v1 + x2*v2 + x3*v3;
    }
    for (; k<end; k++){
      int s = cl[k];
      float x = __expf(lrelu(elg[s] + ern));
      den += x;
      acc = fmaf(x, bf2f(f[(size_t)s*16 + j]), acc);
    }
    float inv = (end>beg) ? 1.0f/den : 0.f;
    float oi = acc*inv + b2[i*16+j] + resb[(size_t)i*NN*16 + (size_t)n*16 + j];
    o += oi * wsoft[type*6 + 4 + i];
  }
  out[(size_t)n*16 + j] = o;
}

extern "C" void kernel_launch(void* const* d_in, const int* in_sizes, int n_in,
                              void* d_out, int out_size, void* d_ws, size_t ws_size,
                              hipStream_t stream)
{
  const float* features0 = (const float*)d_in[0];
  const float* features1 = (const float*)d_in[1];
  const float* fc_w0 = (const float*)d_in[2];
  const float* fc_b0 = (const float*)d_in[3];
  const float* fc_w1 = (const float*)d_in[4];
  const float* fc_b1 = (const float*)d_in[5];
  const float* mix_w = (const float*)d_in[6];
  const float* W0  = (const float*)d_in[7];
  const float* al0 = (const float*)d_in[8];
  const float* ar0 = (const float*)d_in[9];
  const float* b0  = (const float*)d_in[10];
  const float* W1  = (const float*)d_in[11];
  const float* al1 = (const float*)d_in[12];
  const float* ar1 = (const float*)d_in[13];
  const float* b1  = (const float*)d_in[14];
  const float* W2  = (const float*)d_in[15];
  const float* al2 = (const float*)d_in[16];
  const float* ar2 = (const float*)d_in[17];
  const float* b2  = (const float*)d_in[18];
  const float* res2= (const float*)d_in[19];
  const int* src[2] = {(const int*)d_in[20], (const int*)d_in[22]};
  const int* dst[2] = {(const int*)d_in[21], (const int*)d_in[23]};
  (void)in_sizes; (void)n_in; (void)out_size; (void)ws_size;

  char* ws = (char*)d_ws;
  size_t off = 0;
  auto alloc = [&](size_t bytes)->char*{
    char* p = ws + off; off += (bytes + 255) & ~(size_t)255; return p;
  };
  float* wsoft = (float*)alloc(64*4);
  u16*   W0p   = (u16*)  alloc((size_t)2*64*256*2);
  u16*   W1p   = (u16*)  alloc((size_t)2*256*256*2);
  u16*   W2p   = (u16*)  alloc((size_t)256*64*2);
  u16*   Fp    = (u16*)  alloc((size_t)2*128*64*2);
  u16*   V2p   = (u16*)  alloc((size_t)2*128*16*2);
  float* bV    = (float*)alloc((size_t)32*4);
  int*   row2  = (int*)  alloc((size_t)2*(NN+1)*4);
  u16*   col2  = (u16*)  alloc((size_t)2*EE*2);
  u16*   dstOf = (u16*)  alloc((size_t)2*EE*2);
  int*   zeros = (int*)  alloc((size_t)4*NN*4);       // cnt2 + fill2, zeroed in prep
  int*   cnt2  = zeros;
  int*   fill2 = zeros + 2*NN;
  int*   bsum  = (int*)alloc((size_t)2*NB_SCAN*4);
  u16*   h0    = (u16*)alloc((size_t)NN*64*2);
  u16*   h1    = (u16*)alloc((size_t)NN*256*2);
  u16*   h2    = (u16*)alloc((size_t)NN*256*2);
  float* elA   = (float*)alloc((size_t)2*NN*4*4);
  float* erA   = (float*)alloc((size_t)2*NN*4*4);
  float* xbuf  = (float*)alloc((size_t)2*EE*4*4);     // 12.8 MB, reused L0/L1
  // region D (51.2 MB): layer-0 aggB -> layer-1 featD -> layer-2 outputs
  size_t featStride = (size_t)NN*256;                 // u16 elements per graph
  size_t off_D = off;
  u16* regionD = (u16*)alloc(2*featStride*2);
  u16* aggB  = regionD;
  u16* featD = regionD;
  u16*   feat16 = (u16*)(ws + off_D);                          // 2*NN*16 u16 (3.2 MB)
  float* resb   = (float*)(ws + off_D + (size_t)2*NN*16*2);    // 2*NN*16 f32
  float* el2    = resb + (size_t)2*NN*16;
  float* er2    = el2  + (size_t)2*NN;

  // 1. prep ∪ prep2 (one dispatch)
  k_prepAll<<<132,256,0,stream>>>(mix_w, wsoft, W0, W0p, W1, W1p, W2, res2, W2p,
                                  fc_w0, fc_w1, Fp, al0, ar0, fc_b0, fc_b1,
                                  V2p, bV, zeros);

  // 2. input projection (MFMA, + fused layer-0 el/er) ∪ edge count (one dispatch)
  k_inpcnt<<<NGRP + 2*NB_E,256,0,stream>>>(features0, features1, Fp, fc_b0, fc_b1,
                                           V2p, bV, h0, elA, erA,
                                           dst[0], dst[1], cnt2);

  // 3. CSR scan + scatter
  {
    dim3 gS(NB_SCAN, 2), gEb(NB_E, 2);
    k_scan1  <<<gS,1024,0,stream>>>(cnt2, row2, bsum);
    k_scan3  <<<gS,1024,0,stream>>>(row2, bsum);
    k_scatter2<<<gEb,256,0,stream>>>(src[0], dst[0], src[1], dst[1], row2, fill2, col2, dstOf);
  }

  dim3 gE(NB_E, 2);

  // 4. layer 0: alpha, interleaved dual-graph aggregate (2-wave blocks), head GEMM
  k_alpha4<<<gE,256,0,stream>>>(col2, dstOf, elA, erA, (size_t)NN*4, xbuf);
  k_agg0 <<<NN/2,128,0,stream>>>(row2, col2, xbuf, h0, aggB, featStride);
  k_head0<<<NGRP,256,0,stream>>>(aggB, featStride, W0p, b0, wsoft, h1);

  // 5. layer 1: feat = h1 @ W1 (MFMA), alpha, fused aggregation (2-wave blocks)
  k_gemm4<256><<<2*NGRP,256,0,stream>>>(h1, W1p, (size_t)256*256, al1, ar1, 256,
                                        featD, featStride, elA, erA, (size_t)NN*4);
  k_alpha4<<<gE,256,0,stream>>>(col2, dstOf, elA, erA, (size_t)NN*4, xbuf);
  k_aggNF<1><<<NN/2,128,0,stream>>>(row2, col2, xbuf, featD, featStride,
                                    h1, b1, wsoft, 1, h2);

  // 6. layer 2 (both graphs fused; alpha inline in agg2D; feat16 bf16)
  k_gemm2<<<NGRP,256,0,stream>>>(h2, W2p, al2, ar2, feat16, resb, el2, er2);
  k_agg2D<<<NN/16,256,0,stream>>>(row2, col2, el2, er2, feat16, resb, b2, wsoft, (float*)d_out);
}